// Round 7
// baseline (479.474 us; speedup 1.0000x reference)
//
#include <hip/hip_runtime.h>
#include <hip/hip_bf16.h>

#define N_NODES 50000
#define N_EDGES 800000
#define D 128
#define SCAN_B 196  // ceil(N_NODES/256)
#define NT_GEMM 782 // ceil(N_NODES/64)

typedef __attribute__((ext_vector_type(8))) __bf16 bf16x8;
typedef __attribute__((ext_vector_type(4))) float f32x4;

union U8 {
  bf16x8 v;
  uint4 u;
};

// ---- fp32 -> bf16 split helpers (RNE; used in precompute/gather) ----
__device__ __forceinline__ unsigned short bf16_rne(float x) {
  unsigned u = __builtin_bit_cast(unsigned, x);
  unsigned r = u + 0x7fffu + ((u >> 16) & 1u);
  return (unsigned short)(r >> 16);
}
__device__ __forceinline__ float bf16_f(unsigned short b) {
  unsigned u = ((unsigned)b) << 16;
  return __builtin_bit_cast(float, u);
}
__device__ __forceinline__ void split2(float x, unsigned short& hi, unsigned short& lo) {
  hi = bf16_rne(x);
  lo = bf16_rne(x - bf16_f(hi));
}

__device__ __forceinline__ float selu_f(float x) {
  const float alpha = 1.6732632423543772f;
  const float scale = 1.0507009873554805f;
  return scale * (x > 0.0f ? x : alpha * expm1f(x));
}

// split raw fp32 bits (r0,r1 = 8 dwords) -> bf16 hi/lo fragments
__device__ __forceinline__ void splitF(uint4 r0, uint4 r1, U8& ah, U8& al) {
  unsigned u0 = r0.x, u1 = r0.y, u2 = r0.z, u3 = r0.w;
  unsigned u4 = r1.x, u5 = r1.y, u6 = r1.z, u7 = r1.w;
  ah.u.x = (u0 >> 16) | (u1 & 0xffff0000u);
  ah.u.y = (u2 >> 16) | (u3 & 0xffff0000u);
  ah.u.z = (u4 >> 16) | (u5 & 0xffff0000u);
  ah.u.w = (u6 >> 16) | (u7 & 0xffff0000u);
  unsigned r;
#define LOW(u) __builtin_bit_cast(unsigned, __builtin_bit_cast(float, u) - __builtin_bit_cast(float, u & 0xffff0000u))
  r = LOW(u0); al.u.x = r >> 16;
  r = LOW(u1); al.u.x |= r & 0xffff0000u;
  r = LOW(u2); al.u.y = r >> 16;
  r = LOW(u3); al.u.y |= r & 0xffff0000u;
  r = LOW(u4); al.u.z = r >> 16;
  r = LOW(u5); al.u.z |= r & 0xffff0000u;
  r = LOW(u6); al.u.w = r >> 16;
  r = LOW(u7); al.u.w |= r & 0xffff0000u;
#undef LOW
}

// unpack packed hi|lo<<16 dwords -> bf16 hi/lo fragments
__device__ __forceinline__ void splitP(uint4 p0, uint4 p1, U8& ah, U8& al) {
  ah.u.x = (p0.x & 0xffffu) | (p0.y << 16);
  ah.u.y = (p0.z & 0xffffu) | (p0.w << 16);
  ah.u.z = (p1.x & 0xffffu) | (p1.y << 16);
  ah.u.w = (p1.z & 0xffffu) | (p1.w << 16);
  al.u.x = (p0.x >> 16) | (p0.y & 0xffff0000u);
  al.u.y = (p0.z >> 16) | (p0.w & 0xffff0000u);
  al.u.z = (p1.x >> 16) | (p1.y & 0xffff0000u);
  al.u.w = (p1.z >> 16) | (p1.w & 0xffff0000u);
}

// ================= CSR build =================
__global__ __launch_bounds__(256) void hist_kernel(const int* __restrict__ dst,
                                                   int* __restrict__ cnt) {
  int e = blockIdx.x * 256 + threadIdx.x;
  if (e < N_EDGES) atomicAdd(&cnt[dst[e]], 1);
}

__global__ __launch_bounds__(256) void scan1_kernel(const int* __restrict__ cnt,
                                                    int* __restrict__ cursor,
                                                    int* __restrict__ bsum) {
  __shared__ int s[256];
  const int t = threadIdx.x;
  const int i = blockIdx.x * 256 + t;
  int v = (i < N_NODES) ? cnt[i] : 0;
  s[t] = v;
  __syncthreads();
#pragma unroll
  for (int off = 1; off < 256; off <<= 1) {
    int u = (t >= off) ? s[t - off] : 0;
    __syncthreads();
    s[t] += u;
    __syncthreads();
  }
  if (i < N_NODES) cursor[i] = s[t] - v;
  if (t == 255) bsum[blockIdx.x] = s[255];
}

__global__ __launch_bounds__(256) void scan2_kernel(int* __restrict__ bsum) {
  __shared__ int s[256];
  const int t = threadIdx.x;
  int v = (t < SCAN_B) ? bsum[t] : 0;
  s[t] = v;
  __syncthreads();
#pragma unroll
  for (int off = 1; off < 256; off <<= 1) {
    int u = (t >= off) ? s[t - off] : 0;
    __syncthreads();
    s[t] += u;
    __syncthreads();
  }
  if (t < SCAN_B) bsum[t] = s[t] - v;
}

__global__ __launch_bounds__(256) void scan3_kernel(int* __restrict__ cursor,
                                                    const int* __restrict__ bsum) {
  const int i = blockIdx.x * 256 + threadIdx.x;
  if (i < N_NODES) cursor[i] += bsum[blockIdx.x];
}

__global__ __launch_bounds__(256) void fill_kernel(const int* __restrict__ src,
                                                   const int* __restrict__ dst,
                                                   int* __restrict__ cursor,
                                                   int* __restrict__ csr_src) {
  int e = blockIdx.x * 256 + threadIdx.x;
  if (e < N_EDGES) {
    int pos = atomicAdd(&cursor[dst[e]], 1);
    csr_src[pos] = src[e];
  }
}

// ================= weight split/transpose precompute =================
// Buffers hold the LDS image (pre-swizzled): short index = logical ^ ((n&7)<<3),
// logical = n*K + k. gemm staging is then a plain linear copy (G21).
__global__ __launch_bounds__(256) void wsplit_kernel(
    const float* __restrict__ Ws0, const float* __restrict__ Wn0,
    const float* __restrict__ Ws1, const float* __restrict__ Wn1,
    const float* __restrict__ Ws2, const float* __restrict__ Wn2,
    const float* __restrict__ b2,
    unsigned short* __restrict__ wt0h, unsigned short* __restrict__ wt0l,
    unsigned short* __restrict__ wt1h, unsigned short* __restrict__ wt1l,
    unsigned short* __restrict__ wt2h, unsigned short* __restrict__ wt2l,
    float* __restrict__ b2ext) {
  int idx = blockIdx.x * 256 + threadIdx.x;
  if (idx < 32768) {
    int n = idx >> 8, k = idx & 255;
    float wv = (k < 128) ? Ws0[k * 128 + n] : Wn0[(k - 128) * 128 + n];
    unsigned short h, l; split2(wv, h, l);
    int si = idx ^ ((n & 7) << 3);
    wt0h[si] = h; wt0l[si] = l;
  } else if (idx < 65536) {
    int j = idx - 32768;
    int n = j >> 8, k = j & 255;
    float wv = (k < 128) ? Ws1[k * 128 + n] : Wn1[(k - 128) * 128 + n];
    unsigned short h, l; split2(wv, h, l);
    int si = j ^ ((n & 7) << 3);
    wt1h[si] = h; wt1l[si] = l;
  } else if (idx < 81920) {
    int j = idx - 65536;
    int n = j >> 7, k = j & 127;
    float wv = (n < 64) ? Ws2[k * 64 + n] : Wn2[k * 64 + (n - 64)];
    unsigned short h, l; split2(wv, h, l);
    int si = j ^ ((n & 7) << 3);
    wt2h[si] = h; wt2l[si] = l;
  } else if (idx < 82048) {
    int c = idx - 81920;
    b2ext[c] = (c < 64) ? b2[c] : 0.0f;
  }
}

// ================= gather-mean -> packed bf16 hi/lo =================
__global__ __launch_bounds__(256) void gather_split(const float* __restrict__ h,
                                                    const int* __restrict__ cursor,
                                                    const int* __restrict__ csr,
                                                    unsigned* __restrict__ meanPk) {
  const int n = blockIdx.x * 4 + (threadIdx.x >> 6);
  const int lane = threadIdx.x & 63;
  const int end = cursor[n];
  const int start = (n == 0) ? 0 : cursor[n - 1];
  const float* hp = h + lane * 2;
  float ax = 0.f, ay = 0.f;
  int e = start;
  for (; e + 3 < end; e += 4) {
    int s0 = csr[e], s1 = csr[e + 1], s2 = csr[e + 2], s3 = csr[e + 3];
    float2 v0 = *(const float2*)(hp + (size_t)s0 * D);
    float2 v1 = *(const float2*)(hp + (size_t)s1 * D);
    float2 v2 = *(const float2*)(hp + (size_t)s2 * D);
    float2 v3 = *(const float2*)(hp + (size_t)s3 * D);
    ax += (v0.x + v1.x) + (v2.x + v3.x);
    ay += (v0.y + v1.y) + (v2.y + v3.y);
  }
  for (; e < end; ++e) {
    int s0 = csr[e];
    float2 v0 = *(const float2*)(hp + (size_t)s0 * D);
    ax += v0.x; ay += v0.y;
  }
  float inv = 1.0f / (float)max(end - start, 1);
  ax *= inv; ay *= inv;
  unsigned short hx, lx, hy, ly;
  split2(ax, hx, lx);
  split2(ay, hy, ly);
  uint2 pk;
  pk.x = (unsigned)hx | ((unsigned)lx << 16);
  pk.y = (unsigned)hy | ((unsigned)ly << 16);
  *(uint2*)(meanPk + (size_t)n * D + lane * 2) = pk;
}

// ================= persistent MFMA GEMM, B panel in LDS =================
// Grid = persistent blocks (LDS: 2*128*K shorts). Stage B once (1 barrier),
// then loop 64-row tiles barrier-free. A prefetched one tile ahead.
template <int QH, int QM, int ACT, int SPLIT>
__global__ __launch_bounds__(256, 2) void gemm_lds(const float* __restrict__ hsrc,
                                                   const unsigned* __restrict__ meanPk,
                                                   const unsigned short* __restrict__ wth,
                                                   const unsigned short* __restrict__ wtl,
                                                   const float* __restrict__ bias,
                                                   float* __restrict__ out0,
                                                   float* __restrict__ out1) {
  constexpr int NQ = QH + QM;
  constexpr int K = NQ * 64;
  __shared__ unsigned short bsm[2][128 * K];

  const int tid = threadIdx.x;
  const int w = tid >> 6;
  const int l = tid & 63;
  const int lr = l & 15;
  const int lg = l >> 4;

  // ---- stage B panel (linear copy of pre-swizzled buffers) ----
  {
    const uint4* gh = (const uint4*)wth;
    const uint4* gl = (const uint4*)wtl;
    uint4* s0 = (uint4*)&bsm[0][0];
    uint4* s1 = (uint4*)&bsm[1][0];
    constexpr int NU = 16 * K;  // uint4 count per buffer
#pragma unroll 4
    for (int i = tid; i < NU; i += 256) s0[i] = gh[i];
#pragma unroll 4
    for (int i = tid; i < NU; i += 256) s1[i] = gl[i];
  }
  __syncthreads();

  // per-lane A loader: 16 uint4 = the wave-lane's full A slice for one tile
  auto loadA = [&](int t, uint4* r) {
    const int grow = t * 64 + w * 16 + lr;
    const int arow = min(grow, N_NODES - 1);
    const uint4* hp = (const uint4*)(hsrc + (size_t)arow * D);
    const uint4* mp = (QM > 0) ? (const uint4*)(meanPk + (size_t)arow * D) : hp;
#pragma unroll
    for (int q = 0; q < NQ; ++q) {
      const uint4* base = (q < QH) ? (hp + q * 16) : (mp + (q - QH) * 16);
#pragma unroll
      for (int kt = 0; kt < 2; ++kt) {
        r[q * 4 + kt * 2 + 0] = base[kt * 8 + lg * 2];
        r[q * 4 + kt * 2 + 1] = base[kt * 8 + lg * 2 + 1];
      }
    }
  };

  const int stride = gridDim.x;
  uint4 curA[NQ * 4], nxtA[NQ * 4];
  int t = blockIdx.x;
  if (t < NT_GEMM) loadA(t, curA);

  for (; t < NT_GEMM; t += stride) {
    const int tn = t + stride;
    if (tn < NT_GEMM) loadA(tn, nxtA);

    f32x4 accA[8], accB[8];
#pragma unroll
    for (int i = 0; i < 8; ++i) {
      accA[i] = (f32x4){0.f, 0.f, 0.f, 0.f};
      accB[i] = (f32x4){0.f, 0.f, 0.f, 0.f};
    }

#pragma unroll
    for (int q = 0; q < NQ; ++q) {
#pragma unroll
      for (int kt = 0; kt < 2; ++kt) {
        U8 ah, al;
        if (q < QH) splitF(curA[q * 4 + kt * 2], curA[q * 4 + kt * 2 + 1], ah, al);
        else        splitP(curA[q * 4 + kt * 2], curA[q * 4 + kt * 2 + 1], ah, al);
        const int kbase = q * 64 + (((((kt << 2) | lg)) ^ (lr & 7)) << 3);
#pragma unroll
        for (int nf = 0; nf < 8; ++nf) {
          const int si = (nf * 16 + lr) * K + kbase;
          bf16x8 bh = *(const bf16x8*)&bsm[0][si];
          bf16x8 bl = *(const bf16x8*)&bsm[1][si];
          accA[nf] = __builtin_amdgcn_mfma_f32_16x16x32_bf16(ah.v, bh, accA[nf], 0, 0, 0);
          accB[nf] = __builtin_amdgcn_mfma_f32_16x16x32_bf16(al.v, bh, accB[nf], 0, 0, 0);
          accB[nf] = __builtin_amdgcn_mfma_f32_16x16x32_bf16(ah.v, bl, accB[nf], 0, 0, 0);
        }
      }
    }

    // epilogue: C col = nf*16+lr, row = w*16 + lg*4 + i
#pragma unroll
    for (int nf = 0; nf < 8; ++nf) {
      const int col = nf * 16 + lr;
      const float bv = bias[col];
#pragma unroll
      for (int i = 0; i < 4; ++i) {
        const int grow = t * 64 + w * 16 + lg * 4 + i;
        if (grow < N_NODES) {
          float v = accA[nf][i] + accB[nf][i] + bv;
          if (ACT) v = selu_f(v);
          if (SPLIT) {
            if (col < 64) out0[(size_t)grow * 64 + col] = v;
            else out1[(size_t)grow * 64 + (col - 64)] = v;
          } else {
            out0[(size_t)grow * D + col] = v;
          }
        }
      }
    }

#pragma unroll
    for (int i = 0; i < NQ * 4; ++i) curA[i] = nxtA[i];
  }
}

// ================= fused gather(z) + add(u) + softmax =================
__global__ __launch_bounds__(256) void gather_sm(const float* __restrict__ zbuf,
                                                 const int* __restrict__ cursor,
                                                 const int* __restrict__ csr,
                                                 float* __restrict__ out) {
  const int n = blockIdx.x * 8 + (threadIdx.x >> 5);
  const int sl = threadIdx.x & 31;
  const int end = cursor[n];
  const int start = (n == 0) ? 0 : cursor[n - 1];
  const float* zp = zbuf + sl * 2;
  float ax = 0.f, ay = 0.f;
  int e = start;
  for (; e + 3 < end; e += 4) {
    int s0 = csr[e], s1 = csr[e + 1], s2 = csr[e + 2], s3 = csr[e + 3];
    float2 v0 = *(const float2*)(zp + (size_t)s0 * 64);
    float2 v1 = *(const float2*)(zp + (size_t)s1 * 64);
    float2 v2 = *(const float2*)(zp + (size_t)s2 * 64);
    float2 v3 = *(const float2*)(zp + (size_t)s3 * 64);
    ax += (v0.x + v1.x) + (v2.x + v3.x);
    ay += (v0.y + v1.y) + (v2.y + v3.y);
  }
  for (; e < end; ++e) {
    int s0 = csr[e];
    float2 v0 = *(const float2*)(zp + (size_t)s0 * 64);
    ax += v0.x; ay += v0.y;
  }
  float inv = 1.0f / (float)max(end - start, 1);
  size_t o = (size_t)n * 64 + sl * 2;
  float vx = out[o] + ax * inv;
  float vy = out[o + 1] + ay * inv;
  float m = fmaxf(vx, vy);
#pragma unroll
  for (int off = 16; off > 0; off >>= 1) m = fmaxf(m, __shfl_xor(m, off, 64));
  float ex = expf(vx - m);
  float ey = expf(vy - m);
  float s = ex + ey;
#pragma unroll
  for (int off = 16; off > 0; off >>= 1) s += __shfl_xor(s, off, 64);
  float r = 1.0f / s;
  out[o] = ex * r;
  out[o + 1] = ey * r;
}

extern "C" void kernel_launch(void* const* d_in, const int* in_sizes, int n_in,
                              void* d_out, int out_size, void* d_ws, size_t ws_size,
                              hipStream_t stream) {
  const float* x   = (const float*)d_in[0];
  const int* src   = (const int*)d_in[1];
  const int* dst   = (const int*)d_in[2];
  const float* Ws0 = (const float*)d_in[3];
  const float* Wn0 = (const float*)d_in[4];
  const float* b0  = (const float*)d_in[5];
  const float* Ws1 = (const float*)d_in[6];
  const float* Wn1 = (const float*)d_in[7];
  const float* b1  = (const float*)d_in[8];
  const float* Ws2 = (const float*)d_in[9];
  const float* Wn2 = (const float*)d_in[10];
  const float* b2  = (const float*)d_in[11];
  float* out = (float*)d_out;

  // ws layout: cursor int[50048] | csr int[800000] | A=h1 25.6MB | B=h2 25.6MB | C 25.6MB
  char* ws = (char*)d_ws;
  int* cursor = (int*)ws;
  int* csr    = (int*)(ws + 200192);
  float* h1   = (float*)(ws + 3400192);
  float* h2   = (float*)(ws + 29000192);
  char* Creg  = ws + 54600192;
  unsigned* meanPk = (unsigned*)Creg;
  float* zbuf      = (float*)Creg;
  int* cnt         = (int*)Creg;
  int* bsum        = (int*)(Creg + N_NODES * sizeof(int));

  // split weights staged in d_out (12.8 MB; overwritten by layer-2 output later)
  unsigned short* W = (unsigned short*)d_out;
  unsigned short* wt0h = W;
  unsigned short* wt0l = W + 32768;
  unsigned short* wt1h = W + 65536;
  unsigned short* wt1l = W + 98304;
  unsigned short* wt2h = W + 131072;
  unsigned short* wt2l = W + 147456;
  float* b2ext = (float*)(W + 163840);

  // layer-2 weight copy target: A region (h1 is dead by then)
  unsigned short* wt2hc = (unsigned short*)h1;
  unsigned short* wt2lc = wt2hc + 16384;
  float* b2extc = (float*)(wt2hc + 32768);

  // CSR build (parallel 2-level scan)
  hipMemsetAsync(cnt, 0, N_NODES * sizeof(int), stream);
  hist_kernel<<<3125, 256, 0, stream>>>(dst, cnt);
  scan1_kernel<<<SCAN_B, 256, 0, stream>>>(cnt, cursor, bsum);
  scan2_kernel<<<1, 256, 0, stream>>>(bsum);
  scan3_kernel<<<SCAN_B, 256, 0, stream>>>(cursor, bsum);
  fill_kernel<<<3125, 256, 0, stream>>>(src, dst, cursor, csr);
  wsplit_kernel<<<321, 256, 0, stream>>>(Ws0, Wn0, Ws1, Wn1, Ws2, Wn2, b2,
                                         wt0h, wt0l, wt1h, wt1l, wt2h, wt2l, b2ext);

  // layer 0: x -> h1 (selu)
  gather_split<<<12500, 256, 0, stream>>>(x, cursor, csr, meanPk);
  gemm_lds<2, 2, 1, 0><<<256, 256, 0, stream>>>(x, meanPk, wt0h, wt0l, b0, h1, nullptr);

  // layer 1: h1 -> h2 (selu)
  gather_split<<<12500, 256, 0, stream>>>(h1, cursor, csr, meanPk);
  gemm_lds<2, 2, 1, 0><<<256, 256, 0, stream>>>(h1, meanPk, wt1h, wt1l, b1, h2, nullptr);

  // layer 2: u = h2@Ws2 + b2 -> out ; z = h2@Wn2 -> zbuf ; then mean(z) + u -> softmax
  hipMemcpyAsync(wt2hc, wt2h, 66048, hipMemcpyDeviceToDevice, stream);
  gemm_lds<2, 0, 0, 1><<<512, 256, 0, stream>>>(h2, nullptr, wt2hc, wt2lc, b2extc, out, zbuf);
  gather_sm<<<6250, 256, 0, stream>>>(zbuf, cursor, csr, out);
}

// Round 8
// 352.645 us; speedup vs baseline: 1.3597x; 1.3597x over previous
//
#include <hip/hip_runtime.h>
#include <hip/hip_bf16.h>

#define N_NODES 50000
#define N_EDGES 800000
#define D 128
#define SCAN_B 196  // ceil(N_NODES/256)
#define NT_GEMM 782 // ceil(N_NODES/64)

typedef __attribute__((ext_vector_type(8))) __bf16 bf16x8;
typedef __attribute__((ext_vector_type(4))) float f32x4;

union U8 {
  bf16x8 v;
  uint4 u;
};

// ---- fp32 -> bf16 split helpers (RNE; used in precompute/gather) ----
__device__ __forceinline__ unsigned short bf16_rne(float x) {
  unsigned u = __builtin_bit_cast(unsigned, x);
  unsigned r = u + 0x7fffu + ((u >> 16) & 1u);
  return (unsigned short)(r >> 16);
}
__device__ __forceinline__ float bf16_f(unsigned short b) {
  unsigned u = ((unsigned)b) << 16;
  return __builtin_bit_cast(float, u);
}
__device__ __forceinline__ void split2(float x, unsigned short& hi, unsigned short& lo) {
  hi = bf16_rne(x);
  lo = bf16_rne(x - bf16_f(hi));
}

__device__ __forceinline__ float selu_f(float x) {
  const float alpha = 1.6732632423543772f;
  const float scale = 1.0507009873554805f;
  return scale * (x > 0.0f ? x : alpha * expm1f(x));
}

// split raw fp32 bits (r0,r1 = 8 dwords) -> bf16 hi/lo fragments (trunc split)
__device__ __forceinline__ void splitF(uint4 r0, uint4 r1, U8& ah, U8& al) {
  unsigned u0 = r0.x, u1 = r0.y, u2 = r0.z, u3 = r0.w;
  unsigned u4 = r1.x, u5 = r1.y, u6 = r1.z, u7 = r1.w;
  ah.u.x = (u0 >> 16) | (u1 & 0xffff0000u);
  ah.u.y = (u2 >> 16) | (u3 & 0xffff0000u);
  ah.u.z = (u4 >> 16) | (u5 & 0xffff0000u);
  ah.u.w = (u6 >> 16) | (u7 & 0xffff0000u);
  unsigned r;
#define LOW(u) __builtin_bit_cast(unsigned, __builtin_bit_cast(float, u) - __builtin_bit_cast(float, u & 0xffff0000u))
  r = LOW(u0); al.u.x = r >> 16;
  r = LOW(u1); al.u.x |= r & 0xffff0000u;
  r = LOW(u2); al.u.y = r >> 16;
  r = LOW(u3); al.u.y |= r & 0xffff0000u;
  r = LOW(u4); al.u.z = r >> 16;
  r = LOW(u5); al.u.z |= r & 0xffff0000u;
  r = LOW(u6); al.u.w = r >> 16;
  r = LOW(u7); al.u.w |= r & 0xffff0000u;
#undef LOW
}

// unpack packed hi|lo<<16 dwords -> bf16 hi/lo fragments
__device__ __forceinline__ void splitP(uint4 p0, uint4 p1, U8& ah, U8& al) {
  ah.u.x = (p0.x & 0xffffu) | (p0.y << 16);
  ah.u.y = (p0.z & 0xffffu) | (p0.w << 16);
  ah.u.z = (p1.x & 0xffffu) | (p1.y << 16);
  ah.u.w = (p1.z & 0xffffu) | (p1.w << 16);
  al.u.x = (p0.x >> 16) | (p0.y & 0xffff0000u);
  al.u.y = (p0.z >> 16) | (p0.w & 0xffff0000u);
  al.u.z = (p1.x >> 16) | (p1.y & 0xffff0000u);
  al.u.w = (p1.z >> 16) | (p1.w & 0xffff0000u);
}

// ================= CSR build =================
__global__ __launch_bounds__(256) void hist_kernel(const int* __restrict__ dst,
                                                   int* __restrict__ cnt) {
  int e = blockIdx.x * 256 + threadIdx.x;
  if (e < N_EDGES) atomicAdd(&cnt[dst[e]], 1);
}

__global__ __launch_bounds__(256) void scan1_kernel(const int* __restrict__ cnt,
                                                    int* __restrict__ cursor,
                                                    int* __restrict__ bsum) {
  __shared__ int s[256];
  const int t = threadIdx.x;
  const int i = blockIdx.x * 256 + t;
  int v = (i < N_NODES) ? cnt[i] : 0;
  s[t] = v;
  __syncthreads();
#pragma unroll
  for (int off = 1; off < 256; off <<= 1) {
    int u = (t >= off) ? s[t - off] : 0;
    __syncthreads();
    s[t] += u;
    __syncthreads();
  }
  if (i < N_NODES) cursor[i] = s[t] - v;
  if (t == 255) bsum[blockIdx.x] = s[255];
}

__global__ __launch_bounds__(256) void scan2_kernel(int* __restrict__ bsum) {
  __shared__ int s[256];
  const int t = threadIdx.x;
  int v = (t < SCAN_B) ? bsum[t] : 0;
  s[t] = v;
  __syncthreads();
#pragma unroll
  for (int off = 1; off < 256; off <<= 1) {
    int u = (t >= off) ? s[t - off] : 0;
    __syncthreads();
    s[t] += u;
    __syncthreads();
  }
  if (t < SCAN_B) bsum[t] = s[t] - v;
}

__global__ __launch_bounds__(256) void scan3_kernel(int* __restrict__ cursor,
                                                    const int* __restrict__ bsum) {
  const int i = blockIdx.x * 256 + threadIdx.x;
  if (i < N_NODES) cursor[i] += bsum[blockIdx.x];
}

__global__ __launch_bounds__(256) void fill_kernel(const int* __restrict__ src,
                                                   const int* __restrict__ dst,
                                                   int* __restrict__ cursor,
                                                   int* __restrict__ csr_src) {
  int e = blockIdx.x * 256 + threadIdx.x;
  if (e < N_EDGES) {
    int pos = atomicAdd(&cursor[dst[e]], 1);
    csr_src[pos] = src[e];
  }
}

// ================= weight split/transpose precompute =================
// Buffers hold the LDS image (pre-swizzled): short index = logical ^ ((n&7)<<3),
// logical = n*K + k. gemm staging is then a plain linear copy (G21).
__global__ __launch_bounds__(256) void wsplit_kernel(
    const float* __restrict__ Ws0, const float* __restrict__ Wn0,
    const float* __restrict__ Ws1, const float* __restrict__ Wn1,
    const float* __restrict__ Ws2, const float* __restrict__ Wn2,
    const float* __restrict__ b2,
    unsigned short* __restrict__ wt0h, unsigned short* __restrict__ wt0l,
    unsigned short* __restrict__ wt1h, unsigned short* __restrict__ wt1l,
    unsigned short* __restrict__ wt2h, unsigned short* __restrict__ wt2l,
    float* __restrict__ b2ext) {
  int idx = blockIdx.x * 256 + threadIdx.x;
  if (idx < 32768) {
    int n = idx >> 8, k = idx & 255;
    float wv = (k < 128) ? Ws0[k * 128 + n] : Wn0[(k - 128) * 128 + n];
    unsigned short h, l; split2(wv, h, l);
    int si = idx ^ ((n & 7) << 3);
    wt0h[si] = h; wt0l[si] = l;
  } else if (idx < 65536) {
    int j = idx - 32768;
    int n = j >> 8, k = j & 255;
    float wv = (k < 128) ? Ws1[k * 128 + n] : Wn1[(k - 128) * 128 + n];
    unsigned short h, l; split2(wv, h, l);
    int si = j ^ ((n & 7) << 3);
    wt1h[si] = h; wt1l[si] = l;
  } else if (idx < 81920) {
    int j = idx - 65536;
    int n = j >> 7, k = j & 127;
    float wv = (n < 64) ? Ws2[k * 64 + n] : Wn2[k * 64 + (n - 64)];
    unsigned short h, l; split2(wv, h, l);
    int si = j ^ ((n & 7) << 3);
    wt2h[si] = h; wt2l[si] = l;
  } else if (idx < 82048) {
    int c = idx - 81920;
    b2ext[c] = (c < 64) ? b2[c] : 0.0f;
  }
}

// ================= gather-mean -> packed bf16 hi/lo =================
__global__ __launch_bounds__(256) void gather_split(const float* __restrict__ h,
                                                    const int* __restrict__ cursor,
                                                    const int* __restrict__ csr,
                                                    unsigned* __restrict__ meanPk) {
  const int n = blockIdx.x * 4 + (threadIdx.x >> 6);
  const int lane = threadIdx.x & 63;
  const int end = cursor[n];
  const int start = (n == 0) ? 0 : cursor[n - 1];
  const float* hp = h + lane * 2;
  float ax = 0.f, ay = 0.f;
  int e = start;
  for (; e + 3 < end; e += 4) {
    int s0 = csr[e], s1 = csr[e + 1], s2 = csr[e + 2], s3 = csr[e + 3];
    float2 v0 = *(const float2*)(hp + (size_t)s0 * D);
    float2 v1 = *(const float2*)(hp + (size_t)s1 * D);
    float2 v2 = *(const float2*)(hp + (size_t)s2 * D);
    float2 v3 = *(const float2*)(hp + (size_t)s3 * D);
    ax += (v0.x + v1.x) + (v2.x + v3.x);
    ay += (v0.y + v1.y) + (v2.y + v3.y);
  }
  for (; e < end; ++e) {
    int s0 = csr[e];
    float2 v0 = *(const float2*)(hp + (size_t)s0 * D);
    ax += v0.x; ay += v0.y;
  }
  float inv = 1.0f / (float)max(end - start, 1);
  ax *= inv; ay *= inv;
  unsigned short hx, lx, hy, ly;
  split2(ax, hx, lx);
  split2(ay, hy, ly);
  uint2 pk;
  pk.x = (unsigned)hx | ((unsigned)lx << 16);
  pk.y = (unsigned)hy | ((unsigned)ly << 16);
  *(uint2*)(meanPk + (size_t)n * D + lane * 2) = pk;
}

// ================= col-split MFMA GEMM: 64-row B panel in LDS =================
// Block = 64 rows x 64 cols. A slice issued BEFORE the stage barrier (flies
// during staging); inner loop is split -> ds_read -> MFMA only.
template <int QH, int QM, int ACT, int SPLIT>
__global__ __launch_bounds__(256, 2) void gemm_cs(const float* __restrict__ hsrc,
                                                  const unsigned* __restrict__ meanPk,
                                                  const unsigned short* __restrict__ wth,
                                                  const unsigned short* __restrict__ wtl,
                                                  const float* __restrict__ bias,
                                                  float* __restrict__ out0,
                                                  float* __restrict__ out1) {
  constexpr int NQ = QH + QM;
  constexpr int K = NQ * 64;
  __shared__ unsigned short bh_s[64 * K];
  __shared__ unsigned short bl_s[64 * K];

  const int tid = threadIdx.x;
  const int w = tid >> 6;
  const int l = tid & 63;
  const int lr = l & 15;
  const int lg = l >> 4;
  const int cb = blockIdx.y;  // column half
  const int row0 = blockIdx.x * 64;
  const int arow = min(row0 + w * 16 + lr, N_NODES - 1);

  // ---- issue the wave's full A slice first (16 uint4 for K=256) ----
  uint4 a[NQ * 4];
  {
    const uint4* hp = (const uint4*)(hsrc + (size_t)arow * D);
    const uint4* mp = (QM > 0) ? (const uint4*)(meanPk + (size_t)arow * D) : hp;
#pragma unroll
    for (int q = 0; q < NQ; ++q) {
      const uint4* base = (q < QH) ? (hp + q * 16) : (mp + (q - QH) * 16);
#pragma unroll
      for (int kt = 0; kt < 2; ++kt) {
        a[q * 4 + kt * 2 + 0] = base[kt * 8 + lg * 2];
        a[q * 4 + kt * 2 + 1] = base[kt * 8 + lg * 2 + 1];
      }
    }
  }

  // ---- stage this block's 64-row B panel (pre-swizzled, linear copy) ----
  {
    const uint4* gh = (const uint4*)(wth + (size_t)cb * 64 * K);
    const uint4* gl = (const uint4*)(wtl + (size_t)cb * 64 * K);
    uint4* sh = (uint4*)bh_s;
    uint4* sl = (uint4*)bl_s;
    constexpr int NU = 64 * K / 8;  // uint4 per panel
#pragma unroll
    for (int i = 0; i < NU / 256; ++i) {
      sh[tid + i * 256] = gh[tid + i * 256];
      sl[tid + i * 256] = gl[tid + i * 256];
    }
  }
  __syncthreads();

  f32x4 accA[4], accB[4];
#pragma unroll
  for (int i = 0; i < 4; ++i) {
    accA[i] = (f32x4){0.f, 0.f, 0.f, 0.f};
    accB[i] = (f32x4){0.f, 0.f, 0.f, 0.f};
  }

#pragma unroll
  for (int q = 0; q < NQ; ++q) {
#pragma unroll
    for (int kt = 0; kt < 2; ++kt) {
      U8 ah, al;
      if (q < QH) splitF(a[q * 4 + kt * 2], a[q * 4 + kt * 2 + 1], ah, al);
      else        splitP(a[q * 4 + kt * 2], a[q * 4 + kt * 2 + 1], ah, al);
      const int kb = q * 64 + (((((kt << 2) | lg)) ^ (lr & 7)) << 3);
#pragma unroll
      for (int nf = 0; nf < 4; ++nf) {
        const int si = (nf * 16 + lr) * K + kb;
        bf16x8 bh = *(const bf16x8*)&bh_s[si];
        bf16x8 bl = *(const bf16x8*)&bl_s[si];
        accA[nf] = __builtin_amdgcn_mfma_f32_16x16x32_bf16(ah.v, bh, accA[nf], 0, 0, 0);
        accB[nf] = __builtin_amdgcn_mfma_f32_16x16x32_bf16(al.v, bh, accB[nf], 0, 0, 0);
        accB[nf] = __builtin_amdgcn_mfma_f32_16x16x32_bf16(ah.v, bl, accB[nf], 0, 0, 0);
      }
    }
  }

  // epilogue: C col = cb*64 + nf*16 + lr, row = row0 + w*16 + lg*4 + i
#pragma unroll
  for (int nf = 0; nf < 4; ++nf) {
    const int col = cb * 64 + nf * 16 + lr;
    const float bv = bias[col];
#pragma unroll
    for (int i = 0; i < 4; ++i) {
      const int grow = row0 + w * 16 + lg * 4 + i;
      if (grow < N_NODES) {
        float v = accA[nf][i] + accB[nf][i] + bv;
        if (ACT) v = selu_f(v);
        if (SPLIT) {
          if (col < 64) out0[(size_t)grow * 64 + col] = v;
          else out1[(size_t)grow * 64 + (col - 64)] = v;
        } else {
          out0[(size_t)grow * D + col] = v;
        }
      }
    }
  }
}

// ================= fused gather(z) + add(u) + softmax =================
__global__ __launch_bounds__(256) void gather_sm(const float* __restrict__ zbuf,
                                                 const int* __restrict__ cursor,
                                                 const int* __restrict__ csr,
                                                 float* __restrict__ out) {
  const int n = blockIdx.x * 8 + (threadIdx.x >> 5);
  const int sl = threadIdx.x & 31;
  const int end = cursor[n];
  const int start = (n == 0) ? 0 : cursor[n - 1];
  const float* zp = zbuf + sl * 2;
  float ax = 0.f, ay = 0.f;
  int e = start;
  for (; e + 3 < end; e += 4) {
    int s0 = csr[e], s1 = csr[e + 1], s2 = csr[e + 2], s3 = csr[e + 3];
    float2 v0 = *(const float2*)(zp + (size_t)s0 * 64);
    float2 v1 = *(const float2*)(zp + (size_t)s1 * 64);
    float2 v2 = *(const float2*)(zp + (size_t)s2 * 64);
    float2 v3 = *(const float2*)(zp + (size_t)s3 * 64);
    ax += (v0.x + v1.x) + (v2.x + v3.x);
    ay += (v0.y + v1.y) + (v2.y + v3.y);
  }
  for (; e < end; ++e) {
    int s0 = csr[e];
    float2 v0 = *(const float2*)(zp + (size_t)s0 * 64);
    ax += v0.x; ay += v0.y;
  }
  float inv = 1.0f / (float)max(end - start, 1);
  size_t o = (size_t)n * 64 + sl * 2;
  float vx = out[o] + ax * inv;
  float vy = out[o + 1] + ay * inv;
  float m = fmaxf(vx, vy);
#pragma unroll
  for (int off = 16; off > 0; off >>= 1) m = fmaxf(m, __shfl_xor(m, off, 64));
  float ex = expf(vx - m);
  float ey = expf(vy - m);
  float s = ex + ey;
#pragma unroll
  for (int off = 16; off > 0; off >>= 1) s += __shfl_xor(s, off, 64);
  float r = 1.0f / s;
  out[o] = ex * r;
  out[o + 1] = ey * r;
}

extern "C" void kernel_launch(void* const* d_in, const int* in_sizes, int n_in,
                              void* d_out, int out_size, void* d_ws, size_t ws_size,
                              hipStream_t stream) {
  const float* x   = (const float*)d_in[0];
  const int* src   = (const int*)d_in[1];
  const int* dst   = (const int*)d_in[2];
  const float* Ws0 = (const float*)d_in[3];
  const float* Wn0 = (const float*)d_in[4];
  const float* b0  = (const float*)d_in[5];
  const float* Ws1 = (const float*)d_in[6];
  const float* Wn1 = (const float*)d_in[7];
  const float* b1  = (const float*)d_in[8];
  const float* Ws2 = (const float*)d_in[9];
  const float* Wn2 = (const float*)d_in[10];
  const float* b2  = (const float*)d_in[11];
  float* out = (float*)d_out;

  // ws layout: cursor int[50048] | csr int[800000] | A=h1 25.6MB | B=h2 25.6MB | C 25.6MB
  char* ws = (char*)d_ws;
  int* cursor = (int*)ws;
  int* csr    = (int*)(ws + 200192);
  float* h1   = (float*)(ws + 3400192);
  float* h2   = (float*)(ws + 29000192);
  char* Creg  = ws + 54600192;
  unsigned* meanPk = (unsigned*)Creg;
  float* zbuf      = (float*)Creg;
  int* cnt         = (int*)Creg;
  int* bsum        = (int*)(Creg + N_NODES * sizeof(int));

  // split weights staged in d_out (12.8 MB; overwritten by layer-2 output later)
  unsigned short* W = (unsigned short*)d_out;
  unsigned short* wt0h = W;
  unsigned short* wt0l = W + 32768;
  unsigned short* wt1h = W + 65536;
  unsigned short* wt1l = W + 98304;
  unsigned short* wt2h = W + 131072;
  unsigned short* wt2l = W + 147456;
  float* b2ext = (float*)(W + 163840);

  // layer-2 weight copy target: A region (h1 is dead by then)
  unsigned short* wt2hc = (unsigned short*)h1;
  unsigned short* wt2lc = wt2hc + 16384;
  float* b2extc = (float*)(wt2hc + 32768);

  // CSR build (parallel 2-level scan)
  hipMemsetAsync(cnt, 0, N_NODES * sizeof(int), stream);
  hist_kernel<<<3125, 256, 0, stream>>>(dst, cnt);
  scan1_kernel<<<SCAN_B, 256, 0, stream>>>(cnt, cursor, bsum);
  scan2_kernel<<<1, 256, 0, stream>>>(bsum);
  scan3_kernel<<<SCAN_B, 256, 0, stream>>>(cursor, bsum);
  fill_kernel<<<3125, 256, 0, stream>>>(src, dst, cursor, csr);
  wsplit_kernel<<<321, 256, 0, stream>>>(Ws0, Wn0, Ws1, Wn1, Ws2, Wn2, b2,
                                         wt0h, wt0l, wt1h, wt1l, wt2h, wt2l, b2ext);

  // layer 0: x -> h1 (selu)
  gather_split<<<12500, 256, 0, stream>>>(x, cursor, csr, meanPk);
  gemm_cs<2, 2, 1, 0><<<dim3(NT_GEMM, 2), 256, 0, stream>>>(x, meanPk, wt0h, wt0l, b0, h1, nullptr);

  // layer 1: h1 -> h2 (selu)
  gather_split<<<12500, 256, 0, stream>>>(h1, cursor, csr, meanPk);
  gemm_cs<2, 2, 1, 0><<<dim3(NT_GEMM, 2), 256, 0, stream>>>(h1, meanPk, wt1h, wt1l, b1, h2, nullptr);

  // layer 2: u = h2@Ws2 + b2 -> out ; z = h2@Wn2 -> zbuf ; then mean(z) + u -> softmax
  hipMemcpyAsync(wt2hc, wt2h, 66048, hipMemcpyDeviceToDevice, stream);
  gemm_cs<2, 0, 0, 1><<<dim3(NT_GEMM, 2), 256, 0, stream>>>(h2, nullptr, wt2hc, wt2lc, b2extc, out, zbuf);
  gather_sm<<<6250, 256, 0, stream>>>(zbuf, cursor, csr, out);
}

// Round 9
// 344.683 us; speedup vs baseline: 1.3911x; 1.0231x over previous
//
#include <hip/hip_runtime.h>
#include <hip/hip_bf16.h>

#define N_NODES 50000
#define N_EDGES 800000
#define D 128
#define SCAN_B 196  // ceil(N_NODES/256)
#define NT_GEMM 782 // ceil(N_NODES/64)

typedef __attribute__((ext_vector_type(8))) __bf16 bf16x8;
typedef __attribute__((ext_vector_type(4))) float f32x4;

union U8 {
  bf16x8 v;
  uint4 u;
};

// ---- fp32 -> bf16 split helpers (RNE; used in precompute/gather) ----
__device__ __forceinline__ unsigned short bf16_rne(float x) {
  unsigned u = __builtin_bit_cast(unsigned, x);
  unsigned r = u + 0x7fffu + ((u >> 16) & 1u);
  return (unsigned short)(r >> 16);
}
__device__ __forceinline__ float bf16_f(unsigned short b) {
  unsigned u = ((unsigned)b) << 16;
  return __builtin_bit_cast(float, u);
}
__device__ __forceinline__ void split2(float x, unsigned short& hi, unsigned short& lo) {
  hi = bf16_rne(x);
  lo = bf16_rne(x - bf16_f(hi));
}

__device__ __forceinline__ float selu_f(float x) {
  const float alpha = 1.6732632423543772f;
  const float scale = 1.0507009873554805f;
  return scale * (x > 0.0f ? x : alpha * expm1f(x));
}

// split raw fp32 bits (r0,r1 = 8 dwords) -> bf16 hi/lo fragments (trunc split)
__device__ __forceinline__ void splitF(uint4 r0, uint4 r1, U8& ah, U8& al) {
  unsigned u0 = r0.x, u1 = r0.y, u2 = r0.z, u3 = r0.w;
  unsigned u4 = r1.x, u5 = r1.y, u6 = r1.z, u7 = r1.w;
  ah.u.x = (u0 >> 16) | (u1 & 0xffff0000u);
  ah.u.y = (u2 >> 16) | (u3 & 0xffff0000u);
  ah.u.z = (u4 >> 16) | (u5 & 0xffff0000u);
  ah.u.w = (u6 >> 16) | (u7 & 0xffff0000u);
  unsigned r;
#define LOW(u) __builtin_bit_cast(unsigned, __builtin_bit_cast(float, u) - __builtin_bit_cast(float, u & 0xffff0000u))
  r = LOW(u0); al.u.x = r >> 16;
  r = LOW(u1); al.u.x |= r & 0xffff0000u;
  r = LOW(u2); al.u.y = r >> 16;
  r = LOW(u3); al.u.y |= r & 0xffff0000u;
  r = LOW(u4); al.u.z = r >> 16;
  r = LOW(u5); al.u.z |= r & 0xffff0000u;
  r = LOW(u6); al.u.w = r >> 16;
  r = LOW(u7); al.u.w |= r & 0xffff0000u;
#undef LOW
}

// unpack packed hi|lo<<16 dwords -> bf16 hi/lo fragments
__device__ __forceinline__ void splitP(uint4 p0, uint4 p1, U8& ah, U8& al) {
  ah.u.x = (p0.x & 0xffffu) | (p0.y << 16);
  ah.u.y = (p0.z & 0xffffu) | (p0.w << 16);
  ah.u.z = (p1.x & 0xffffu) | (p1.y << 16);
  ah.u.w = (p1.z & 0xffffu) | (p1.w << 16);
  al.u.x = (p0.x >> 16) | (p0.y & 0xffff0000u);
  al.u.y = (p0.z >> 16) | (p0.w & 0xffff0000u);
  al.u.z = (p1.x >> 16) | (p1.y & 0xffff0000u);
  al.u.w = (p1.z >> 16) | (p1.w & 0xffff0000u);
}

// ================= CSR build =================
__global__ __launch_bounds__(256) void hist_kernel(const int* __restrict__ dst,
                                                   int* __restrict__ cnt) {
  int e = blockIdx.x * 256 + threadIdx.x;
  if (e < N_EDGES) atomicAdd(&cnt[dst[e]], 1);
}

__global__ __launch_bounds__(256) void scan1_kernel(const int* __restrict__ cnt,
                                                    int* __restrict__ cursor,
                                                    int* __restrict__ bsum) {
  __shared__ int s[256];
  const int t = threadIdx.x;
  const int i = blockIdx.x * 256 + t;
  int v = (i < N_NODES) ? cnt[i] : 0;
  s[t] = v;
  __syncthreads();
#pragma unroll
  for (int off = 1; off < 256; off <<= 1) {
    int u = (t >= off) ? s[t - off] : 0;
    __syncthreads();
    s[t] += u;
    __syncthreads();
  }
  if (i < N_NODES) cursor[i] = s[t] - v;
  if (t == 255) bsum[blockIdx.x] = s[255];
}

__global__ __launch_bounds__(256) void scan2_kernel(int* __restrict__ bsum) {
  __shared__ int s[256];
  const int t = threadIdx.x;
  int v = (t < SCAN_B) ? bsum[t] : 0;
  s[t] = v;
  __syncthreads();
#pragma unroll
  for (int off = 1; off < 256; off <<= 1) {
    int u = (t >= off) ? s[t - off] : 0;
    __syncthreads();
    s[t] += u;
    __syncthreads();
  }
  if (t < SCAN_B) bsum[t] = s[t] - v;
}

__global__ __launch_bounds__(256) void scan3_kernel(int* __restrict__ cursor,
                                                    const int* __restrict__ bsum) {
  const int i = blockIdx.x * 256 + threadIdx.x;
  if (i < N_NODES) cursor[i] += bsum[blockIdx.x];
}

__global__ __launch_bounds__(256) void fill_kernel(const int* __restrict__ src,
                                                   const int* __restrict__ dst,
                                                   int* __restrict__ cursor,
                                                   int* __restrict__ csr_src) {
  int e = blockIdx.x * 256 + threadIdx.x;
  if (e < N_EDGES) {
    int pos = atomicAdd(&cursor[dst[e]], 1);
    csr_src[pos] = src[e];
  }
}

// ================= weight split/transpose precompute =================
// Buffers hold the LDS image (pre-swizzled): short index = logical ^ ((n&7)<<3),
// logical = n*K + k. gemm staging is then a plain linear copy (G21).
__global__ __launch_bounds__(256) void wsplit_kernel(
    const float* __restrict__ Ws0, const float* __restrict__ Wn0,
    const float* __restrict__ Ws1, const float* __restrict__ Wn1,
    const float* __restrict__ Ws2, const float* __restrict__ Wn2,
    const float* __restrict__ b2,
    unsigned short* __restrict__ wt0h, unsigned short* __restrict__ wt0l,
    unsigned short* __restrict__ wt1h, unsigned short* __restrict__ wt1l,
    unsigned short* __restrict__ wt2h, unsigned short* __restrict__ wt2l,
    float* __restrict__ b2ext) {
  int idx = blockIdx.x * 256 + threadIdx.x;
  if (idx < 32768) {
    int n = idx >> 8, k = idx & 255;
    float wv = (k < 128) ? Ws0[k * 128 + n] : Wn0[(k - 128) * 128 + n];
    unsigned short h, l; split2(wv, h, l);
    int si = idx ^ ((n & 7) << 3);
    wt0h[si] = h; wt0l[si] = l;
  } else if (idx < 65536) {
    int j = idx - 32768;
    int n = j >> 8, k = j & 255;
    float wv = (k < 128) ? Ws1[k * 128 + n] : Wn1[(k - 128) * 128 + n];
    unsigned short h, l; split2(wv, h, l);
    int si = j ^ ((n & 7) << 3);
    wt1h[si] = h; wt1l[si] = l;
  } else if (idx < 81920) {
    int j = idx - 65536;
    int n = j >> 7, k = j & 127;
    float wv = (n < 64) ? Ws2[k * 64 + n] : Wn2[k * 64 + (n - 64)];
    unsigned short h, l; split2(wv, h, l);
    int si = j ^ ((n & 7) << 3);
    wt2h[si] = h; wt2l[si] = l;
  } else if (idx < 82048) {
    int c = idx - 81920;
    b2ext[c] = (c < 64) ? b2[c] : 0.0f;
  }
}

// ================= gather-mean -> packed bf16 hi/lo (deep-MLP) =================
// 32 lanes per node, float4 per lane; 8-edge unrolled pipeline (8 outstanding
// 16B loads per lane) to cover L2/L3 latency. 8 nodes per block.
__global__ __launch_bounds__(256) void gather_split(const float* __restrict__ h,
                                                    const int* __restrict__ cursor,
                                                    const int* __restrict__ csr,
                                                    unsigned* __restrict__ meanPk) {
  const int n = blockIdx.x * 8 + (threadIdx.x >> 5);
  const int sl = threadIdx.x & 31;
  const int end = cursor[n];
  const int start = (n == 0) ? 0 : cursor[n - 1];
  const float4* hp = (const float4*)h + sl;  // row stride = 32 float4
  float4 acc = make_float4(0.f, 0.f, 0.f, 0.f);
  int e = start;
  for (; e + 7 < end; e += 8) {
    int s0 = csr[e],     s1 = csr[e + 1], s2 = csr[e + 2], s3 = csr[e + 3];
    int s4 = csr[e + 4], s5 = csr[e + 5], s6 = csr[e + 6], s7 = csr[e + 7];
    float4 v0 = hp[(size_t)s0 * 32];
    float4 v1 = hp[(size_t)s1 * 32];
    float4 v2 = hp[(size_t)s2 * 32];
    float4 v3 = hp[(size_t)s3 * 32];
    float4 v4 = hp[(size_t)s4 * 32];
    float4 v5 = hp[(size_t)s5 * 32];
    float4 v6 = hp[(size_t)s6 * 32];
    float4 v7 = hp[(size_t)s7 * 32];
    acc.x += ((v0.x + v1.x) + (v2.x + v3.x)) + ((v4.x + v5.x) + (v6.x + v7.x));
    acc.y += ((v0.y + v1.y) + (v2.y + v3.y)) + ((v4.y + v5.y) + (v6.y + v7.y));
    acc.z += ((v0.z + v1.z) + (v2.z + v3.z)) + ((v4.z + v5.z) + (v6.z + v7.z));
    acc.w += ((v0.w + v1.w) + (v2.w + v3.w)) + ((v4.w + v5.w) + (v6.w + v7.w));
  }
  if (e + 3 < end) {
    int s0 = csr[e], s1 = csr[e + 1], s2 = csr[e + 2], s3 = csr[e + 3];
    float4 v0 = hp[(size_t)s0 * 32];
    float4 v1 = hp[(size_t)s1 * 32];
    float4 v2 = hp[(size_t)s2 * 32];
    float4 v3 = hp[(size_t)s3 * 32];
    acc.x += (v0.x + v1.x) + (v2.x + v3.x);
    acc.y += (v0.y + v1.y) + (v2.y + v3.y);
    acc.z += (v0.z + v1.z) + (v2.z + v3.z);
    acc.w += (v0.w + v1.w) + (v2.w + v3.w);
    e += 4;
  }
  for (; e < end; ++e) {
    float4 v0 = hp[(size_t)csr[e] * 32];
    acc.x += v0.x; acc.y += v0.y; acc.z += v0.z; acc.w += v0.w;
  }
  float inv = 1.0f / (float)max(end - start, 1);
  acc.x *= inv; acc.y *= inv; acc.z *= inv; acc.w *= inv;
  unsigned short h0, l0, h1, l1, h2, l2, h3, l3;
  split2(acc.x, h0, l0);
  split2(acc.y, h1, l1);
  split2(acc.z, h2, l2);
  split2(acc.w, h3, l3);
  uint4 pk;
  pk.x = (unsigned)h0 | ((unsigned)l0 << 16);
  pk.y = (unsigned)h1 | ((unsigned)l1 << 16);
  pk.z = (unsigned)h2 | ((unsigned)l2 << 16);
  pk.w = (unsigned)h3 | ((unsigned)l3 << 16);
  *(uint4*)(meanPk + (size_t)n * D + sl * 4) = pk;
}

// ================= col-split MFMA GEMM: 64-row B panel in LDS =================
// Block = 64 rows x 64 cols. A slice issued BEFORE the stage barrier (flies
// during staging); inner loop is split -> ds_read -> MFMA only.
template <int QH, int QM, int ACT, int SPLIT>
__global__ __launch_bounds__(256, 2) void gemm_cs(const float* __restrict__ hsrc,
                                                  const unsigned* __restrict__ meanPk,
                                                  const unsigned short* __restrict__ wth,
                                                  const unsigned short* __restrict__ wtl,
                                                  const float* __restrict__ bias,
                                                  float* __restrict__ out0,
                                                  float* __restrict__ out1) {
  constexpr int NQ = QH + QM;
  constexpr int K = NQ * 64;
  __shared__ unsigned short bh_s[64 * K];
  __shared__ unsigned short bl_s[64 * K];

  const int tid = threadIdx.x;
  const int w = tid >> 6;
  const int l = tid & 63;
  const int lr = l & 15;
  const int lg = l >> 4;
  const int cb = blockIdx.y;  // column half
  const int row0 = blockIdx.x * 64;
  const int arow = min(row0 + w * 16 + lr, N_NODES - 1);

  // ---- issue the wave's full A slice first (16 uint4 for K=256) ----
  uint4 a[NQ * 4];
  {
    const uint4* hp = (const uint4*)(hsrc + (size_t)arow * D);
    const uint4* mp = (QM > 0) ? (const uint4*)(meanPk + (size_t)arow * D) : hp;
#pragma unroll
    for (int q = 0; q < NQ; ++q) {
      const uint4* base = (q < QH) ? (hp + q * 16) : (mp + (q - QH) * 16);
#pragma unroll
      for (int kt = 0; kt < 2; ++kt) {
        a[q * 4 + kt * 2 + 0] = base[kt * 8 + lg * 2];
        a[q * 4 + kt * 2 + 1] = base[kt * 8 + lg * 2 + 1];
      }
    }
  }

  // ---- stage this block's 64-row B panel (pre-swizzled, linear copy) ----
  {
    const uint4* gh = (const uint4*)(wth + (size_t)cb * 64 * K);
    const uint4* gl = (const uint4*)(wtl + (size_t)cb * 64 * K);
    uint4* sh = (uint4*)bh_s;
    uint4* sl = (uint4*)bl_s;
    constexpr int NU = 64 * K / 8;  // uint4 per panel
#pragma unroll
    for (int i = 0; i < NU / 256; ++i) {
      sh[tid + i * 256] = gh[tid + i * 256];
      sl[tid + i * 256] = gl[tid + i * 256];
    }
  }
  __syncthreads();

  f32x4 accA[4], accB[4];
#pragma unroll
  for (int i = 0; i < 4; ++i) {
    accA[i] = (f32x4){0.f, 0.f, 0.f, 0.f};
    accB[i] = (f32x4){0.f, 0.f, 0.f, 0.f};
  }

#pragma unroll
  for (int q = 0; q < NQ; ++q) {
#pragma unroll
    for (int kt = 0; kt < 2; ++kt) {
      U8 ah, al;
      if (q < QH) splitF(a[q * 4 + kt * 2], a[q * 4 + kt * 2 + 1], ah, al);
      else        splitP(a[q * 4 + kt * 2], a[q * 4 + kt * 2 + 1], ah, al);
      const int kb = q * 64 + (((((kt << 2) | lg)) ^ (lr & 7)) << 3);
#pragma unroll
      for (int nf = 0; nf < 4; ++nf) {
        const int si = (nf * 16 + lr) * K + kb;
        bf16x8 bh = *(const bf16x8*)&bh_s[si];
        bf16x8 bl = *(const bf16x8*)&bl_s[si];
        accA[nf] = __builtin_amdgcn_mfma_f32_16x16x32_bf16(ah.v, bh, accA[nf], 0, 0, 0);
        accB[nf] = __builtin_amdgcn_mfma_f32_16x16x32_bf16(al.v, bh, accB[nf], 0, 0, 0);
        accB[nf] = __builtin_amdgcn_mfma_f32_16x16x32_bf16(ah.v, bl, accB[nf], 0, 0, 0);
      }
    }
  }

  // epilogue: C col = cb*64 + nf*16 + lr, row = row0 + w*16 + lg*4 + i
#pragma unroll
  for (int nf = 0; nf < 4; ++nf) {
    const int col = cb * 64 + nf * 16 + lr;
    const float bv = bias[col];
#pragma unroll
    for (int i = 0; i < 4; ++i) {
      const int grow = row0 + w * 16 + lg * 4 + i;
      if (grow < N_NODES) {
        float v = accA[nf][i] + accB[nf][i] + bv;
        if (ACT) v = selu_f(v);
        if (SPLIT) {
          if (col < 64) out0[(size_t)grow * 64 + col] = v;
          else out1[(size_t)grow * 64 + (col - 64)] = v;
        } else {
          out0[(size_t)grow * D + col] = v;
        }
      }
    }
  }
}

// ================= fused gather(z) + add(u) + softmax =================
__global__ __launch_bounds__(256) void gather_sm(const float* __restrict__ zbuf,
                                                 const int* __restrict__ cursor,
                                                 const int* __restrict__ csr,
                                                 float* __restrict__ out) {
  const int n = blockIdx.x * 8 + (threadIdx.x >> 5);
  const int sl = threadIdx.x & 31;
  const int end = cursor[n];
  const int start = (n == 0) ? 0 : cursor[n - 1];
  const float* zp = zbuf + sl * 2;
  float ax = 0.f, ay = 0.f;
  int e = start;
  for (; e + 7 < end; e += 8) {
    int s0 = csr[e],     s1 = csr[e + 1], s2 = csr[e + 2], s3 = csr[e + 3];
    int s4 = csr[e + 4], s5 = csr[e + 5], s6 = csr[e + 6], s7 = csr[e + 7];
    float2 v0 = *(const float2*)(zp + (size_t)s0 * 64);
    float2 v1 = *(const float2*)(zp + (size_t)s1 * 64);
    float2 v2 = *(const float2*)(zp + (size_t)s2 * 64);
    float2 v3 = *(const float2*)(zp + (size_t)s3 * 64);
    float2 v4 = *(const float2*)(zp + (size_t)s4 * 64);
    float2 v5 = *(const float2*)(zp + (size_t)s5 * 64);
    float2 v6 = *(const float2*)(zp + (size_t)s6 * 64);
    float2 v7 = *(const float2*)(zp + (size_t)s7 * 64);
    ax += ((v0.x + v1.x) + (v2.x + v3.x)) + ((v4.x + v5.x) + (v6.x + v7.x));
    ay += ((v0.y + v1.y) + (v2.y + v3.y)) + ((v4.y + v5.y) + (v6.y + v7.y));
  }
  if (e + 3 < end) {
    int s0 = csr[e], s1 = csr[e + 1], s2 = csr[e + 2], s3 = csr[e + 3];
    float2 v0 = *(const float2*)(zp + (size_t)s0 * 64);
    float2 v1 = *(const float2*)(zp + (size_t)s1 * 64);
    float2 v2 = *(const float2*)(zp + (size_t)s2 * 64);
    float2 v3 = *(const float2*)(zp + (size_t)s3 * 64);
    ax += (v0.x + v1.x) + (v2.x + v3.x);
    ay += (v0.y + v1.y) + (v2.y + v3.y);
    e += 4;
  }
  for (; e < end; ++e) {
    float2 v0 = *(const float2*)(zp + (size_t)csr[e] * 64);
    ax += v0.x; ay += v0.y;
  }
  float inv = 1.0f / (float)max(end - start, 1);
  size_t o = (size_t)n * 64 + sl * 2;
  float vx = out[o] + ax * inv;
  float vy = out[o + 1] + ay * inv;
  float m = fmaxf(vx, vy);
#pragma unroll
  for (int off = 16; off > 0; off >>= 1) m = fmaxf(m, __shfl_xor(m, off, 64));
  float ex = expf(vx - m);
  float ey = expf(vy - m);
  float s = ex + ey;
#pragma unroll
  for (int off = 16; off > 0; off >>= 1) s += __shfl_xor(s, off, 64);
  float r = 1.0f / s;
  out[o] = ex * r;
  out[o + 1] = ey * r;
}

extern "C" void kernel_launch(void* const* d_in, const int* in_sizes, int n_in,
                              void* d_out, int out_size, void* d_ws, size_t ws_size,
                              hipStream_t stream) {
  const float* x   = (const float*)d_in[0];
  const int* src   = (const int*)d_in[1];
  const int* dst   = (const int*)d_in[2];
  const float* Ws0 = (const float*)d_in[3];
  const float* Wn0 = (const float*)d_in[4];
  const float* b0  = (const float*)d_in[5];
  const float* Ws1 = (const float*)d_in[6];
  const float* Wn1 = (const float*)d_in[7];
  const float* b1  = (const float*)d_in[8];
  const float* Ws2 = (const float*)d_in[9];
  const float* Wn2 = (const float*)d_in[10];
  const float* b2  = (const float*)d_in[11];
  float* out = (float*)d_out;

  // ws layout: cursor int[50048] | csr int[800000] | A=h1 25.6MB | B=h2 25.6MB | C 25.6MB
  char* ws = (char*)d_ws;
  int* cursor = (int*)ws;
  int* csr    = (int*)(ws + 200192);
  float* h1   = (float*)(ws + 3400192);
  float* h2   = (float*)(ws + 29000192);
  char* Creg  = ws + 54600192;
  unsigned* meanPk = (unsigned*)Creg;
  float* zbuf      = (float*)Creg;
  int* cnt         = (int*)Creg;
  int* bsum        = (int*)(Creg + N_NODES * sizeof(int));

  // split weights staged in d_out (12.8 MB; overwritten by layer-2 output later)
  unsigned short* W = (unsigned short*)d_out;
  unsigned short* wt0h = W;
  unsigned short* wt0l = W + 32768;
  unsigned short* wt1h = W + 65536;
  unsigned short* wt1l = W + 98304;
  unsigned short* wt2h = W + 131072;
  unsigned short* wt2l = W + 147456;
  float* b2ext = (float*)(W + 163840);

  // layer-2 weight copy target: A region (h1 is dead by then)
  unsigned short* wt2hc = (unsigned short*)h1;
  unsigned short* wt2lc = wt2hc + 16384;
  float* b2extc = (float*)(wt2hc + 32768);

  // CSR build (parallel 2-level scan)
  hipMemsetAsync(cnt, 0, N_NODES * sizeof(int), stream);
  hist_kernel<<<3125, 256, 0, stream>>>(dst, cnt);
  scan1_kernel<<<SCAN_B, 256, 0, stream>>>(cnt, cursor, bsum);
  scan2_kernel<<<1, 256, 0, stream>>>(bsum);
  scan3_kernel<<<SCAN_B, 256, 0, stream>>>(cursor, bsum);
  fill_kernel<<<3125, 256, 0, stream>>>(src, dst, cursor, csr);
  wsplit_kernel<<<321, 256, 0, stream>>>(Ws0, Wn0, Ws1, Wn1, Ws2, Wn2, b2,
                                         wt0h, wt0l, wt1h, wt1l, wt2h, wt2l, b2ext);

  // layer 0: x -> h1 (selu)
  gather_split<<<6250, 256, 0, stream>>>(x, cursor, csr, meanPk);
  gemm_cs<2, 2, 1, 0><<<dim3(NT_GEMM, 2), 256, 0, stream>>>(x, meanPk, wt0h, wt0l, b0, h1, nullptr);

  // layer 1: h1 -> h2 (selu)
  gather_split<<<6250, 256, 0, stream>>>(h1, cursor, csr, meanPk);
  gemm_cs<2, 2, 1, 0><<<dim3(NT_GEMM, 2), 256, 0, stream>>>(h1, meanPk, wt1h, wt1l, b1, h2, nullptr);

  // layer 2: u = h2@Ws2 + b2 -> out ; z = h2@Wn2 -> zbuf ; then mean(z) + u -> softmax
  hipMemcpyAsync(wt2hc, wt2h, 66048, hipMemcpyDeviceToDevice, stream);
  gemm_cs<2, 0, 0, 1><<<dim3(NT_GEMM, 2), 256, 0, stream>>>(h2, nullptr, wt2hc, wt2lc, b2extc, out, zbuf);
  gather_sm<<<6250, 256, 0, stream>>>(zbuf, cursor, csr, out);
}

// Round 10
// 291.013 us; speedup vs baseline: 1.6476x; 1.1844x over previous
//
#include <hip/hip_runtime.h>
#include <hip/hip_bf16.h>

#define N_NODES 50000
#define N_EDGES 800000
#define D 128
#define SCAN_B 196  // ceil(N_NODES/256)
#define NT_GEMM 782 // ceil(N_NODES/64)

typedef __attribute__((ext_vector_type(8))) __bf16 bf16x8;
typedef __attribute__((ext_vector_type(4))) float f32x4;

union U8 {
  bf16x8 v;
  uint4 u;
};

// ---- fp32 -> bf16 helpers ----
__device__ __forceinline__ unsigned short bf16_rne(float x) {
  unsigned u = __builtin_bit_cast(unsigned, x);
  unsigned r = u + 0x7fffu + ((u >> 16) & 1u);
  return (unsigned short)(r >> 16);
}
__device__ __forceinline__ float bf16_f(unsigned short b) {
  unsigned u = ((unsigned)b) << 16;
  return __builtin_bit_cast(float, u);
}
__device__ __forceinline__ void split2(float x, unsigned short& hi, unsigned short& lo) {
  hi = bf16_rne(x);
  lo = bf16_rne(x - bf16_f(hi));
}

__device__ __forceinline__ float selu_f(float x) {
  const float alpha = 1.6732632423543772f;
  const float scale = 1.0507009873554805f;
  return scale * (x > 0.0f ? x : alpha * expm1f(x));
}

// split raw fp32 bits (r0,r1 = 8 dwords) -> bf16 hi/lo fragments (trunc split)
__device__ __forceinline__ void splitF(uint4 r0, uint4 r1, U8& ah, U8& al) {
  unsigned u0 = r0.x, u1 = r0.y, u2 = r0.z, u3 = r0.w;
  unsigned u4 = r1.x, u5 = r1.y, u6 = r1.z, u7 = r1.w;
  ah.u.x = (u0 >> 16) | (u1 & 0xffff0000u);
  ah.u.y = (u2 >> 16) | (u3 & 0xffff0000u);
  ah.u.z = (u4 >> 16) | (u5 & 0xffff0000u);
  ah.u.w = (u6 >> 16) | (u7 & 0xffff0000u);
  unsigned r;
#define LOW(u) __builtin_bit_cast(unsigned, __builtin_bit_cast(float, u) - __builtin_bit_cast(float, u & 0xffff0000u))
  r = LOW(u0); al.u.x = r >> 16;
  r = LOW(u1); al.u.x |= r & 0xffff0000u;
  r = LOW(u2); al.u.y = r >> 16;
  r = LOW(u3); al.u.y |= r & 0xffff0000u;
  r = LOW(u4); al.u.z = r >> 16;
  r = LOW(u5); al.u.z |= r & 0xffff0000u;
  r = LOW(u6); al.u.w = r >> 16;
  r = LOW(u7); al.u.w |= r & 0xffff0000u;
#undef LOW
}

// ================= CSR build =================
__global__ __launch_bounds__(256) void hist_kernel(const int* __restrict__ dst,
                                                   int* __restrict__ cnt) {
  int e = blockIdx.x * 256 + threadIdx.x;
  if (e < N_EDGES) atomicAdd(&cnt[dst[e]], 1);
}

__global__ __launch_bounds__(256) void scan1_kernel(const int* __restrict__ cnt,
                                                    int* __restrict__ cursor,
                                                    int* __restrict__ bsum) {
  __shared__ int s[256];
  const int t = threadIdx.x;
  const int i = blockIdx.x * 256 + t;
  int v = (i < N_NODES) ? cnt[i] : 0;
  s[t] = v;
  __syncthreads();
#pragma unroll
  for (int off = 1; off < 256; off <<= 1) {
    int u = (t >= off) ? s[t - off] : 0;
    __syncthreads();
    s[t] += u;
    __syncthreads();
  }
  if (i < N_NODES) cursor[i] = s[t] - v;
  if (t == 255) bsum[blockIdx.x] = s[255];
}

__global__ __launch_bounds__(256) void scan2_kernel(int* __restrict__ bsum) {
  __shared__ int s[256];
  const int t = threadIdx.x;
  int v = (t < SCAN_B) ? bsum[t] : 0;
  s[t] = v;
  __syncthreads();
#pragma unroll
  for (int off = 1; off < 256; off <<= 1) {
    int u = (t >= off) ? s[t - off] : 0;
    __syncthreads();
    s[t] += u;
    __syncthreads();
  }
  if (t < SCAN_B) bsum[t] = s[t] - v;
}

__global__ __launch_bounds__(256) void scan3_kernel(int* __restrict__ cursor,
                                                    const int* __restrict__ bsum) {
  const int i = blockIdx.x * 256 + threadIdx.x;
  if (i < N_NODES) cursor[i] += bsum[blockIdx.x];
}

__global__ __launch_bounds__(256) void fill_kernel(const int* __restrict__ src,
                                                   const int* __restrict__ dst,
                                                   int* __restrict__ cursor,
                                                   int* __restrict__ csr_src) {
  int e = blockIdx.x * 256 + threadIdx.x;
  if (e < N_EDGES) {
    int pos = atomicAdd(&cursor[dst[e]], 1);
    csr_src[pos] = src[e];
  }
}

// ================= weight split/transpose precompute =================
// Per-layer B image for gemm_dual, K=128, pre-swizzled (si = idx ^ ((n&7)<<3)).
// Layers 0/1: n in [0,256): n<128 -> Ws col n, n>=128 -> Wn col n-128.
// Layer 2:    n in [0,128): n<64  -> Ws2 col n, n>=64  -> Wn2 col n-64.
__global__ __launch_bounds__(256) void wsplit_kernel(
    const float* __restrict__ Ws0, const float* __restrict__ Wn0,
    const float* __restrict__ Ws1, const float* __restrict__ Wn1,
    const float* __restrict__ Ws2, const float* __restrict__ Wn2,
    unsigned short* __restrict__ wb) {
  int idx = blockIdx.x * 256 + threadIdx.x;
  if (idx < 32768) {
    int n = idx >> 7, k = idx & 127;
    float wv = (n < 128) ? Ws0[k * 128 + n] : Wn0[k * 128 + (n - 128)];
    unsigned short h, l; split2(wv, h, l);
    int si = idx ^ ((n & 7) << 3);
    wb[si] = h; wb[32768 + si] = l;
  } else if (idx < 65536) {
    int j = idx - 32768;
    int n = j >> 7, k = j & 127;
    float wv = (n < 128) ? Ws1[k * 128 + n] : Wn1[k * 128 + (n - 128)];
    unsigned short h, l; split2(wv, h, l);
    int si = j ^ ((n & 7) << 3);
    wb[65536 + si] = h; wb[98304 + si] = l;
  } else if (idx < 81920) {
    int j = idx - 65536;
    int n = j >> 7, k = j & 127;
    float wv = (n < 64) ? Ws2[k * 64 + n] : Wn2[k * 64 + (n - 64)];
    unsigned short h, l; split2(wv, h, l);
    int si = j ^ ((n & 7) << 3);
    wb[131072 + si] = h; wb[147456 + si] = l;
  }
}

// ================= dual-output MFMA GEMM (K=128, B panel in LDS) =================
// Block = 64 rows x 64 cols (col-block cb). cb < ZCB: fp32 self/u (+bias) to out0.
// cb >= ZCB: bf16 z to out1. A slice issued before the stage barrier.
template <int NCB, int ZCB>
__global__ __launch_bounds__(256, 2) void gemm_dual(const float* __restrict__ hsrc,
                                                    const unsigned short* __restrict__ wth,
                                                    const unsigned short* __restrict__ wtl,
                                                    const float* __restrict__ bias,
                                                    float* __restrict__ out0,
                                                    unsigned short* __restrict__ out1) {
  constexpr int K = 128;
  __shared__ unsigned short bh_s[64 * K];
  __shared__ unsigned short bl_s[64 * K];

  const int tid = threadIdx.x;
  const int w = tid >> 6;
  const int l = tid & 63;
  const int lr = l & 15;
  const int lg = l >> 4;
  const int cb = blockIdx.y;
  const int row0 = blockIdx.x * 64;
  const int arow = min(row0 + w * 16 + lr, N_NODES - 1);

  // ---- issue the wave's full A slice first (8 uint4, K=128) ----
  uint4 a[8];
  {
    const uint4* hp = (const uint4*)(hsrc + (size_t)arow * D);
#pragma unroll
    for (int q = 0; q < 2; ++q)
#pragma unroll
      for (int kt = 0; kt < 2; ++kt) {
        a[q * 4 + kt * 2 + 0] = hp[q * 16 + kt * 8 + lg * 2];
        a[q * 4 + kt * 2 + 1] = hp[q * 16 + kt * 8 + lg * 2 + 1];
      }
  }

  // ---- stage this block's 64-col B panel (pre-swizzled, linear copy) ----
  {
    const uint4* gh = (const uint4*)(wth + (size_t)cb * 64 * K);
    const uint4* gl = (const uint4*)(wtl + (size_t)cb * 64 * K);
    uint4* sh = (uint4*)bh_s;
    uint4* sl = (uint4*)bl_s;
#pragma unroll
    for (int i = 0; i < 4; ++i) {
      sh[tid + i * 256] = gh[tid + i * 256];
      sl[tid + i * 256] = gl[tid + i * 256];
    }
  }
  __syncthreads();

  f32x4 accA[4], accB[4];
#pragma unroll
  for (int i = 0; i < 4; ++i) {
    accA[i] = (f32x4){0.f, 0.f, 0.f, 0.f};
    accB[i] = (f32x4){0.f, 0.f, 0.f, 0.f};
  }

#pragma unroll
  for (int q = 0; q < 2; ++q) {
#pragma unroll
    for (int kt = 0; kt < 2; ++kt) {
      U8 ah, al;
      splitF(a[q * 4 + kt * 2], a[q * 4 + kt * 2 + 1], ah, al);
      const int kb = q * 64 + (((((kt << 2) | lg)) ^ (lr & 7)) << 3);
#pragma unroll
      for (int nf = 0; nf < 4; ++nf) {
        const int si = (nf * 16 + lr) * K + kb;
        bf16x8 bh = *(const bf16x8*)&bh_s[si];
        bf16x8 bl = *(const bf16x8*)&bl_s[si];
        accA[nf] = __builtin_amdgcn_mfma_f32_16x16x32_bf16(ah.v, bh, accA[nf], 0, 0, 0);
        accB[nf] = __builtin_amdgcn_mfma_f32_16x16x32_bf16(al.v, bh, accB[nf], 0, 0, 0);
        accB[nf] = __builtin_amdgcn_mfma_f32_16x16x32_bf16(ah.v, bl, accB[nf], 0, 0, 0);
      }
    }
  }

  // epilogue
#pragma unroll
  for (int nf = 0; nf < 4; ++nf) {
    const int col = cb * 64 + nf * 16 + lr;
#pragma unroll
    for (int i = 0; i < 4; ++i) {
      const int grow = row0 + w * 16 + lg * 4 + i;
      if (grow < N_NODES) {
        float v = accA[nf][i] + accB[nf][i];
        if (cb < ZCB) {
          out0[(size_t)grow * (ZCB * 64) + col] = v + bias[col];
        } else {
          out1[(size_t)grow * ((NCB - ZCB) * 64) + (col - ZCB * 64)] = bf16_rne(v);
        }
      }
    }
  }
}

// ================= gather mean(z bf16) + self + SELU -> h_next =================
// 32 lanes per node, ushort4 (8B, 4 bf16) per lane; 8-edge deep pipeline.
__global__ __launch_bounds__(256) void gather_act(const unsigned short* __restrict__ zb,
                                                  const float* __restrict__ selfb,
                                                  const int* __restrict__ cursor,
                                                  const int* __restrict__ csr,
                                                  float* __restrict__ hnext) {
  const int n = blockIdx.x * 8 + (threadIdx.x >> 5);
  const int sl = threadIdx.x & 31;
  const int end = cursor[n];
  const int start = (n == 0) ? 0 : cursor[n - 1];
  const ushort4* zp = (const ushort4*)zb + sl;  // row stride = 32 ushort4
  float ax = 0.f, ay = 0.f, az = 0.f, aw = 0.f;
#define ACC4(v) { ax += bf16_f(v.x); ay += bf16_f(v.y); az += bf16_f(v.z); aw += bf16_f(v.w); }
  int e = start;
  for (; e + 7 < end; e += 8) {
    int s0 = csr[e],     s1 = csr[e + 1], s2 = csr[e + 2], s3 = csr[e + 3];
    int s4 = csr[e + 4], s5 = csr[e + 5], s6 = csr[e + 6], s7 = csr[e + 7];
    ushort4 v0 = zp[(size_t)s0 * 32];
    ushort4 v1 = zp[(size_t)s1 * 32];
    ushort4 v2 = zp[(size_t)s2 * 32];
    ushort4 v3 = zp[(size_t)s3 * 32];
    ushort4 v4 = zp[(size_t)s4 * 32];
    ushort4 v5 = zp[(size_t)s5 * 32];
    ushort4 v6 = zp[(size_t)s6 * 32];
    ushort4 v7 = zp[(size_t)s7 * 32];
    ACC4(v0) ACC4(v1) ACC4(v2) ACC4(v3) ACC4(v4) ACC4(v5) ACC4(v6) ACC4(v7)
  }
  if (e + 3 < end) {
    int s0 = csr[e], s1 = csr[e + 1], s2 = csr[e + 2], s3 = csr[e + 3];
    ushort4 v0 = zp[(size_t)s0 * 32];
    ushort4 v1 = zp[(size_t)s1 * 32];
    ushort4 v2 = zp[(size_t)s2 * 32];
    ushort4 v3 = zp[(size_t)s3 * 32];
    ACC4(v0) ACC4(v1) ACC4(v2) ACC4(v3)
    e += 4;
  }
  for (; e < end; ++e) {
    ushort4 v0 = zp[(size_t)csr[e] * 32];
    ACC4(v0)
  }
#undef ACC4
  float inv = 1.0f / (float)max(end - start, 1);
  float4 sv = *(const float4*)(selfb + (size_t)n * D + sl * 4);
  float4 o;
  o.x = selu_f(sv.x + ax * inv);
  o.y = selu_f(sv.y + ay * inv);
  o.z = selu_f(sv.z + az * inv);
  o.w = selu_f(sv.w + aw * inv);
  *(float4*)(hnext + (size_t)n * D + sl * 4) = o;
}

// ================= gather mean(z2 bf16) + u + softmax -> out =================
__global__ __launch_bounds__(256) void gather_sm(const unsigned short* __restrict__ z2,
                                                 const float* __restrict__ u,
                                                 const int* __restrict__ cursor,
                                                 const int* __restrict__ csr,
                                                 float* __restrict__ out) {
  const int n = blockIdx.x * 8 + (threadIdx.x >> 5);
  const int sl = threadIdx.x & 31;
  const int end = cursor[n];
  const int start = (n == 0) ? 0 : cursor[n - 1];
  const ushort2* zp = (const ushort2*)z2 + sl;  // row stride = 32 ushort2
  float ax = 0.f, ay = 0.f;
#define ACC2(v) { ax += bf16_f(v.x); ay += bf16_f(v.y); }
  int e = start;
  for (; e + 7 < end; e += 8) {
    int s0 = csr[e],     s1 = csr[e + 1], s2 = csr[e + 2], s3 = csr[e + 3];
    int s4 = csr[e + 4], s5 = csr[e + 5], s6 = csr[e + 6], s7 = csr[e + 7];
    ushort2 v0 = zp[(size_t)s0 * 32];
    ushort2 v1 = zp[(size_t)s1 * 32];
    ushort2 v2 = zp[(size_t)s2 * 32];
    ushort2 v3 = zp[(size_t)s3 * 32];
    ushort2 v4 = zp[(size_t)s4 * 32];
    ushort2 v5 = zp[(size_t)s5 * 32];
    ushort2 v6 = zp[(size_t)s6 * 32];
    ushort2 v7 = zp[(size_t)s7 * 32];
    ACC2(v0) ACC2(v1) ACC2(v2) ACC2(v3) ACC2(v4) ACC2(v5) ACC2(v6) ACC2(v7)
  }
  if (e + 3 < end) {
    int s0 = csr[e], s1 = csr[e + 1], s2 = csr[e + 2], s3 = csr[e + 3];
    ushort2 v0 = zp[(size_t)s0 * 32];
    ushort2 v1 = zp[(size_t)s1 * 32];
    ushort2 v2 = zp[(size_t)s2 * 32];
    ushort2 v3 = zp[(size_t)s3 * 32];
    ACC2(v0) ACC2(v1) ACC2(v2) ACC2(v3)
    e += 4;
  }
  for (; e < end; ++e) {
    ushort2 v0 = zp[(size_t)csr[e] * 32];
    ACC2(v0)
  }
#undef ACC2
  float inv = 1.0f / (float)max(end - start, 1);
  size_t o = (size_t)n * 64 + sl * 2;
  float vx = u[o] + ax * inv;
  float vy = u[o + 1] + ay * inv;
  float m = fmaxf(vx, vy);
#pragma unroll
  for (int off = 16; off > 0; off >>= 1) m = fmaxf(m, __shfl_xor(m, off, 64));
  float ex = expf(vx - m);
  float ey = expf(vy - m);
  float s = ex + ey;
#pragma unroll
  for (int off = 16; off > 0; off >>= 1) s += __shfl_xor(s, off, 64);
  float r = 1.0f / s;
  out[o] = ex * r;
  out[o + 1] = ey * r;
}

extern "C" void kernel_launch(void* const* d_in, const int* in_sizes, int n_in,
                              void* d_out, int out_size, void* d_ws, size_t ws_size,
                              hipStream_t stream) {
  const float* x   = (const float*)d_in[0];
  const int* src   = (const int*)d_in[1];
  const int* dst   = (const int*)d_in[2];
  const float* Ws0 = (const float*)d_in[3];
  const float* Wn0 = (const float*)d_in[4];
  const float* b0  = (const float*)d_in[5];
  const float* Ws1 = (const float*)d_in[6];
  const float* Wn1 = (const float*)d_in[7];
  const float* b1  = (const float*)d_in[8];
  const float* Ws2 = (const float*)d_in[9];
  const float* Wn2 = (const float*)d_in[10];
  const float* b2  = (const float*)d_in[11];
  float* out = (float*)d_out;

  // ws layout (80.6 MB, within proven footprint):
  //   cursor int[50048] | csr int[800000] | h1 25.6MB | h2 25.6MB | C 25.6MB
  // h2 region head additionally holds split weights until layer-1 gather
  // clobbers it (wt2 copied to dead h1 just before).
  // C region: cnt/bsum (CSR build) -> selfb/u + z2.
  char* ws = (char*)d_ws;
  int* cursor = (int*)ws;
  int* csr    = (int*)(ws + 200192);
  float* h1   = (float*)(ws + 3400192);
  float* h2   = (float*)(ws + 29000192);
  char* Creg  = ws + 54600192;
  float* selfb = (float*)Creg;                              // self / u
  unsigned short* z2 = (unsigned short*)(Creg + 12800000);  // layer-2 z (6.4MB)
  int* cnt  = (int*)Creg;
  int* bsum = (int*)(Creg + 200192);

  // z for layers 0/1 lives in d_out (12.8 MB exactly; dead before final write)
  unsigned short* zb = (unsigned short*)d_out;

  // split weights staged at h2 base (328 KB)
  unsigned short* wb = (unsigned short*)h2;
  unsigned short* wt0h = wb;
  unsigned short* wt0l = wb + 32768;
  unsigned short* wt1h = wb + 65536;
  unsigned short* wt1l = wb + 98304;
  unsigned short* wt2h = wb + 131072;
  unsigned short* wt2l = wb + 147456;

  // layer-2 weight copy target: h1 base (h1 dead after layer-1 gemm reads it)
  unsigned short* wt2hc = (unsigned short*)h1;
  unsigned short* wt2lc = wt2hc + 16384;

  // CSR build (parallel 2-level scan)
  hipMemsetAsync(cnt, 0, N_NODES * sizeof(int), stream);
  hist_kernel<<<3125, 256, 0, stream>>>(dst, cnt);
  scan1_kernel<<<SCAN_B, 256, 0, stream>>>(cnt, cursor, bsum);
  scan2_kernel<<<1, 256, 0, stream>>>(bsum);
  scan3_kernel<<<SCAN_B, 256, 0, stream>>>(cursor, bsum);
  fill_kernel<<<3125, 256, 0, stream>>>(src, dst, cursor, csr);
  wsplit_kernel<<<320, 256, 0, stream>>>(Ws0, Wn0, Ws1, Wn1, Ws2, Wn2, wb);

  // layer 0: self = x@Ws0 + b0 ; z = x@Wn0 (bf16) ; h1 = selu(self + mean(z))
  gemm_dual<4, 2><<<dim3(NT_GEMM, 4), 256, 0, stream>>>(x, wt0h, wt0l, b0, selfb, zb);
  gather_act<<<6250, 256, 0, stream>>>(zb, selfb, cursor, csr, h1);

  // layer 1: same with h1 -> h2
  gemm_dual<4, 2><<<dim3(NT_GEMM, 4), 256, 0, stream>>>(h1, wt1h, wt1l, b1, selfb, zb);
  hipMemcpyAsync(wt2hc, wt2h, 65536, hipMemcpyDeviceToDevice, stream);  // h1 dead now
  gather_act<<<6250, 256, 0, stream>>>(zb, selfb, cursor, csr, h2);     // clobbers wb

  // layer 2: u = h2@Ws2 + b2 ; z2 = h2@Wn2 (bf16) ; out = softmax(u + mean(z2))
  gemm_dual<2, 1><<<dim3(NT_GEMM, 2), 256, 0, stream>>>(h2, wt2hc, wt2lc, b2, selfb, z2);
  gather_sm<<<6250, 256, 0, stream>>>(z2, selfb, cursor, csr, out);
}

// Round 11
// 279.806 us; speedup vs baseline: 1.7136x; 1.0401x over previous
//
#include <hip/hip_runtime.h>
#include <hip/hip_bf16.h>

#define N_NODES 50000
#define N_EDGES 800000
#define D 128
#define SCAN_B 196  // ceil(N_NODES/256)
#define NT_GEMM 782 // ceil(N_NODES/64)
#define E_CHUNK 2048
#define FILL_CH 391 // ceil(N_EDGES/E_CHUNK)

typedef __attribute__((ext_vector_type(8))) __bf16 bf16x8;
typedef __attribute__((ext_vector_type(4))) float f32x4;

union U8 {
  bf16x8 v;
  uint4 u;
};

// ---- fp32 -> bf16 helpers ----
__device__ __forceinline__ unsigned short bf16_rne(float x) {
  unsigned u = __builtin_bit_cast(unsigned, x);
  unsigned r = u + 0x7fffu + ((u >> 16) & 1u);
  return (unsigned short)(r >> 16);
}
__device__ __forceinline__ float bf16_f(unsigned short b) {
  unsigned u = ((unsigned)b) << 16;
  return __builtin_bit_cast(float, u);
}
__device__ __forceinline__ void split2(float x, unsigned short& hi, unsigned short& lo) {
  hi = bf16_rne(x);
  lo = bf16_rne(x - bf16_f(hi));
}

__device__ __forceinline__ float selu_f(float x) {
  const float alpha = 1.6732632423543772f;
  const float scale = 1.0507009873554805f;
  return scale * (x > 0.0f ? x : alpha * expm1f(x));
}

// split raw fp32 bits (r0,r1 = 8 dwords) -> bf16 hi/lo fragments (trunc split)
__device__ __forceinline__ void splitF(uint4 r0, uint4 r1, U8& ah, U8& al) {
  unsigned u0 = r0.x, u1 = r0.y, u2 = r0.z, u3 = r0.w;
  unsigned u4 = r1.x, u5 = r1.y, u6 = r1.z, u7 = r1.w;
  ah.u.x = (u0 >> 16) | (u1 & 0xffff0000u);
  ah.u.y = (u2 >> 16) | (u3 & 0xffff0000u);
  ah.u.z = (u4 >> 16) | (u5 & 0xffff0000u);
  ah.u.w = (u6 >> 16) | (u7 & 0xffff0000u);
  unsigned r;
#define LOW(u) __builtin_bit_cast(unsigned, __builtin_bit_cast(float, u) - __builtin_bit_cast(float, u & 0xffff0000u))
  r = LOW(u0); al.u.x = r >> 16;
  r = LOW(u1); al.u.x |= r & 0xffff0000u;
  r = LOW(u2); al.u.y = r >> 16;
  r = LOW(u3); al.u.y |= r & 0xffff0000u;
  r = LOW(u4); al.u.z = r >> 16;
  r = LOW(u5); al.u.z |= r & 0xffff0000u;
  r = LOW(u6); al.u.w = r >> 16;
  r = LOW(u7); al.u.w |= r & 0xffff0000u;
#undef LOW
}

// ================= CSR build (XCD-class-partitioned) =================
// class = (dst>>4)&7 -> 16-node stripes = one 64B cursor line per stripe.
// Block bid: chunk = bid>>3, class = bid&7 (flat%8 ~ XCD round-robin).
__global__ __launch_bounds__(256) void hist_kernel(const int* __restrict__ dst,
                                                   int* __restrict__ cnt) {
  const int cls = blockIdx.x & 7;
  const int base = (blockIdx.x >> 3) * E_CHUNK + threadIdx.x;
#pragma unroll
  for (int i = 0; i < E_CHUNK / 256; ++i) {
    int e = base + i * 256;
    if (e < N_EDGES) {
      int d = dst[e];
      if (((d >> 4) & 7) == cls) atomicAdd(&cnt[d], 1);
    }
  }
}

__global__ __launch_bounds__(256) void scan1_kernel(const int* __restrict__ cnt,
                                                    int* __restrict__ cursor,
                                                    int* __restrict__ bsum) {
  __shared__ int s[256];
  const int t = threadIdx.x;
  const int i = blockIdx.x * 256 + t;
  int v = (i < N_NODES) ? cnt[i] : 0;
  s[t] = v;
  __syncthreads();
#pragma unroll
  for (int off = 1; off < 256; off <<= 1) {
    int u = (t >= off) ? s[t - off] : 0;
    __syncthreads();
    s[t] += u;
    __syncthreads();
  }
  if (i < N_NODES) cursor[i] = s[t] - v;
  if (t == 255) bsum[blockIdx.x] = s[255];
}

__global__ __launch_bounds__(256) void scan2_kernel(int* __restrict__ bsum) {
  __shared__ int s[256];
  const int t = threadIdx.x;
  int v = (t < SCAN_B) ? bsum[t] : 0;
  s[t] = v;
  __syncthreads();
#pragma unroll
  for (int off = 1; off < 256; off <<= 1) {
    int u = (t >= off) ? s[t - off] : 0;
    __syncthreads();
    s[t] += u;
    __syncthreads();
  }
  if (t < SCAN_B) bsum[t] = s[t] - v;
}

__global__ __launch_bounds__(256) void scan3_kernel(int* __restrict__ cursor,
                                                    const int* __restrict__ bsum) {
  const int i = blockIdx.x * 256 + threadIdx.x;
  if (i < N_NODES) cursor[i] += bsum[blockIdx.x];
}

__global__ __launch_bounds__(256) void fill_kernel(const int* __restrict__ src,
                                                   const int* __restrict__ dst,
                                                   int* __restrict__ cursor,
                                                   int* __restrict__ csr_src) {
  const int cls = blockIdx.x & 7;
  const int base = (blockIdx.x >> 3) * E_CHUNK + threadIdx.x;
#pragma unroll
  for (int i = 0; i < E_CHUNK / 256; ++i) {
    int e = base + i * 256;
    if (e < N_EDGES) {
      int d = dst[e];
      if (((d >> 4) & 7) == cls) {
        int pos = atomicAdd(&cursor[d], 1);
        csr_src[pos] = src[e];
      }
    }
  }
}

// ================= weight split/transpose precompute =================
// Per-layer B image for gemm_dual, K=128, pre-swizzled (si = idx ^ ((n&7)<<3)).
__global__ __launch_bounds__(256) void wsplit_kernel(
    const float* __restrict__ Ws0, const float* __restrict__ Wn0,
    const float* __restrict__ Ws1, const float* __restrict__ Wn1,
    const float* __restrict__ Ws2, const float* __restrict__ Wn2,
    unsigned short* __restrict__ wb) {
  int idx = blockIdx.x * 256 + threadIdx.x;
  if (idx < 32768) {
    int n = idx >> 7, k = idx & 127;
    float wv = (n < 128) ? Ws0[k * 128 + n] : Wn0[k * 128 + (n - 128)];
    unsigned short h, l; split2(wv, h, l);
    int si = idx ^ ((n & 7) << 3);
    wb[si] = h; wb[32768 + si] = l;
  } else if (idx < 65536) {
    int j = idx - 32768;
    int n = j >> 7, k = j & 127;
    float wv = (n < 128) ? Ws1[k * 128 + n] : Wn1[k * 128 + (n - 128)];
    unsigned short h, l; split2(wv, h, l);
    int si = j ^ ((n & 7) << 3);
    wb[65536 + si] = h; wb[98304 + si] = l;
  } else if (idx < 81920) {
    int j = idx - 65536;
    int n = j >> 7, k = j & 127;
    float wv = (n < 64) ? Ws2[k * 64 + n] : Wn2[k * 64 + (n - 64)];
    unsigned short h, l; split2(wv, h, l);
    int si = j ^ ((n & 7) << 3);
    wb[131072 + si] = h; wb[147456 + si] = l;
  }
}

// ================= dual-output MFMA GEMM (K=128, B panel in LDS) =================
template <int NCB, int ZCB>
__global__ __launch_bounds__(256, 2) void gemm_dual(const float* __restrict__ hsrc,
                                                    const unsigned short* __restrict__ wth,
                                                    const unsigned short* __restrict__ wtl,
                                                    const float* __restrict__ bias,
                                                    float* __restrict__ out0,
                                                    unsigned short* __restrict__ out1) {
  constexpr int K = 128;
  __shared__ unsigned short bh_s[64 * K];
  __shared__ unsigned short bl_s[64 * K];

  const int tid = threadIdx.x;
  const int w = tid >> 6;
  const int l = tid & 63;
  const int lr = l & 15;
  const int lg = l >> 4;
  const int cb = blockIdx.y;
  const int row0 = blockIdx.x * 64;
  const int arow = min(row0 + w * 16 + lr, N_NODES - 1);

  // ---- issue the wave's full A slice first (8 uint4, K=128) ----
  uint4 a[8];
  {
    const uint4* hp = (const uint4*)(hsrc + (size_t)arow * D);
#pragma unroll
    for (int q = 0; q < 2; ++q)
#pragma unroll
      for (int kt = 0; kt < 2; ++kt) {
        a[q * 4 + kt * 2 + 0] = hp[q * 16 + kt * 8 + lg * 2];
        a[q * 4 + kt * 2 + 1] = hp[q * 16 + kt * 8 + lg * 2 + 1];
      }
  }

  // ---- stage this block's 64-col B panel (pre-swizzled, linear copy) ----
  {
    const uint4* gh = (const uint4*)(wth + (size_t)cb * 64 * K);
    const uint4* gl = (const uint4*)(wtl + (size_t)cb * 64 * K);
    uint4* sh = (uint4*)bh_s;
    uint4* sl = (uint4*)bl_s;
#pragma unroll
    for (int i = 0; i < 4; ++i) {
      sh[tid + i * 256] = gh[tid + i * 256];
      sl[tid + i * 256] = gl[tid + i * 256];
    }
  }
  __syncthreads();

  f32x4 accA[4], accB[4];
#pragma unroll
  for (int i = 0; i < 4; ++i) {
    accA[i] = (f32x4){0.f, 0.f, 0.f, 0.f};
    accB[i] = (f32x4){0.f, 0.f, 0.f, 0.f};
  }

#pragma unroll
  for (int q = 0; q < 2; ++q) {
#pragma unroll
    for (int kt = 0; kt < 2; ++kt) {
      U8 ah, al;
      splitF(a[q * 4 + kt * 2], a[q * 4 + kt * 2 + 1], ah, al);
      const int kb = q * 64 + (((((kt << 2) | lg)) ^ (lr & 7)) << 3);
#pragma unroll
      for (int nf = 0; nf < 4; ++nf) {
        const int si = (nf * 16 + lr) * K + kb;
        bf16x8 bh = *(const bf16x8*)&bh_s[si];
        bf16x8 bl = *(const bf16x8*)&bl_s[si];
        accA[nf] = __builtin_amdgcn_mfma_f32_16x16x32_bf16(ah.v, bh, accA[nf], 0, 0, 0);
        accB[nf] = __builtin_amdgcn_mfma_f32_16x16x32_bf16(al.v, bh, accB[nf], 0, 0, 0);
        accB[nf] = __builtin_amdgcn_mfma_f32_16x16x32_bf16(ah.v, bl, accB[nf], 0, 0, 0);
      }
    }
  }

  // epilogue
#pragma unroll
  for (int nf = 0; nf < 4; ++nf) {
    const int col = cb * 64 + nf * 16 + lr;
#pragma unroll
    for (int i = 0; i < 4; ++i) {
      const int grow = row0 + w * 16 + lg * 4 + i;
      if (grow < N_NODES) {
        float v = accA[nf][i] + accB[nf][i];
        if (cb < ZCB) {
          out0[(size_t)grow * (ZCB * 64) + col] = v + bias[col];
        } else {
          out1[(size_t)grow * ((NCB - ZCB) * 64) + (col - ZCB * 64)] = bf16_rne(v);
        }
      }
    }
  }
}

// ================= gather mean(z bf16) + self + SELU -> h_next =================
__global__ __launch_bounds__(256) void gather_act(const unsigned short* __restrict__ zb,
                                                  const float* __restrict__ selfb,
                                                  const int* __restrict__ cursor,
                                                  const int* __restrict__ csr,
                                                  float* __restrict__ hnext) {
  const int n = blockIdx.x * 8 + (threadIdx.x >> 5);
  const int sl = threadIdx.x & 31;
  const int end = cursor[n];
  const int start = (n == 0) ? 0 : cursor[n - 1];
  const ushort4* zp = (const ushort4*)zb + sl;  // row stride = 32 ushort4
  float ax = 0.f, ay = 0.f, az = 0.f, aw = 0.f;
#define ACC4(v) { ax += bf16_f(v.x); ay += bf16_f(v.y); az += bf16_f(v.z); aw += bf16_f(v.w); }
  int e = start;
  for (; e + 7 < end; e += 8) {
    int s0 = csr[e],     s1 = csr[e + 1], s2 = csr[e + 2], s3 = csr[e + 3];
    int s4 = csr[e + 4], s5 = csr[e + 5], s6 = csr[e + 6], s7 = csr[e + 7];
    ushort4 v0 = zp[(size_t)s0 * 32];
    ushort4 v1 = zp[(size_t)s1 * 32];
    ushort4 v2 = zp[(size_t)s2 * 32];
    ushort4 v3 = zp[(size_t)s3 * 32];
    ushort4 v4 = zp[(size_t)s4 * 32];
    ushort4 v5 = zp[(size_t)s5 * 32];
    ushort4 v6 = zp[(size_t)s6 * 32];
    ushort4 v7 = zp[(size_t)s7 * 32];
    ACC4(v0) ACC4(v1) ACC4(v2) ACC4(v3) ACC4(v4) ACC4(v5) ACC4(v6) ACC4(v7)
  }
  if (e + 3 < end) {
    int s0 = csr[e], s1 = csr[e + 1], s2 = csr[e + 2], s3 = csr[e + 3];
    ushort4 v0 = zp[(size_t)s0 * 32];
    ushort4 v1 = zp[(size_t)s1 * 32];
    ushort4 v2 = zp[(size_t)s2 * 32];
    ushort4 v3 = zp[(size_t)s3 * 32];
    ACC4(v0) ACC4(v1) ACC4(v2) ACC4(v3)
    e += 4;
  }
  for (; e < end; ++e) {
    ushort4 v0 = zp[(size_t)csr[e] * 32];
    ACC4(v0)
  }
#undef ACC4
  float inv = 1.0f / (float)max(end - start, 1);
  float4 sv = *(const float4*)(selfb + (size_t)n * D + sl * 4);
  float4 o;
  o.x = selu_f(sv.x + ax * inv);
  o.y = selu_f(sv.y + ay * inv);
  o.z = selu_f(sv.z + az * inv);
  o.w = selu_f(sv.w + aw * inv);
  *(float4*)(hnext + (size_t)n * D + sl * 4) = o;
}

// ================= gather mean(z2 bf16) + u + softmax -> out =================
__global__ __launch_bounds__(256) void gather_sm(const unsigned short* __restrict__ z2,
                                                 const float* __restrict__ u,
                                                 const int* __restrict__ cursor,
                                                 const int* __restrict__ csr,
                                                 float* __restrict__ out) {
  const int n = blockIdx.x * 8 + (threadIdx.x >> 5);
  const int sl = threadIdx.x & 31;
  const int end = cursor[n];
  const int start = (n == 0) ? 0 : cursor[n - 1];
  const ushort2* zp = (const ushort2*)z2 + sl;  // row stride = 32 ushort2
  float ax = 0.f, ay = 0.f;
#define ACC2(v) { ax += bf16_f(v.x); ay += bf16_f(v.y); }
  int e = start;
  for (; e + 7 < end; e += 8) {
    int s0 = csr[e],     s1 = csr[e + 1], s2 = csr[e + 2], s3 = csr[e + 3];
    int s4 = csr[e + 4], s5 = csr[e + 5], s6 = csr[e + 6], s7 = csr[e + 7];
    ushort2 v0 = zp[(size_t)s0 * 32];
    ushort2 v1 = zp[(size_t)s1 * 32];
    ushort2 v2 = zp[(size_t)s2 * 32];
    ushort2 v3 = zp[(size_t)s3 * 32];
    ushort2 v4 = zp[(size_t)s4 * 32];
    ushort2 v5 = zp[(size_t)s5 * 32];
    ushort2 v6 = zp[(size_t)s6 * 32];
    ushort2 v7 = zp[(size_t)s7 * 32];
    ACC2(v0) ACC2(v1) ACC2(v2) ACC2(v3) ACC2(v4) ACC2(v5) ACC2(v6) ACC2(v7)
  }
  if (e + 3 < end) {
    int s0 = csr[e], s1 = csr[e + 1], s2 = csr[e + 2], s3 = csr[e + 3];
    ushort2 v0 = zp[(size_t)s0 * 32];
    ushort2 v1 = zp[(size_t)s1 * 32];
    ushort2 v2 = zp[(size_t)s2 * 32];
    ushort2 v3 = zp[(size_t)s3 * 32];
    ACC2(v0) ACC2(v1) ACC2(v2) ACC2(v3)
    e += 4;
  }
  for (; e < end; ++e) {
    ushort2 v0 = zp[(size_t)csr[e] * 32];
    ACC2(v0)
  }
#undef ACC2
  float inv = 1.0f / (float)max(end - start, 1);
  size_t o = (size_t)n * 64 + sl * 2;
  float vx = u[o] + ax * inv;
  float vy = u[o + 1] + ay * inv;
  float m = fmaxf(vx, vy);
#pragma unroll
  for (int off = 16; off > 0; off >>= 1) m = fmaxf(m, __shfl_xor(m, off, 64));
  float ex = expf(vx - m);
  float ey = expf(vy - m);
  float s = ex + ey;
#pragma unroll
  for (int off = 16; off > 0; off >>= 1) s += __shfl_xor(s, off, 64);
  float r = 1.0f / s;
  out[o] = ex * r;
  out[o + 1] = ey * r;
}

extern "C" void kernel_launch(void* const* d_in, const int* in_sizes, int n_in,
                              void* d_out, int out_size, void* d_ws, size_t ws_size,
                              hipStream_t stream) {
  const float* x   = (const float*)d_in[0];
  const int* src   = (const int*)d_in[1];
  const int* dst   = (const int*)d_in[2];
  const float* Ws0 = (const float*)d_in[3];
  const float* Wn0 = (const float*)d_in[4];
  const float* b0  = (const float*)d_in[5];
  const float* Ws1 = (const float*)d_in[6];
  const float* Wn1 = (const float*)d_in[7];
  const float* b1  = (const float*)d_in[8];
  const float* Ws2 = (const float*)d_in[9];
  const float* Wn2 = (const float*)d_in[10];
  const float* b2  = (const float*)d_in[11];
  float* out = (float*)d_out;

  // ws layout (identical to R10)
  char* ws = (char*)d_ws;
  int* cursor = (int*)ws;
  int* csr    = (int*)(ws + 200192);
  float* h1   = (float*)(ws + 3400192);
  float* h2   = (float*)(ws + 29000192);
  char* Creg  = ws + 54600192;
  float* selfb = (float*)Creg;                              // self / u
  unsigned short* z2 = (unsigned short*)(Creg + 12800000);  // layer-2 z (6.4MB)
  int* cnt  = (int*)Creg;
  int* bsum = (int*)(Creg + 200192);

  // z for layers 0/1 lives in d_out (12.8 MB exactly; dead before final write)
  unsigned short* zb = (unsigned short*)d_out;

  // split weights staged at h2 base (328 KB)
  unsigned short* wb = (unsigned short*)h2;
  unsigned short* wt0h = wb;
  unsigned short* wt0l = wb + 32768;
  unsigned short* wt1h = wb + 65536;
  unsigned short* wt1l = wb + 98304;
  unsigned short* wt2h = wb + 131072;
  unsigned short* wt2l = wb + 147456;

  // layer-2 weight copy target: h1 base (h1 dead after layer-1 gemm reads it)
  unsigned short* wt2hc = (unsigned short*)h1;
  unsigned short* wt2lc = wt2hc + 16384;

  // CSR build (XCD-class-partitioned hist/fill + parallel 2-level scan)
  hipMemsetAsync(cnt, 0, N_NODES * sizeof(int), stream);
  hist_kernel<<<8 * FILL_CH, 256, 0, stream>>>(dst, cnt);
  scan1_kernel<<<SCAN_B, 256, 0, stream>>>(cnt, cursor, bsum);
  scan2_kernel<<<1, 256, 0, stream>>>(bsum);
  scan3_kernel<<<SCAN_B, 256, 0, stream>>>(cursor, bsum);
  fill_kernel<<<8 * FILL_CH, 256, 0, stream>>>(src, dst, cursor, csr);
  wsplit_kernel<<<320, 256, 0, stream>>>(Ws0, Wn0, Ws1, Wn1, Ws2, Wn2, wb);

  // layer 0: self = x@Ws0 + b0 ; z = x@Wn0 (bf16) ; h1 = selu(self + mean(z))
  gemm_dual<4, 2><<<dim3(NT_GEMM, 4), 256, 0, stream>>>(x, wt0h, wt0l, b0, selfb, zb);
  gather_act<<<6250, 256, 0, stream>>>(zb, selfb, cursor, csr, h1);

  // layer 1: same with h1 -> h2
  gemm_dual<4, 2><<<dim3(NT_GEMM, 4), 256, 0, stream>>>(h1, wt1h, wt1l, b1, selfb, zb);
  hipMemcpyAsync(wt2hc, wt2h, 65536, hipMemcpyDeviceToDevice, stream);  // h1 dead now
  gather_act<<<6250, 256, 0, stream>>>(zb, selfb, cursor, csr, h2);     // clobbers wb

  // layer 2: u = h2@Ws2 + b2 ; z2 = h2@Wn2 (bf16) ; out = softmax(u + mean(z2))
  gemm_dual<2, 1><<<dim3(NT_GEMM, 2), 256, 0, stream>>>(h2, wt2hc, wt2lc, b2, selfb, z2);
  gather_sm<<<6250, 256, 0, stream>>>(z2, selfb, cursor, csr, out);
}

// Round 12
// 258.510 us; speedup vs baseline: 1.8548x; 1.0824x over previous
//
#include <hip/hip_runtime.h>
#include <hip/hip_bf16.h>

#define N_NODES 50000
#define N_EDGES 800000
#define D 128
#define SCAN_B 196  // ceil(N_NODES/256)
#define NT_GEMM 782 // ceil(N_NODES/64)
#define E_CHUNK 2048
#define FILL_CH 391 // ceil(N_EDGES/E_CHUNK)

typedef __attribute__((ext_vector_type(8))) __bf16 bf16x8;
typedef __attribute__((ext_vector_type(4))) float f32x4;

union U8 {
  bf16x8 v;
  uint4 u;
};

// ---- fp32 -> bf16 helpers ----
__device__ __forceinline__ unsigned short bf16_rne(float x) {
  unsigned u = __builtin_bit_cast(unsigned, x);
  unsigned r = u + 0x7fffu + ((u >> 16) & 1u);
  return (unsigned short)(r >> 16);
}
__device__ __forceinline__ float bf16_f(unsigned short b) {
  unsigned u = ((unsigned)b) << 16;
  return __builtin_bit_cast(float, u);
}
__device__ __forceinline__ void split2(float x, unsigned short& hi, unsigned short& lo) {
  hi = bf16_rne(x);
  lo = bf16_rne(x - bf16_f(hi));
}

__device__ __forceinline__ float selu_f(float x) {
  const float alpha = 1.6732632423543772f;
  const float scale = 1.0507009873554805f;
  return scale * (x > 0.0f ? x : alpha * expm1f(x));
}

// split raw fp32 bits (r0,r1 = 8 dwords) -> bf16 hi/lo fragments (trunc split)
__device__ __forceinline__ void splitF(uint4 r0, uint4 r1, U8& ah, U8& al) {
  unsigned u0 = r0.x, u1 = r0.y, u2 = r0.z, u3 = r0.w;
  unsigned u4 = r1.x, u5 = r1.y, u6 = r1.z, u7 = r1.w;
  ah.u.x = (u0 >> 16) | (u1 & 0xffff0000u);
  ah.u.y = (u2 >> 16) | (u3 & 0xffff0000u);
  ah.u.z = (u4 >> 16) | (u5 & 0xffff0000u);
  ah.u.w = (u6 >> 16) | (u7 & 0xffff0000u);
  unsigned r;
#define LOW(u) __builtin_bit_cast(unsigned, __builtin_bit_cast(float, u) - __builtin_bit_cast(float, u & 0xffff0000u))
  r = LOW(u0); al.u.x = r >> 16;
  r = LOW(u1); al.u.x |= r & 0xffff0000u;
  r = LOW(u2); al.u.y = r >> 16;
  r = LOW(u3); al.u.y |= r & 0xffff0000u;
  r = LOW(u4); al.u.z = r >> 16;
  r = LOW(u5); al.u.z |= r & 0xffff0000u;
  r = LOW(u6); al.u.w = r >> 16;
  r = LOW(u7); al.u.w |= r & 0xffff0000u;
#undef LOW
}

// ================= CSR build (XCD-class-partitioned) =================
__global__ __launch_bounds__(256) void hist_kernel(const int* __restrict__ dst,
                                                   int* __restrict__ cnt) {
  const int cls = blockIdx.x & 7;
  const int base = (blockIdx.x >> 3) * E_CHUNK + threadIdx.x;
#pragma unroll
  for (int i = 0; i < E_CHUNK / 256; ++i) {
    int e = base + i * 256;
    if (e < N_EDGES) {
      int d = dst[e];
      if (((d >> 4) & 7) == cls) atomicAdd(&cnt[d], 1);
    }
  }
}

__global__ __launch_bounds__(256) void scan1_kernel(const int* __restrict__ cnt,
                                                    int* __restrict__ cursor,
                                                    int* __restrict__ bsum) {
  __shared__ int s[256];
  const int t = threadIdx.x;
  const int i = blockIdx.x * 256 + t;
  int v = (i < N_NODES) ? cnt[i] : 0;
  s[t] = v;
  __syncthreads();
#pragma unroll
  for (int off = 1; off < 256; off <<= 1) {
    int u = (t >= off) ? s[t - off] : 0;
    __syncthreads();
    s[t] += u;
    __syncthreads();
  }
  if (i < N_NODES) cursor[i] = s[t] - v;
  if (t == 255) bsum[blockIdx.x] = s[255];
}

__global__ __launch_bounds__(256) void scan2_kernel(int* __restrict__ bsum) {
  __shared__ int s[256];
  const int t = threadIdx.x;
  int v = (t < SCAN_B) ? bsum[t] : 0;
  s[t] = v;
  __syncthreads();
#pragma unroll
  for (int off = 1; off < 256; off <<= 1) {
    int u = (t >= off) ? s[t - off] : 0;
    __syncthreads();
    s[t] += u;
    __syncthreads();
  }
  if (t < SCAN_B) bsum[t] = s[t] - v;
}

__global__ __launch_bounds__(256) void scan3_kernel(int* __restrict__ cursor,
                                                    const int* __restrict__ bsum) {
  const int i = blockIdx.x * 256 + threadIdx.x;
  if (i < N_NODES) cursor[i] += bsum[blockIdx.x];
}

__global__ __launch_bounds__(256) void fill_kernel(const int* __restrict__ src,
                                                   const int* __restrict__ dst,
                                                   int* __restrict__ cursor,
                                                   int* __restrict__ csr_src) {
  const int cls = blockIdx.x & 7;
  const int base = (blockIdx.x >> 3) * E_CHUNK + threadIdx.x;
#pragma unroll
  for (int i = 0; i < E_CHUNK / 256; ++i) {
    int e = base + i * 256;
    if (e < N_EDGES) {
      int d = dst[e];
      if (((d >> 4) & 7) == cls) {
        int pos = atomicAdd(&cursor[d], 1);
        csr_src[pos] = src[e];
      }
    }
  }
}

// ================= weight split/transpose precompute =================
// Per-layer B image, K=128, pre-swizzled (si = idx ^ ((n&7)<<3), idx = n*K+k).
__global__ __launch_bounds__(256) void wsplit_kernel(
    const float* __restrict__ Ws0, const float* __restrict__ Wn0,
    const float* __restrict__ Ws1, const float* __restrict__ Wn1,
    const float* __restrict__ Ws2, const float* __restrict__ Wn2,
    unsigned short* __restrict__ wb) {
  int idx = blockIdx.x * 256 + threadIdx.x;
  if (idx < 32768) {
    int n = idx >> 7, k = idx & 127;
    float wv = (n < 128) ? Ws0[k * 128 + n] : Wn0[k * 128 + (n - 128)];
    unsigned short h, l; split2(wv, h, l);
    int si = idx ^ ((n & 7) << 3);
    wb[si] = h; wb[32768 + si] = l;
  } else if (idx < 65536) {
    int j = idx - 32768;
    int n = j >> 7, k = j & 127;
    float wv = (n < 128) ? Ws1[k * 128 + n] : Wn1[k * 128 + (n - 128)];
    unsigned short h, l; split2(wv, h, l);
    int si = j ^ ((n & 7) << 3);
    wb[65536 + si] = h; wb[98304 + si] = l;
  } else if (idx < 81920) {
    int j = idx - 65536;
    int n = j >> 7, k = j & 127;
    float wv = (n < 64) ? Ws2[k * 64 + n] : Wn2[k * 64 + (n - 64)];
    unsigned short h, l; split2(wv, h, l);
    int si = j ^ ((n & 7) << 3);
    wb[131072 + si] = h; wb[147456 + si] = l;
  }
}

// ================= dual-output MFMA GEMM, 128-col panels =================
// Block = 64 rows x 128 cols (panel cb). TC = total output cols, ZC = fp32
// (self/u, +bias) col count from col 0; rest bf16 z. LDS 64KB -> 2 blocks/CU.
template <int TC, int ZC>
__global__ __launch_bounds__(256, 2) void gemm_dual(const float* __restrict__ hsrc,
                                                    const unsigned short* __restrict__ wth,
                                                    const unsigned short* __restrict__ wtl,
                                                    const float* __restrict__ bias,
                                                    float* __restrict__ out0,
                                                    unsigned short* __restrict__ out1) {
  constexpr int K = 128;
  __shared__ unsigned short bh_s[128 * K];
  __shared__ unsigned short bl_s[128 * K];

  const int tid = threadIdx.x;
  const int w = tid >> 6;
  const int l = tid & 63;
  const int lr = l & 15;
  const int lg = l >> 4;
  const int cb = blockIdx.y;
  const int colbase = cb * 128;
  const int row0 = blockIdx.x * 64;
  const int arow = min(row0 + w * 16 + lr, N_NODES - 1);

  // ---- issue the wave's full A slice first (8 uint4, K=128) ----
  uint4 a[8];
  {
    const uint4* hp = (const uint4*)(hsrc + (size_t)arow * D);
#pragma unroll
    for (int q = 0; q < 2; ++q)
#pragma unroll
      for (int kt = 0; kt < 2; ++kt) {
        a[q * 4 + kt * 2 + 0] = hp[q * 16 + kt * 8 + lg * 2];
        a[q * 4 + kt * 2 + 1] = hp[q * 16 + kt * 8 + lg * 2 + 1];
      }
  }

  // ---- stage this panel's 128 cols of B (pre-swizzled, linear copy) ----
  {
    const uint4* gh = (const uint4*)(wth + (size_t)colbase * K);
    const uint4* gl = (const uint4*)(wtl + (size_t)colbase * K);
    uint4* sh = (uint4*)bh_s;
    uint4* sl = (uint4*)bl_s;
#pragma unroll
    for (int i = 0; i < 8; ++i) {
      sh[tid + i * 256] = gh[tid + i * 256];
      sl[tid + i * 256] = gl[tid + i * 256];
    }
  }
  __syncthreads();

  f32x4 accA[8], accB[8];
#pragma unroll
  for (int i = 0; i < 8; ++i) {
    accA[i] = (f32x4){0.f, 0.f, 0.f, 0.f};
    accB[i] = (f32x4){0.f, 0.f, 0.f, 0.f};
  }

#pragma unroll
  for (int q = 0; q < 2; ++q) {
#pragma unroll
    for (int kt = 0; kt < 2; ++kt) {
      U8 ah, al;
      splitF(a[q * 4 + kt * 2], a[q * 4 + kt * 2 + 1], ah, al);
      const int kb = q * 64 + (((((kt << 2) | lg)) ^ (lr & 7)) << 3);
#pragma unroll
      for (int nf = 0; nf < 8; ++nf) {
        const int si = (nf * 16 + lr) * K + kb;
        bf16x8 bh = *(const bf16x8*)&bh_s[si];
        bf16x8 bl = *(const bf16x8*)&bl_s[si];
        accA[nf] = __builtin_amdgcn_mfma_f32_16x16x32_bf16(ah.v, bh, accA[nf], 0, 0, 0);
        accB[nf] = __builtin_amdgcn_mfma_f32_16x16x32_bf16(al.v, bh, accB[nf], 0, 0, 0);
        accB[nf] = __builtin_amdgcn_mfma_f32_16x16x32_bf16(ah.v, bl, accB[nf], 0, 0, 0);
      }
    }
  }

  // epilogue: col = colbase + nf*16 + lr; fp32(+bias) if col < ZC else bf16 z
#pragma unroll
  for (int nf = 0; nf < 8; ++nf) {
    const int col = colbase + nf * 16 + lr;
#pragma unroll
    for (int i = 0; i < 4; ++i) {
      const int grow = row0 + w * 16 + lg * 4 + i;
      if (grow < N_NODES) {
        float v = accA[nf][i] + accB[nf][i];
        if (col < ZC) {
          out0[(size_t)grow * ZC + col] = v + bias[col];
        } else {
          out1[(size_t)grow * (TC - ZC) + (col - ZC)] = bf16_rne(v);
        }
      }
    }
  }
}

// ================= gather mean(z bf16) + self + SELU -> h_next =================
__global__ __launch_bounds__(256) void gather_act(const unsigned short* __restrict__ zb,
                                                  const float* __restrict__ selfb,
                                                  const int* __restrict__ cursor,
                                                  const int* __restrict__ csr,
                                                  float* __restrict__ hnext) {
  const int n = blockIdx.x * 8 + (threadIdx.x >> 5);
  const int sl = threadIdx.x & 31;
  const int end = cursor[n];
  const int start = (n == 0) ? 0 : cursor[n - 1];
  const ushort4* zp = (const ushort4*)zb + sl;  // row stride = 32 ushort4
  float ax = 0.f, ay = 0.f, az = 0.f, aw = 0.f;
#define ACC4(v) { ax += bf16_f(v.x); ay += bf16_f(v.y); az += bf16_f(v.z); aw += bf16_f(v.w); }
  int e = start;
  for (; e + 7 < end; e += 8) {
    int s0 = csr[e],     s1 = csr[e + 1], s2 = csr[e + 2], s3 = csr[e + 3];
    int s4 = csr[e + 4], s5 = csr[e + 5], s6 = csr[e + 6], s7 = csr[e + 7];
    ushort4 v0 = zp[(size_t)s0 * 32];
    ushort4 v1 = zp[(size_t)s1 * 32];
    ushort4 v2 = zp[(size_t)s2 * 32];
    ushort4 v3 = zp[(size_t)s3 * 32];
    ushort4 v4 = zp[(size_t)s4 * 32];
    ushort4 v5 = zp[(size_t)s5 * 32];
    ushort4 v6 = zp[(size_t)s6 * 32];
    ushort4 v7 = zp[(size_t)s7 * 32];
    ACC4(v0) ACC4(v1) ACC4(v2) ACC4(v3) ACC4(v4) ACC4(v5) ACC4(v6) ACC4(v7)
  }
  if (e + 3 < end) {
    int s0 = csr[e], s1 = csr[e + 1], s2 = csr[e + 2], s3 = csr[e + 3];
    ushort4 v0 = zp[(size_t)s0 * 32];
    ushort4 v1 = zp[(size_t)s1 * 32];
    ushort4 v2 = zp[(size_t)s2 * 32];
    ushort4 v3 = zp[(size_t)s3 * 32];
    ACC4(v0) ACC4(v1) ACC4(v2) ACC4(v3)
    e += 4;
  }
  for (; e < end; ++e) {
    ushort4 v0 = zp[(size_t)csr[e] * 32];
    ACC4(v0)
  }
#undef ACC4
  float inv = 1.0f / (float)max(end - start, 1);
  float4 sv = *(const float4*)(selfb + (size_t)n * D + sl * 4);
  float4 o;
  o.x = selu_f(sv.x + ax * inv);
  o.y = selu_f(sv.y + ay * inv);
  o.z = selu_f(sv.z + az * inv);
  o.w = selu_f(sv.w + aw * inv);
  *(float4*)(hnext + (size_t)n * D + sl * 4) = o;
}

// ================= gather mean(z2 bf16) + u + softmax -> out =================
__global__ __launch_bounds__(256) void gather_sm(const unsigned short* __restrict__ z2,
                                                 const float* __restrict__ u,
                                                 const int* __restrict__ cursor,
                                                 const int* __restrict__ csr,
                                                 float* __restrict__ out) {
  const int n = blockIdx.x * 8 + (threadIdx.x >> 5);
  const int sl = threadIdx.x & 31;
  const int end = cursor[n];
  const int start = (n == 0) ? 0 : cursor[n - 1];
  const ushort2* zp = (const ushort2*)z2 + sl;  // row stride = 32 ushort2
  float ax = 0.f, ay = 0.f;
#define ACC2(v) { ax += bf16_f(v.x); ay += bf16_f(v.y); }
  int e = start;
  for (; e + 7 < end; e += 8) {
    int s0 = csr[e],     s1 = csr[e + 1], s2 = csr[e + 2], s3 = csr[e + 3];
    int s4 = csr[e + 4], s5 = csr[e + 5], s6 = csr[e + 6], s7 = csr[e + 7];
    ushort2 v0 = zp[(size_t)s0 * 32];
    ushort2 v1 = zp[(size_t)s1 * 32];
    ushort2 v2 = zp[(size_t)s2 * 32];
    ushort2 v3 = zp[(size_t)s3 * 32];
    ushort2 v4 = zp[(size_t)s4 * 32];
    ushort2 v5 = zp[(size_t)s5 * 32];
    ushort2 v6 = zp[(size_t)s6 * 32];
    ushort2 v7 = zp[(size_t)s7 * 32];
    ACC2(v0) ACC2(v1) ACC2(v2) ACC2(v3) ACC2(v4) ACC2(v5) ACC2(v6) ACC2(v7)
  }
  if (e + 3 < end) {
    int s0 = csr[e], s1 = csr[e + 1], s2 = csr[e + 2], s3 = csr[e + 3];
    ushort2 v0 = zp[(size_t)s0 * 32];
    ushort2 v1 = zp[(size_t)s1 * 32];
    ushort2 v2 = zp[(size_t)s2 * 32];
    ushort2 v3 = zp[(size_t)s3 * 32];
    ACC2(v0) ACC2(v1) ACC2(v2) ACC2(v3)
    e += 4;
  }
  for (; e < end; ++e) {
    ushort2 v0 = zp[(size_t)csr[e] * 32];
    ACC2(v0)
  }
#undef ACC2
  float inv = 1.0f / (float)max(end - start, 1);
  size_t o = (size_t)n * 64 + sl * 2;
  float vx = u[o] + ax * inv;
  float vy = u[o + 1] + ay * inv;
  float m = fmaxf(vx, vy);
#pragma unroll
  for (int off = 16; off > 0; off >>= 1) m = fmaxf(m, __shfl_xor(m, off, 64));
  float ex = expf(vx - m);
  float ey = expf(vy - m);
  float s = ex + ey;
#pragma unroll
  for (int off = 16; off > 0; off >>= 1) s += __shfl_xor(s, off, 64);
  float r = 1.0f / s;
  out[o] = ex * r;
  out[o + 1] = ey * r;
}

extern "C" void kernel_launch(void* const* d_in, const int* in_sizes, int n_in,
                              void* d_out, int out_size, void* d_ws, size_t ws_size,
                              hipStream_t stream) {
  const float* x   = (const float*)d_in[0];
  const int* src   = (const int*)d_in[1];
  const int* dst   = (const int*)d_in[2];
  const float* Ws0 = (const float*)d_in[3];
  const float* Wn0 = (const float*)d_in[4];
  const float* b0  = (const float*)d_in[5];
  const float* Ws1 = (const float*)d_in[6];
  const float* Wn1 = (const float*)d_in[7];
  const float* b1  = (const float*)d_in[8];
  const float* Ws2 = (const float*)d_in[9];
  const float* Wn2 = (const float*)d_in[10];
  const float* b2  = (const float*)d_in[11];
  float* out = (float*)d_out;

  // ws layout (identical to R10/R11)
  char* ws = (char*)d_ws;
  int* cursor = (int*)ws;
  int* csr    = (int*)(ws + 200192);
  float* h1   = (float*)(ws + 3400192);
  float* h2   = (float*)(ws + 29000192);
  char* Creg  = ws + 54600192;
  float* selfb = (float*)Creg;                              // self / u
  unsigned short* z2 = (unsigned short*)(Creg + 12800000);  // layer-2 z (6.4MB)
  int* cnt  = (int*)Creg;
  int* bsum = (int*)(Creg + 200192);

  // z for layers 0/1 lives in d_out (12.8 MB exactly; dead before final write)
  unsigned short* zb = (unsigned short*)d_out;

  // split weights staged at h2 base (328 KB)
  unsigned short* wb = (unsigned short*)h2;
  unsigned short* wt0h = wb;
  unsigned short* wt0l = wb + 32768;
  unsigned short* wt1h = wb + 65536;
  unsigned short* wt1l = wb + 98304;
  unsigned short* wt2h = wb + 131072;
  unsigned short* wt2l = wb + 147456;

  // layer-2 weight copy target: h1 base (h1 dead after layer-1 gemm reads it)
  unsigned short* wt2hc = (unsigned short*)h1;
  unsigned short* wt2lc = wt2hc + 16384;

  // CSR build (XCD-class-partitioned hist/fill + parallel 2-level scan)
  hipMemsetAsync(cnt, 0, N_NODES * sizeof(int), stream);
  hist_kernel<<<8 * FILL_CH, 256, 0, stream>>>(dst, cnt);
  scan1_kernel<<<SCAN_B, 256, 0, stream>>>(cnt, cursor, bsum);
  scan2_kernel<<<1, 256, 0, stream>>>(bsum);
  scan3_kernel<<<SCAN_B, 256, 0, stream>>>(cursor, bsum);
  fill_kernel<<<8 * FILL_CH, 256, 0, stream>>>(src, dst, cursor, csr);
  wsplit_kernel<<<320, 256, 0, stream>>>(Ws0, Wn0, Ws1, Wn1, Ws2, Wn2, wb);

  // layer 0: self = x@Ws0 + b0 ; z = x@Wn0 (bf16) ; h1 = selu(self + mean(z))
  gemm_dual<256, 128><<<dim3(NT_GEMM, 2), 256, 0, stream>>>(x, wt0h, wt0l, b0, selfb, zb);
  gather_act<<<6250, 256, 0, stream>>>(zb, selfb, cursor, csr, h1);

  // layer 1: same with h1 -> h2
  gemm_dual<256, 128><<<dim3(NT_GEMM, 2), 256, 0, stream>>>(h1, wt1h, wt1l, b1, selfb, zb);
  hipMemcpyAsync(wt2hc, wt2h, 65536, hipMemcpyDeviceToDevice, stream);  // h1 dead now
  gather_act<<<6250, 256, 0, stream>>>(zb, selfb, cursor, csr, h2);     // clobbers wb

  // layer 2: u = h2@Ws2 + b2 ; z2 = h2@Wn2 (bf16) ; out = softmax(u + mean(z2))
  gemm_dual<128, 64><<<dim3(NT_GEMM, 1), 256, 0, stream>>>(h2, wt2hc, wt2lc, b2, selfb, z2);
  gather_sm<<<6250, 256, 0, stream>>>(z2, selfb, cursor, csr, out);
}

// Round 13
// 254.553 us; speedup vs baseline: 1.8836x; 1.0155x over previous
//
#include <hip/hip_runtime.h>
#include <hip/hip_bf16.h>

#define N_NODES 50000
#define N_EDGES 800000
#define D 128
#define NP4 50048       // padded per-bank node count
#define SCAN1_B 782     // (4*NP4)/256
#define NT_GEMM 782     // ceil(N_NODES/64)
#define E_CHUNK 2048
#define FILL_CH 391     // ceil(N_EDGES/E_CHUNK)

typedef __attribute__((ext_vector_type(8))) __bf16 bf16x8;
typedef __attribute__((ext_vector_type(4))) float f32x4;

union U8 {
  bf16x8 v;
  uint4 u;
};

// ---- fp32 -> bf16 helpers ----
__device__ __forceinline__ unsigned short bf16_rne(float x) {
  unsigned u = __builtin_bit_cast(unsigned, x);
  unsigned r = u + 0x7fffu + ((u >> 16) & 1u);
  return (unsigned short)(r >> 16);
}
__device__ __forceinline__ float bf16_f(unsigned short b) {
  unsigned u = ((unsigned)b) << 16;
  return __builtin_bit_cast(float, u);
}
__device__ __forceinline__ void split2(float x, unsigned short& hi, unsigned short& lo) {
  hi = bf16_rne(x);
  lo = bf16_rne(x - bf16_f(hi));
}

__device__ __forceinline__ float selu_f(float x) {
  const float alpha = 1.6732632423543772f;
  const float scale = 1.0507009873554805f;
  return scale * (x > 0.0f ? x : alpha * expm1f(x));
}

// split raw fp32 bits (r0,r1 = 8 dwords) -> bf16 hi/lo fragments (trunc split)
__device__ __forceinline__ void splitF(uint4 r0, uint4 r1, U8& ah, U8& al) {
  unsigned u0 = r0.x, u1 = r0.y, u2 = r0.z, u3 = r0.w;
  unsigned u4 = r1.x, u5 = r1.y, u6 = r1.z, u7 = r1.w;
  ah.u.x = (u0 >> 16) | (u1 & 0xffff0000u);
  ah.u.y = (u2 >> 16) | (u3 & 0xffff0000u);
  ah.u.z = (u4 >> 16) | (u5 & 0xffff0000u);
  ah.u.w = (u6 >> 16) | (u7 & 0xffff0000u);
  unsigned r;
#define LOW(u) __builtin_bit_cast(unsigned, __builtin_bit_cast(float, u) - __builtin_bit_cast(float, u & 0xffff0000u))
  r = LOW(u0); al.u.x = r >> 16;
  r = LOW(u1); al.u.x |= r & 0xffff0000u;
  r = LOW(u2); al.u.y = r >> 16;
  r = LOW(u3); al.u.y |= r & 0xffff0000u;
  r = LOW(u4); al.u.z = r >> 16;
  r = LOW(u5); al.u.z |= r & 0xffff0000u;
  r = LOW(u6); al.u.w = r >> 16;
  r = LOW(u7); al.u.w |= r & 0xffff0000u;
#undef LOW
}

// ================= CSR build =================
// XCD-class partition (class = (dst>>4)&7, block bid: chunk=bid>>3, cls=bid&7)
// + 4-way sub-counters keyed by e&3, layout [p][NP4] (contention spread).
__global__ __launch_bounds__(256) void hist_kernel(const int* __restrict__ dst,
                                                   int* __restrict__ cnt) {
  const int cls = blockIdx.x & 7;
  const int base = (blockIdx.x >> 3) * E_CHUNK + threadIdx.x;
#pragma unroll
  for (int i = 0; i < E_CHUNK / 256; ++i) {
    int e = base + i * 256;
    if (e < N_EDGES) {
      int d = dst[e];
      if (((d >> 4) & 7) == cls) atomicAdd(&cnt[(e & 3) * NP4 + d], 1);
    }
  }
}

// scan1: exclusive scan partials over logical node-major order j=(n<<2)|p,
// reading/writing the transposed [p][NP4] layout.
__global__ __launch_bounds__(256) void scan1_kernel(const int* __restrict__ cnt,
                                                    int* __restrict__ cur,
                                                    int* __restrict__ bsum) {
  __shared__ int s[256];
  const int t = threadIdx.x;
  const int j = blockIdx.x * 256 + t;
  const int n = j >> 2, p = j & 3;
  int v = (n < N_NODES) ? cnt[p * NP4 + n] : 0;
  s[t] = v;
  __syncthreads();
#pragma unroll
  for (int off = 1; off < 256; off <<= 1) {
    int u = (t >= off) ? s[t - off] : 0;
    __syncthreads();
    s[t] += u;
    __syncthreads();
  }
  if (n < N_NODES) cur[p * NP4 + n] = s[t] - v;  // missing block offset
  if (t == 255) bsum[blockIdx.x] = s[255];
}

// scan2: scan the SCAN1_B block sums (<=1024)
__global__ __launch_bounds__(1024) void scan2_kernel(int* __restrict__ bsum) {
  __shared__ int s[1024];
  const int t = threadIdx.x;
  int v = (t < SCAN1_B) ? bsum[t] : 0;
  s[t] = v;
  __syncthreads();
  for (int off = 1; off < 1024; off <<= 1) {
    int u = (t >= off) ? s[t - off] : 0;
    __syncthreads();
    s[t] += u;
    __syncthreads();
  }
  if (t < SCAN1_B) bsum[t] = s[t] - v;  // exclusive
}

// scan3: add block offsets; emit rowptr[n] at p==0
__global__ __launch_bounds__(256) void scan3_kernel(int* __restrict__ cur,
                                                    int* __restrict__ rowptr,
                                                    const int* __restrict__ bsum) {
  const int j = blockIdx.x * 256 + threadIdx.x;
  const int n = j >> 2, p = j & 3;
  if (n < N_NODES) {
    int v = cur[p * NP4 + n] + bsum[blockIdx.x];
    cur[p * NP4 + n] = v;
    if (p == 0) rowptr[n] = v;
  }
}

__global__ __launch_bounds__(256) void fill_kernel(const int* __restrict__ src,
                                                   const int* __restrict__ dst,
                                                   int* __restrict__ cur,
                                                   int* __restrict__ csr_src) {
  const int cls = blockIdx.x & 7;
  const int base = (blockIdx.x >> 3) * E_CHUNK + threadIdx.x;
#pragma unroll
  for (int i = 0; i < E_CHUNK / 256; ++i) {
    int e = base + i * 256;
    if (e < N_EDGES) {
      int d = dst[e];
      if (((d >> 4) & 7) == cls) {
        int pos = atomicAdd(&cur[(e & 3) * NP4 + d], 1);
        csr_src[pos] = src[e];
      }
    }
  }
}

// ================= weight split/transpose precompute =================
// Per-layer B image, K=128, pre-swizzled (si = idx ^ ((n&7)<<3), idx = n*K+k).
__global__ __launch_bounds__(256) void wsplit_kernel(
    const float* __restrict__ Ws0, const float* __restrict__ Wn0,
    const float* __restrict__ Ws1, const float* __restrict__ Wn1,
    const float* __restrict__ Ws2, const float* __restrict__ Wn2,
    unsigned short* __restrict__ wb) {
  int idx = blockIdx.x * 256 + threadIdx.x;
  if (idx < 32768) {
    int n = idx >> 7, k = idx & 127;
    float wv = (n < 128) ? Ws0[k * 128 + n] : Wn0[k * 128 + (n - 128)];
    unsigned short h, l; split2(wv, h, l);
    int si = idx ^ ((n & 7) << 3);
    wb[si] = h; wb[32768 + si] = l;
  } else if (idx < 65536) {
    int j = idx - 32768;
    int n = j >> 7, k = j & 127;
    float wv = (n < 128) ? Ws1[k * 128 + n] : Wn1[k * 128 + (n - 128)];
    unsigned short h, l; split2(wv, h, l);
    int si = j ^ ((n & 7) << 3);
    wb[65536 + si] = h; wb[98304 + si] = l;
  } else if (idx < 81920) {
    int j = idx - 65536;
    int n = j >> 7, k = j & 127;
    float wv = (n < 64) ? Ws2[k * 64 + n] : Wn2[k * 64 + (n - 64)];
    unsigned short h, l; split2(wv, h, l);
    int si = j ^ ((n & 7) << 3);
    wb[131072 + si] = h; wb[147456 + si] = l;
  }
}

// ================= dual-output MFMA GEMM, 128-col panels =================
template <int TC, int ZC>
__global__ __launch_bounds__(256, 2) void gemm_dual(const float* __restrict__ hsrc,
                                                    const unsigned short* __restrict__ wth,
                                                    const unsigned short* __restrict__ wtl,
                                                    const float* __restrict__ bias,
                                                    float* __restrict__ out0,
                                                    unsigned short* __restrict__ out1) {
  constexpr int K = 128;
  __shared__ unsigned short bh_s[128 * K];
  __shared__ unsigned short bl_s[128 * K];

  const int tid = threadIdx.x;
  const int w = tid >> 6;
  const int l = tid & 63;
  const int lr = l & 15;
  const int lg = l >> 4;
  const int cb = blockIdx.y;
  const int colbase = cb * 128;
  const int row0 = blockIdx.x * 64;
  const int arow = min(row0 + w * 16 + lr, N_NODES - 1);

  uint4 a[8];
  {
    const uint4* hp = (const uint4*)(hsrc + (size_t)arow * D);
#pragma unroll
    for (int q = 0; q < 2; ++q)
#pragma unroll
      for (int kt = 0; kt < 2; ++kt) {
        a[q * 4 + kt * 2 + 0] = hp[q * 16 + kt * 8 + lg * 2];
        a[q * 4 + kt * 2 + 1] = hp[q * 16 + kt * 8 + lg * 2 + 1];
      }
  }

  {
    const uint4* gh = (const uint4*)(wth + (size_t)colbase * K);
    const uint4* gl = (const uint4*)(wtl + (size_t)colbase * K);
    uint4* sh = (uint4*)bh_s;
    uint4* sl = (uint4*)bl_s;
#pragma unroll
    for (int i = 0; i < 8; ++i) {
      sh[tid + i * 256] = gh[tid + i * 256];
      sl[tid + i * 256] = gl[tid + i * 256];
    }
  }
  __syncthreads();

  f32x4 accA[8], accB[8];
#pragma unroll
  for (int i = 0; i < 8; ++i) {
    accA[i] = (f32x4){0.f, 0.f, 0.f, 0.f};
    accB[i] = (f32x4){0.f, 0.f, 0.f, 0.f};
  }

#pragma unroll
  for (int q = 0; q < 2; ++q) {
#pragma unroll
    for (int kt = 0; kt < 2; ++kt) {
      U8 ah, al;
      splitF(a[q * 4 + kt * 2], a[q * 4 + kt * 2 + 1], ah, al);
      const int kb = q * 64 + (((((kt << 2) | lg)) ^ (lr & 7)) << 3);
#pragma unroll
      for (int nf = 0; nf < 8; ++nf) {
        const int si = (nf * 16 + lr) * K + kb;
        bf16x8 bh = *(const bf16x8*)&bh_s[si];
        bf16x8 bl = *(const bf16x8*)&bl_s[si];
        accA[nf] = __builtin_amdgcn_mfma_f32_16x16x32_bf16(ah.v, bh, accA[nf], 0, 0, 0);
        accB[nf] = __builtin_amdgcn_mfma_f32_16x16x32_bf16(al.v, bh, accB[nf], 0, 0, 0);
        accB[nf] = __builtin_amdgcn_mfma_f32_16x16x32_bf16(ah.v, bl, accB[nf], 0, 0, 0);
      }
    }
  }

#pragma unroll
  for (int nf = 0; nf < 8; ++nf) {
    const int col = colbase + nf * 16 + lr;
#pragma unroll
    for (int i = 0; i < 4; ++i) {
      const int grow = row0 + w * 16 + lg * 4 + i;
      if (grow < N_NODES) {
        float v = accA[nf][i] + accB[nf][i];
        if (col < ZC) {
          out0[(size_t)grow * ZC + col] = v + bias[col];
        } else {
          out1[(size_t)grow * (TC - ZC) + (col - ZC)] = bf16_rne(v);
        }
      }
    }
  }
}

// ================= gather mean(z bf16) + self + SELU -> h_next =================
__global__ __launch_bounds__(256) void gather_act(const unsigned short* __restrict__ zb,
                                                  const float* __restrict__ selfb,
                                                  const int* __restrict__ rowptr,
                                                  const int* __restrict__ csr,
                                                  float* __restrict__ hnext) {
  const int n = blockIdx.x * 8 + (threadIdx.x >> 5);
  const int sl = threadIdx.x & 31;
  const int start = rowptr[n];
  const int end = (n < N_NODES - 1) ? rowptr[n + 1] : N_EDGES;
  const ushort4* zp = (const ushort4*)zb + sl;  // row stride = 32 ushort4
  float ax = 0.f, ay = 0.f, az = 0.f, aw = 0.f;
#define ACC4(v) { ax += bf16_f(v.x); ay += bf16_f(v.y); az += bf16_f(v.z); aw += bf16_f(v.w); }
  int e = start;
  for (; e + 7 < end; e += 8) {
    int s0 = csr[e],     s1 = csr[e + 1], s2 = csr[e + 2], s3 = csr[e + 3];
    int s4 = csr[e + 4], s5 = csr[e + 5], s6 = csr[e + 6], s7 = csr[e + 7];
    ushort4 v0 = zp[(size_t)s0 * 32];
    ushort4 v1 = zp[(size_t)s1 * 32];
    ushort4 v2 = zp[(size_t)s2 * 32];
    ushort4 v3 = zp[(size_t)s3 * 32];
    ushort4 v4 = zp[(size_t)s4 * 32];
    ushort4 v5 = zp[(size_t)s5 * 32];
    ushort4 v6 = zp[(size_t)s6 * 32];
    ushort4 v7 = zp[(size_t)s7 * 32];
    ACC4(v0) ACC4(v1) ACC4(v2) ACC4(v3) ACC4(v4) ACC4(v5) ACC4(v6) ACC4(v7)
  }
  if (e + 3 < end) {
    int s0 = csr[e], s1 = csr[e + 1], s2 = csr[e + 2], s3 = csr[e + 3];
    ushort4 v0 = zp[(size_t)s0 * 32];
    ushort4 v1 = zp[(size_t)s1 * 32];
    ushort4 v2 = zp[(size_t)s2 * 32];
    ushort4 v3 = zp[(size_t)s3 * 32];
    ACC4(v0) ACC4(v1) ACC4(v2) ACC4(v3)
    e += 4;
  }
  for (; e < end; ++e) {
    ushort4 v0 = zp[(size_t)csr[e] * 32];
    ACC4(v0)
  }
#undef ACC4
  float inv = 1.0f / (float)max(end - start, 1);
  float4 sv = *(const float4*)(selfb + (size_t)n * D + sl * 4);
  float4 o;
  o.x = selu_f(sv.x + ax * inv);
  o.y = selu_f(sv.y + ay * inv);
  o.z = selu_f(sv.z + az * inv);
  o.w = selu_f(sv.w + aw * inv);
  *(float4*)(hnext + (size_t)n * D + sl * 4) = o;
}

// ================= gather mean(z2 bf16) + u + softmax -> out =================
__global__ __launch_bounds__(256) void gather_sm(const unsigned short* __restrict__ z2,
                                                 const float* __restrict__ u,
                                                 const int* __restrict__ rowptr,
                                                 const int* __restrict__ csr,
                                                 float* __restrict__ out) {
  const int n = blockIdx.x * 8 + (threadIdx.x >> 5);
  const int sl = threadIdx.x & 31;
  const int start = rowptr[n];
  const int end = (n < N_NODES - 1) ? rowptr[n + 1] : N_EDGES;
  const ushort2* zp = (const ushort2*)z2 + sl;  // row stride = 32 ushort2
  float ax = 0.f, ay = 0.f;
#define ACC2(v) { ax += bf16_f(v.x); ay += bf16_f(v.y); }
  int e = start;
  for (; e + 7 < end; e += 8) {
    int s0 = csr[e],     s1 = csr[e + 1], s2 = csr[e + 2], s3 = csr[e + 3];
    int s4 = csr[e + 4], s5 = csr[e + 5], s6 = csr[e + 6], s7 = csr[e + 7];
    ushort2 v0 = zp[(size_t)s0 * 32];
    ushort2 v1 = zp[(size_t)s1 * 32];
    ushort2 v2 = zp[(size_t)s2 * 32];
    ushort2 v3 = zp[(size_t)s3 * 32];
    ushort2 v4 = zp[(size_t)s4 * 32];
    ushort2 v5 = zp[(size_t)s5 * 32];
    ushort2 v6 = zp[(size_t)s6 * 32];
    ushort2 v7 = zp[(size_t)s7 * 32];
    ACC2(v0) ACC2(v1) ACC2(v2) ACC2(v3) ACC2(v4) ACC2(v5) ACC2(v6) ACC2(v7)
  }
  if (e + 3 < end) {
    int s0 = csr[e], s1 = csr[e + 1], s2 = csr[e + 2], s3 = csr[e + 3];
    ushort2 v0 = zp[(size_t)s0 * 32];
    ushort2 v1 = zp[(size_t)s1 * 32];
    ushort2 v2 = zp[(size_t)s2 * 32];
    ushort2 v3 = zp[(size_t)s3 * 32];
    ACC2(v0) ACC2(v1) ACC2(v2) ACC2(v3)
    e += 4;
  }
  for (; e < end; ++e) {
    ushort2 v0 = zp[(size_t)csr[e] * 32];
    ACC2(v0)
  }
#undef ACC2
  float inv = 1.0f / (float)max(end - start, 1);
  size_t o = (size_t)n * 64 + sl * 2;
  float vx = u[o] + ax * inv;
  float vy = u[o + 1] + ay * inv;
  float m = fmaxf(vx, vy);
#pragma unroll
  for (int off = 16; off > 0; off >>= 1) m = fmaxf(m, __shfl_xor(m, off, 64));
  float ex = expf(vx - m);
  float ey = expf(vy - m);
  float s = ex + ey;
#pragma unroll
  for (int off = 16; off > 0; off >>= 1) s += __shfl_xor(s, off, 64);
  float r = 1.0f / s;
  out[o] = ex * r;
  out[o + 1] = ey * r;
}

extern "C" void kernel_launch(void* const* d_in, const int* in_sizes, int n_in,
                              void* d_out, int out_size, void* d_ws, size_t ws_size,
                              hipStream_t stream) {
  const float* x   = (const float*)d_in[0];
  const int* src   = (const int*)d_in[1];
  const int* dst   = (const int*)d_in[2];
  const float* Ws0 = (const float*)d_in[3];
  const float* Wn0 = (const float*)d_in[4];
  const float* b0  = (const float*)d_in[5];
  const float* Ws1 = (const float*)d_in[6];
  const float* Wn1 = (const float*)d_in[7];
  const float* b1  = (const float*)d_in[8];
  const float* Ws2 = (const float*)d_in[9];
  const float* Wn2 = (const float*)d_in[10];
  const float* b2  = (const float*)d_in[11];
  float* out = (float*)d_out;

  // ws layout (same 80.2 MB footprint):
  //   rowptr int[50048] | csr int[800000] | h1 25.6MB | h2 25.6MB | Creg 25.6MB
  // Creg: cnt[4*NP4] | cursorP[4*NP4] | bsum (CSR build) -> selfb/u + z2 later.
  char* ws = (char*)d_ws;
  int* rowptr = (int*)ws;
  int* csr    = (int*)(ws + 200192);
  float* h1   = (float*)(ws + 3400192);
  float* h2   = (float*)(ws + 29000192);
  char* Creg  = ws + 54600192;
  float* selfb = (float*)Creg;                              // self / u
  unsigned short* z2 = (unsigned short*)(Creg + 12800000);  // layer-2 z (6.4MB)
  int* cnt     = (int*)Creg;                                // 800768 B
  int* cursorP = (int*)(Creg + 800768);                     // 800768 B
  int* bsum    = (int*)(Creg + 1601536);                    // SCAN1_B ints

  // z for layers 0/1 lives in d_out (12.8 MB exactly; dead before final write)
  unsigned short* zb = (unsigned short*)d_out;

  // split weights staged at h2 base (328 KB)
  unsigned short* wb = (unsigned short*)h2;
  unsigned short* wt0h = wb;
  unsigned short* wt0l = wb + 32768;
  unsigned short* wt1h = wb + 65536;
  unsigned short* wt1l = wb + 98304;
  unsigned short* wt2h = wb + 131072;
  unsigned short* wt2l = wb + 147456;

  // layer-2 weight copy target: h1 base (h1 dead after layer-1 gemm reads it)
  unsigned short* wt2hc = (unsigned short*)h1;
  unsigned short* wt2lc = wt2hc + 16384;

  // CSR build: class-partitioned hist/fill + 4-bank sub-counters + 2-level scan
  hipMemsetAsync(cnt, 0, 4 * NP4 * sizeof(int), stream);
  hist_kernel<<<8 * FILL_CH, 256, 0, stream>>>(dst, cnt);
  scan1_kernel<<<SCAN1_B, 256, 0, stream>>>(cnt, cursorP, bsum);
  scan2_kernel<<<1, 1024, 0, stream>>>(bsum);
  scan3_kernel<<<SCAN1_B, 256, 0, stream>>>(cursorP, rowptr, bsum);
  fill_kernel<<<8 * FILL_CH, 256, 0, stream>>>(src, dst, cursorP, csr);
  wsplit_kernel<<<320, 256, 0, stream>>>(Ws0, Wn0, Ws1, Wn1, Ws2, Wn2, wb);

  // layer 0: self = x@Ws0 + b0 ; z = x@Wn0 (bf16) ; h1 = selu(self + mean(z))
  gemm_dual<256, 128><<<dim3(NT_GEMM, 2), 256, 0, stream>>>(x, wt0h, wt0l, b0, selfb, zb);
  gather_act<<<6250, 256, 0, stream>>>(zb, selfb, rowptr, csr, h1);

  // layer 1: same with h1 -> h2
  gemm_dual<256, 128><<<dim3(NT_GEMM, 2), 256, 0, stream>>>(h1, wt1h, wt1l, b1, selfb, zb);
  hipMemcpyAsync(wt2hc, wt2h, 65536, hipMemcpyDeviceToDevice, stream);  // h1 dead now
  gather_act<<<6250, 256, 0, stream>>>(zb, selfb, rowptr, csr, h2);     // clobbers wb

  // layer 2: u = h2@Ws2 + b2 ; z2 = h2@Wn2 (bf16) ; out = softmax(u + mean(z2))
  gemm_dual<128, 64><<<dim3(NT_GEMM, 1), 256, 0, stream>>>(h2, wt2hc, wt2lc, b2, selfb, z2);
  gather_sm<<<6250, 256, 0, stream>>>(z2, selfb, rowptr, csr, out);
}

// Round 14
// 254.156 us; speedup vs baseline: 1.8865x; 1.0016x over previous
//
#include <hip/hip_runtime.h>
#include <hip/hip_bf16.h>

#define N_NODES 50000
#define N_EDGES 800000
#define D 128
#define NP4 50048       // padded per-bank node count
#define SCAN1_B 782     // (4*NP4)/256
#define NT_GEMM 782     // ceil(N_NODES/64)
#define E_CHUNK 2048
#define FILL_CH 391     // ceil(N_EDGES/E_CHUNK)

typedef __attribute__((ext_vector_type(8))) __bf16 bf16x8;
typedef __attribute__((ext_vector_type(4))) float f32x4;

union U8 {
  bf16x8 v;
  uint4 u;
};

// ---- fp32 -> bf16 helpers ----
__device__ __forceinline__ unsigned short bf16_rne(float x) {
  unsigned u = __builtin_bit_cast(unsigned, x);
  unsigned r = u + 0x7fffu + ((u >> 16) & 1u);
  return (unsigned short)(r >> 16);
}
__device__ __forceinline__ float bf16_f(unsigned short b) {
  unsigned u = ((unsigned)b) << 16;
  return __builtin_bit_cast(float, u);
}
__device__ __forceinline__ void split2(float x, unsigned short& hi, unsigned short& lo) {
  hi = bf16_rne(x);
  lo = bf16_rne(x - bf16_f(hi));
}

__device__ __forceinline__ float selu_f(float x) {
  const float alpha = 1.6732632423543772f;
  const float scale = 1.0507009873554805f;
  return scale * (x > 0.0f ? x : alpha * expm1f(x));
}

// split raw fp32 bits (r0,r1 = 8 dwords) -> bf16 hi/lo fragments (trunc split)
__device__ __forceinline__ void splitF(uint4 r0, uint4 r1, U8& ah, U8& al) {
  unsigned u0 = r0.x, u1 = r0.y, u2 = r0.z, u3 = r0.w;
  unsigned u4 = r1.x, u5 = r1.y, u6 = r1.z, u7 = r1.w;
  ah.u.x = (u0 >> 16) | (u1 & 0xffff0000u);
  ah.u.y = (u2 >> 16) | (u3 & 0xffff0000u);
  ah.u.z = (u4 >> 16) | (u5 & 0xffff0000u);
  ah.u.w = (u6 >> 16) | (u7 & 0xffff0000u);
  unsigned r;
#define LOW(u) __builtin_bit_cast(unsigned, __builtin_bit_cast(float, u) - __builtin_bit_cast(float, u & 0xffff0000u))
  r = LOW(u0); al.u.x = r >> 16;
  r = LOW(u1); al.u.x |= r & 0xffff0000u;
  r = LOW(u2); al.u.y = r >> 16;
  r = LOW(u3); al.u.y |= r & 0xffff0000u;
  r = LOW(u4); al.u.z = r >> 16;
  r = LOW(u5); al.u.z |= r & 0xffff0000u;
  r = LOW(u6); al.u.w = r >> 16;
  r = LOW(u7); al.u.w |= r & 0xffff0000u;
#undef LOW
}

// ================= zero (replaces runtime fillBuffer: 40us -> ~4us) =================
__global__ __launch_bounds__(256) void zero_kernel(int* __restrict__ p, int n) {
  int i = blockIdx.x * 256 + threadIdx.x;
  if (i < n) p[i] = 0;
}

// ================= CSR build =================
// XCD-class partition (class = (dst>>4)&7, block bid: chunk=bid>>3, cls=bid&7)
// + 4-way sub-counters keyed by e&3, layout [p][NP4] (contention spread).
__global__ __launch_bounds__(256) void hist_kernel(const int* __restrict__ dst,
                                                   int* __restrict__ cnt) {
  const int cls = blockIdx.x & 7;
  const int base = (blockIdx.x >> 3) * E_CHUNK + threadIdx.x;
#pragma unroll
  for (int i = 0; i < E_CHUNK / 256; ++i) {
    int e = base + i * 256;
    if (e < N_EDGES) {
      int d = dst[e];
      if (((d >> 4) & 7) == cls) atomicAdd(&cnt[(e & 3) * NP4 + d], 1);
    }
  }
}

// scan1: exclusive scan partials over logical node-major order j=(n<<2)|p,
// reading/writing the transposed [p][NP4] layout.
__global__ __launch_bounds__(256) void scan1_kernel(const int* __restrict__ cnt,
                                                    int* __restrict__ cur,
                                                    int* __restrict__ bsum) {
  __shared__ int s[256];
  const int t = threadIdx.x;
  const int j = blockIdx.x * 256 + t;
  const int n = j >> 2, p = j & 3;
  int v = (n < N_NODES) ? cnt[p * NP4 + n] : 0;
  s[t] = v;
  __syncthreads();
#pragma unroll
  for (int off = 1; off < 256; off <<= 1) {
    int u = (t >= off) ? s[t - off] : 0;
    __syncthreads();
    s[t] += u;
    __syncthreads();
  }
  if (n < N_NODES) cur[p * NP4 + n] = s[t] - v;  // missing block offset
  if (t == 255) bsum[blockIdx.x] = s[255];
}

// scan2: scan the SCAN1_B block sums (<=1024)
__global__ __launch_bounds__(1024) void scan2_kernel(int* __restrict__ bsum) {
  __shared__ int s[1024];
  const int t = threadIdx.x;
  int v = (t < SCAN1_B) ? bsum[t] : 0;
  s[t] = v;
  __syncthreads();
  for (int off = 1; off < 1024; off <<= 1) {
    int u = (t >= off) ? s[t - off] : 0;
    __syncthreads();
    s[t] += u;
    __syncthreads();
  }
  if (t < SCAN1_B) bsum[t] = s[t] - v;  // exclusive
}

// scan3: add block offsets; emit rowptr[n] at p==0
__global__ __launch_bounds__(256) void scan3_kernel(int* __restrict__ cur,
                                                    int* __restrict__ rowptr,
                                                    const int* __restrict__ bsum) {
  const int j = blockIdx.x * 256 + threadIdx.x;
  const int n = j >> 2, p = j & 3;
  if (n < N_NODES) {
    int v = cur[p * NP4 + n] + bsum[blockIdx.x];
    cur[p * NP4 + n] = v;
    if (p == 0) rowptr[n] = v;
  }
}

__global__ __launch_bounds__(256) void fill_kernel(const int* __restrict__ src,
                                                   const int* __restrict__ dst,
                                                   int* __restrict__ cur,
                                                   int* __restrict__ csr_src) {
  const int cls = blockIdx.x & 7;
  const int base = (blockIdx.x >> 3) * E_CHUNK + threadIdx.x;
#pragma unroll
  for (int i = 0; i < E_CHUNK / 256; ++i) {
    int e = base + i * 256;
    if (e < N_EDGES) {
      int d = dst[e];
      if (((d >> 4) & 7) == cls) {
        int pos = atomicAdd(&cur[(e & 3) * NP4 + d], 1);
        csr_src[pos] = src[e];
      }
    }
  }
}

// ================= weight split/transpose precompute =================
// Per-layer B image, K=128, pre-swizzled (si = idx ^ ((n&7)<<3), idx = n*K+k).
__global__ __launch_bounds__(256) void wsplit_kernel(
    const float* __restrict__ Ws0, const float* __restrict__ Wn0,
    const float* __restrict__ Ws1, const float* __restrict__ Wn1,
    const float* __restrict__ Ws2, const float* __restrict__ Wn2,
    unsigned short* __restrict__ wb) {
  int idx = blockIdx.x * 256 + threadIdx.x;
  if (idx < 32768) {
    int n = idx >> 7, k = idx & 127;
    float wv = (n < 128) ? Ws0[k * 128 + n] : Wn0[k * 128 + (n - 128)];
    unsigned short h, l; split2(wv, h, l);
    int si = idx ^ ((n & 7) << 3);
    wb[si] = h; wb[32768 + si] = l;
  } else if (idx < 65536) {
    int j = idx - 32768;
    int n = j >> 7, k = j & 127;
    float wv = (n < 128) ? Ws1[k * 128 + n] : Wn1[k * 128 + (n - 128)];
    unsigned short h, l; split2(wv, h, l);
    int si = j ^ ((n & 7) << 3);
    wb[65536 + si] = h; wb[98304 + si] = l;
  } else if (idx < 81920) {
    int j = idx - 65536;
    int n = j >> 7, k = j & 127;
    float wv = (n < 64) ? Ws2[k * 64 + n] : Wn2[k * 64 + (n - 64)];
    unsigned short h, l; split2(wv, h, l);
    int si = j ^ ((n & 7) << 3);
    wb[131072 + si] = h; wb[147456 + si] = l;
  }
}

// ================= dual-output MFMA GEMM, 128-col panels =================
template <int TC, int ZC>
__global__ __launch_bounds__(256, 2) void gemm_dual(const float* __restrict__ hsrc,
                                                    const unsigned short* __restrict__ wth,
                                                    const unsigned short* __restrict__ wtl,
                                                    const float* __restrict__ bias,
                                                    float* __restrict__ out0,
                                                    unsigned short* __restrict__ out1) {
  constexpr int K = 128;
  __shared__ unsigned short bh_s[128 * K];
  __shared__ unsigned short bl_s[128 * K];

  const int tid = threadIdx.x;
  const int w = tid >> 6;
  const int l = tid & 63;
  const int lr = l & 15;
  const int lg = l >> 4;
  const int cb = blockIdx.y;
  const int colbase = cb * 128;
  const int row0 = blockIdx.x * 64;
  const int arow = min(row0 + w * 16 + lr, N_NODES - 1);

  uint4 a[8];
  {
    const uint4* hp = (const uint4*)(hsrc + (size_t)arow * D);
#pragma unroll
    for (int q = 0; q < 2; ++q)
#pragma unroll
      for (int kt = 0; kt < 2; ++kt) {
        a[q * 4 + kt * 2 + 0] = hp[q * 16 + kt * 8 + lg * 2];
        a[q * 4 + kt * 2 + 1] = hp[q * 16 + kt * 8 + lg * 2 + 1];
      }
  }

  {
    const uint4* gh = (const uint4*)(wth + (size_t)colbase * K);
    const uint4* gl = (const uint4*)(wtl + (size_t)colbase * K);
    uint4* sh = (uint4*)bh_s;
    uint4* sl = (uint4*)bl_s;
#pragma unroll
    for (int i = 0; i < 8; ++i) {
      sh[tid + i * 256] = gh[tid + i * 256];
      sl[tid + i * 256] = gl[tid + i * 256];
    }
  }
  __syncthreads();

  f32x4 accA[8], accB[8];
#pragma unroll
  for (int i = 0; i < 8; ++i) {
    accA[i] = (f32x4){0.f, 0.f, 0.f, 0.f};
    accB[i] = (f32x4){0.f, 0.f, 0.f, 0.f};
  }

#pragma unroll
  for (int q = 0; q < 2; ++q) {
#pragma unroll
    for (int kt = 0; kt < 2; ++kt) {
      U8 ah, al;
      splitF(a[q * 4 + kt * 2], a[q * 4 + kt * 2 + 1], ah, al);
      const int kb = q * 64 + (((((kt << 2) | lg)) ^ (lr & 7)) << 3);
#pragma unroll
      for (int nf = 0; nf < 8; ++nf) {
        const int si = (nf * 16 + lr) * K + kb;
        bf16x8 bh = *(const bf16x8*)&bh_s[si];
        bf16x8 bl = *(const bf16x8*)&bl_s[si];
        accA[nf] = __builtin_amdgcn_mfma_f32_16x16x32_bf16(ah.v, bh, accA[nf], 0, 0, 0);
        accB[nf] = __builtin_amdgcn_mfma_f32_16x16x32_bf16(al.v, bh, accB[nf], 0, 0, 0);
        accB[nf] = __builtin_amdgcn_mfma_f32_16x16x32_bf16(ah.v, bl, accB[nf], 0, 0, 0);
      }
    }
  }

#pragma unroll
  for (int nf = 0; nf < 8; ++nf) {
    const int col = colbase + nf * 16 + lr;
#pragma unroll
    for (int i = 0; i < 4; ++i) {
      const int grow = row0 + w * 16 + lg * 4 + i;
      if (grow < N_NODES) {
        float v = accA[nf][i] + accB[nf][i];
        if (col < ZC) {
          out0[(size_t)grow * ZC + col] = v + bias[col];
        } else {
          out1[(size_t)grow * (TC - ZC) + (col - ZC)] = bf16_rne(v);
        }
      }
    }
  }
}

// ================= gather mean(z bf16) + self + SELU -> h_next =================
__global__ __launch_bounds__(256) void gather_act(const unsigned short* __restrict__ zb,
                                                  const float* __restrict__ selfb,
                                                  const int* __restrict__ rowptr,
                                                  const int* __restrict__ csr,
                                                  float* __restrict__ hnext) {
  const int n = blockIdx.x * 8 + (threadIdx.x >> 5);
  const int sl = threadIdx.x & 31;
  const int start = rowptr[n];
  const int end = (n < N_NODES - 1) ? rowptr[n + 1] : N_EDGES;
  const ushort4* zp = (const ushort4*)zb + sl;  // row stride = 32 ushort4
  float ax = 0.f, ay = 0.f, az = 0.f, aw = 0.f;
#define ACC4(v) { ax += bf16_f(v.x); ay += bf16_f(v.y); az += bf16_f(v.z); aw += bf16_f(v.w); }
  int e = start;
  for (; e + 7 < end; e += 8) {
    int s0 = csr[e],     s1 = csr[e + 1], s2 = csr[e + 2], s3 = csr[e + 3];
    int s4 = csr[e + 4], s5 = csr[e + 5], s6 = csr[e + 6], s7 = csr[e + 7];
    ushort4 v0 = zp[(size_t)s0 * 32];
    ushort4 v1 = zp[(size_t)s1 * 32];
    ushort4 v2 = zp[(size_t)s2 * 32];
    ushort4 v3 = zp[(size_t)s3 * 32];
    ushort4 v4 = zp[(size_t)s4 * 32];
    ushort4 v5 = zp[(size_t)s5 * 32];
    ushort4 v6 = zp[(size_t)s6 * 32];
    ushort4 v7 = zp[(size_t)s7 * 32];
    ACC4(v0) ACC4(v1) ACC4(v2) ACC4(v3) ACC4(v4) ACC4(v5) ACC4(v6) ACC4(v7)
  }
  if (e + 3 < end) {
    int s0 = csr[e], s1 = csr[e + 1], s2 = csr[e + 2], s3 = csr[e + 3];
    ushort4 v0 = zp[(size_t)s0 * 32];
    ushort4 v1 = zp[(size_t)s1 * 32];
    ushort4 v2 = zp[(size_t)s2 * 32];
    ushort4 v3 = zp[(size_t)s3 * 32];
    ACC4(v0) ACC4(v1) ACC4(v2) ACC4(v3)
    e += 4;
  }
  for (; e < end; ++e) {
    ushort4 v0 = zp[(size_t)csr[e] * 32];
    ACC4(v0)
  }
#undef ACC4
  float inv = 1.0f / (float)max(end - start, 1);
  float4 sv = *(const float4*)(selfb + (size_t)n * D + sl * 4);
  float4 o;
  o.x = selu_f(sv.x + ax * inv);
  o.y = selu_f(sv.y + ay * inv);
  o.z = selu_f(sv.z + az * inv);
  o.w = selu_f(sv.w + aw * inv);
  *(float4*)(hnext + (size_t)n * D + sl * 4) = o;
}

// ================= gather mean(z2 bf16) + u + softmax -> out =================
__global__ __launch_bounds__(256) void gather_sm(const unsigned short* __restrict__ z2,
                                                 const float* __restrict__ u,
                                                 const int* __restrict__ rowptr,
                                                 const int* __restrict__ csr,
                                                 float* __restrict__ out) {
  const int n = blockIdx.x * 8 + (threadIdx.x >> 5);
  const int sl = threadIdx.x & 31;
  const int start = rowptr[n];
  const int end = (n < N_NODES - 1) ? rowptr[n + 1] : N_EDGES;
  const ushort2* zp = (const ushort2*)z2 + sl;  // row stride = 32 ushort2
  float ax = 0.f, ay = 0.f;
#define ACC2(v) { ax += bf16_f(v.x); ay += bf16_f(v.y); }
  int e = start;
  for (; e + 7 < end; e += 8) {
    int s0 = csr[e],     s1 = csr[e + 1], s2 = csr[e + 2], s3 = csr[e + 3];
    int s4 = csr[e + 4], s5 = csr[e + 5], s6 = csr[e + 6], s7 = csr[e + 7];
    ushort2 v0 = zp[(size_t)s0 * 32];
    ushort2 v1 = zp[(size_t)s1 * 32];
    ushort2 v2 = zp[(size_t)s2 * 32];
    ushort2 v3 = zp[(size_t)s3 * 32];
    ushort2 v4 = zp[(size_t)s4 * 32];
    ushort2 v5 = zp[(size_t)s5 * 32];
    ushort2 v6 = zp[(size_t)s6 * 32];
    ushort2 v7 = zp[(size_t)s7 * 32];
    ACC2(v0) ACC2(v1) ACC2(v2) ACC2(v3) ACC2(v4) ACC2(v5) ACC2(v6) ACC2(v7)
  }
  if (e + 3 < end) {
    int s0 = csr[e], s1 = csr[e + 1], s2 = csr[e + 2], s3 = csr[e + 3];
    ushort2 v0 = zp[(size_t)s0 * 32];
    ushort2 v1 = zp[(size_t)s1 * 32];
    ushort2 v2 = zp[(size_t)s2 * 32];
    ushort2 v3 = zp[(size_t)s3 * 32];
    ACC2(v0) ACC2(v1) ACC2(v2) ACC2(v3)
    e += 4;
  }
  for (; e < end; ++e) {
    ushort2 v0 = zp[(size_t)csr[e] * 32];
    ACC2(v0)
  }
#undef ACC2
  float inv = 1.0f / (float)max(end - start, 1);
  size_t o = (size_t)n * 64 + sl * 2;
  float vx = u[o] + ax * inv;
  float vy = u[o + 1] + ay * inv;
  float m = fmaxf(vx, vy);
#pragma unroll
  for (int off = 16; off > 0; off >>= 1) m = fmaxf(m, __shfl_xor(m, off, 64));
  float ex = expf(vx - m);
  float ey = expf(vy - m);
  float s = ex + ey;
#pragma unroll
  for (int off = 16; off > 0; off >>= 1) s += __shfl_xor(s, off, 64);
  float r = 1.0f / s;
  out[o] = ex * r;
  out[o + 1] = ey * r;
}

extern "C" void kernel_launch(void* const* d_in, const int* in_sizes, int n_in,
                              void* d_out, int out_size, void* d_ws, size_t ws_size,
                              hipStream_t stream) {
  const float* x   = (const float*)d_in[0];
  const int* src   = (const int*)d_in[1];
  const int* dst   = (const int*)d_in[2];
  const float* Ws0 = (const float*)d_in[3];
  const float* Wn0 = (const float*)d_in[4];
  const float* b0  = (const float*)d_in[5];
  const float* Ws1 = (const float*)d_in[6];
  const float* Wn1 = (const float*)d_in[7];
  const float* b1  = (const float*)d_in[8];
  const float* Ws2 = (const float*)d_in[9];
  const float* Wn2 = (const float*)d_in[10];
  const float* b2  = (const float*)d_in[11];
  float* out = (float*)d_out;

  // ws layout (same 80.2 MB footprint):
  //   rowptr int[50048] | csr int[800000] | h1 25.6MB | h2 25.6MB | Creg 25.6MB
  // Creg: cnt[4*NP4] | cursorP[4*NP4] | bsum (CSR build) -> selfb/u + z2 later.
  char* ws = (char*)d_ws;
  int* rowptr = (int*)ws;
  int* csr    = (int*)(ws + 200192);
  float* h1   = (float*)(ws + 3400192);
  float* h2   = (float*)(ws + 29000192);
  char* Creg  = ws + 54600192;
  float* selfb = (float*)Creg;                              // self / u
  unsigned short* z2 = (unsigned short*)(Creg + 12800000);  // layer-2 z (6.4MB)
  int* cnt     = (int*)Creg;                                // 800768 B
  int* cursorP = (int*)(Creg + 800768);                     // 800768 B
  int* bsum    = (int*)(Creg + 1601536);                    // SCAN1_B ints

  // z for layers 0/1 lives in d_out (12.8 MB exactly; dead before final write)
  unsigned short* zb = (unsigned short*)d_out;

  // split weights staged at h2 base (328 KB)
  unsigned short* wb = (unsigned short*)h2;
  unsigned short* wt0h = wb;
  unsigned short* wt0l = wb + 32768;
  unsigned short* wt1h = wb + 65536;
  unsigned short* wt1l = wb + 98304;
  unsigned short* wt2h = wb + 131072;
  unsigned short* wt2l = wb + 147456;

  // layer-2 weight copy target: h1 base (h1 dead after layer-1 gemm reads it)
  unsigned short* wt2hc = (unsigned short*)h1;
  unsigned short* wt2lc = wt2hc + 16384;

  // CSR build: custom zero + class-partitioned hist/fill + 4-bank sub-counters
  zero_kernel<<<SCAN1_B, 256, 0, stream>>>(cnt, 4 * NP4);
  hist_kernel<<<8 * FILL_CH, 256, 0, stream>>>(dst, cnt);
  scan1_kernel<<<SCAN1_B, 256, 0, stream>>>(cnt, cursorP, bsum);
  scan2_kernel<<<1, 1024, 0, stream>>>(bsum);
  scan3_kernel<<<SCAN1_B, 256, 0, stream>>>(cursorP, rowptr, bsum);
  fill_kernel<<<8 * FILL_CH, 256, 0, stream>>>(src, dst, cursorP, csr);
  wsplit_kernel<<<320, 256, 0, stream>>>(Ws0, Wn0, Ws1, Wn1, Ws2, Wn2, wb);

  // layer 0: self = x@Ws0 + b0 ; z = x@Wn0 (bf16) ; h1 = selu(self + mean(z))
  gemm_dual<256, 128><<<dim3(NT_GEMM, 2), 256, 0, stream>>>(x, wt0h, wt0l, b0, selfb, zb);
  gather_act<<<6250, 256, 0, stream>>>(zb, selfb, rowptr, csr, h1);

  // layer 1: same with h1 -> h2
  gemm_dual<256, 128><<<dim3(NT_GEMM, 2), 256, 0, stream>>>(h1, wt1h, wt1l, b1, selfb, zb);
  hipMemcpyAsync(wt2hc, wt2h, 65536, hipMemcpyDeviceToDevice, stream);  // h1 dead now
  gather_act<<<6250, 256, 0, stream>>>(zb, selfb, rowptr, csr, h2);     // clobbers wb

  // layer 2: u = h2@Ws2 + b2 ; z2 = h2@Wn2 (bf16) ; out = softmax(u + mean(z2))
  gemm_dual<128, 64><<<dim3(NT_GEMM, 1), 256, 0, stream>>>(h2, wt2hc, wt2lc, b2, selfb, z2);
  gather_sm<<<6250, 256, 0, stream>>>(z2, selfb, rowptr, csr, out);
}

// Round 15
// 251.248 us; speedup vs baseline: 1.9084x; 1.0116x over previous
//
#include <hip/hip_runtime.h>
#include <hip/hip_bf16.h>

#define N_NODES 50000
#define N_EDGES 800000
#define D 128
#define NP4 50048       // padded per-bank node count
#define SCAN1_B 782     // (4*NP4)/256
#define NT_GEMM 782     // ceil(N_NODES/64)
#define E_CHUNK 2048
#define FILL_CH 391     // ceil(N_EDGES/E_CHUNK)

typedef __attribute__((ext_vector_type(8))) __bf16 bf16x8;
typedef __attribute__((ext_vector_type(4))) float f32x4;

union U8 {
  bf16x8 v;
  uint4 u;
};

// ---- fp32 -> bf16 helpers ----
__device__ __forceinline__ unsigned short bf16_rne(float x) {
  unsigned u = __builtin_bit_cast(unsigned, x);
  unsigned r = u + 0x7fffu + ((u >> 16) & 1u);
  return (unsigned short)(r >> 16);
}
__device__ __forceinline__ float bf16_f(unsigned short b) {
  unsigned u = ((unsigned)b) << 16;
  return __builtin_bit_cast(float, u);
}
__device__ __forceinline__ void split2(float x, unsigned short& hi, unsigned short& lo) {
  hi = bf16_rne(x);
  lo = bf16_rne(x - bf16_f(hi));
}

__device__ __forceinline__ float selu_f(float x) {
  const float alpha = 1.6732632423543772f;
  const float scale = 1.0507009873554805f;
  return scale * (x > 0.0f ? x : alpha * expm1f(x));
}

// split raw fp32 bits (r0,r1 = 8 dwords) -> bf16 hi/lo fragments (trunc split)
__device__ __forceinline__ void splitF(uint4 r0, uint4 r1, U8& ah, U8& al) {
  unsigned u0 = r0.x, u1 = r0.y, u2 = r0.z, u3 = r0.w;
  unsigned u4 = r1.x, u5 = r1.y, u6 = r1.z, u7 = r1.w;
  ah.u.x = (u0 >> 16) | (u1 & 0xffff0000u);
  ah.u.y = (u2 >> 16) | (u3 & 0xffff0000u);
  ah.u.z = (u4 >> 16) | (u5 & 0xffff0000u);
  ah.u.w = (u6 >> 16) | (u7 & 0xffff0000u);
  unsigned r;
#define LOW(u) __builtin_bit_cast(unsigned, __builtin_bit_cast(float, u) - __builtin_bit_cast(float, u & 0xffff0000u))
  r = LOW(u0); al.u.x = r >> 16;
  r = LOW(u1); al.u.x |= r & 0xffff0000u;
  r = LOW(u2); al.u.y = r >> 16;
  r = LOW(u3); al.u.y |= r & 0xffff0000u;
  r = LOW(u4); al.u.z = r >> 16;
  r = LOW(u5); al.u.z |= r & 0xffff0000u;
  r = LOW(u6); al.u.w = r >> 16;
  r = LOW(u7); al.u.w |= r & 0xffff0000u;
#undef LOW
}

// ================= zero =================
__global__ __launch_bounds__(256) void zero_kernel(int* __restrict__ p, int n) {
  int i = blockIdx.x * 256 + threadIdx.x;
  if (i < n) p[i] = 0;
}

// ================= CSR build =================
// XCD-class partition (class = (dst>>4)&7, block bid: chunk=bid>>3, cls=bid&7)
// + 4-way sub-counters keyed by e&3, layout [p][NP4] (contention spread).
__global__ __launch_bounds__(256) void hist_kernel(const int* __restrict__ dst,
                                                   int* __restrict__ cnt) {
  const int cls = blockIdx.x & 7;
  const int base = (blockIdx.x >> 3) * E_CHUNK + threadIdx.x;
#pragma unroll
  for (int i = 0; i < E_CHUNK / 256; ++i) {
    int e = base + i * 256;
    if (e < N_EDGES) {
      int d = dst[e];
      if (((d >> 4) & 7) == cls) atomicAdd(&cnt[(e & 3) * NP4 + d], 1);
    }
  }
}

// scan1: exclusive scan partials over logical node-major order j=(n<<2)|p,
// reading/writing the transposed [p][NP4] layout.
__global__ __launch_bounds__(256) void scan1_kernel(const int* __restrict__ cnt,
                                                    int* __restrict__ cur,
                                                    int* __restrict__ bsum) {
  __shared__ int s[256];
  const int t = threadIdx.x;
  const int j = blockIdx.x * 256 + t;
  const int n = j >> 2, p = j & 3;
  int v = (n < N_NODES) ? cnt[p * NP4 + n] : 0;
  s[t] = v;
  __syncthreads();
#pragma unroll
  for (int off = 1; off < 256; off <<= 1) {
    int u = (t >= off) ? s[t - off] : 0;
    __syncthreads();
    s[t] += u;
    __syncthreads();
  }
  if (n < N_NODES) cur[p * NP4 + n] = s[t] - v;  // missing block offset
  if (t == 255) bsum[blockIdx.x] = s[255];
}

// scan2: scan the SCAN1_B block sums (<=1024)
__global__ __launch_bounds__(1024) void scan2_kernel(int* __restrict__ bsum) {
  __shared__ int s[1024];
  const int t = threadIdx.x;
  int v = (t < SCAN1_B) ? bsum[t] : 0;
  s[t] = v;
  __syncthreads();
  for (int off = 1; off < 1024; off <<= 1) {
    int u = (t >= off) ? s[t - off] : 0;
    __syncthreads();
    s[t] += u;
    __syncthreads();
  }
  if (t < SCAN1_B) bsum[t] = s[t] - v;  // exclusive
}

// scan3: add block offsets; emit rowptr[n] at p==0
__global__ __launch_bounds__(256) void scan3_kernel(int* __restrict__ cur,
                                                    int* __restrict__ rowptr,
                                                    const int* __restrict__ bsum) {
  const int j = blockIdx.x * 256 + threadIdx.x;
  const int n = j >> 2, p = j & 3;
  if (n < N_NODES) {
    int v = cur[p * NP4 + n] + bsum[blockIdx.x];
    cur[p * NP4 + n] = v;
    if (p == 0) rowptr[n] = v;
  }
}

__global__ __launch_bounds__(256) void fill_kernel(const int* __restrict__ src,
                                                   const int* __restrict__ dst,
                                                   int* __restrict__ cur,
                                                   int* __restrict__ csr_src) {
  const int cls = blockIdx.x & 7;
  const int base = (blockIdx.x >> 3) * E_CHUNK + threadIdx.x;
#pragma unroll
  for (int i = 0; i < E_CHUNK / 256; ++i) {
    int e = base + i * 256;
    if (e < N_EDGES) {
      int d = dst[e];
      if (((d >> 4) & 7) == cls) {
        int pos = atomicAdd(&cur[(e & 3) * NP4 + d], 1);
        csr_src[pos] = src[e];
      }
    }
  }
}

// ================= weight split/transpose precompute =================
// Per-layer B image, K=128, pre-swizzled (si = idx ^ ((n&7)<<3), idx = n*K+k).
__global__ __launch_bounds__(256) void wsplit_kernel(
    const float* __restrict__ Ws0, const float* __restrict__ Wn0,
    const float* __restrict__ Ws1, const float* __restrict__ Wn1,
    const float* __restrict__ Ws2, const float* __restrict__ Wn2,
    unsigned short* __restrict__ wb) {
  int idx = blockIdx.x * 256 + threadIdx.x;
  if (idx < 32768) {
    int n = idx >> 7, k = idx & 127;
    float wv = (n < 128) ? Ws0[k * 128 + n] : Wn0[k * 128 + (n - 128)];
    unsigned short h, l; split2(wv, h, l);
    int si = idx ^ ((n & 7) << 3);
    wb[si] = h; wb[32768 + si] = l;
  } else if (idx < 65536) {
    int j = idx - 32768;
    int n = j >> 7, k = j & 127;
    float wv = (n < 128) ? Ws1[k * 128 + n] : Wn1[k * 128 + (n - 128)];
    unsigned short h, l; split2(wv, h, l);
    int si = j ^ ((n & 7) << 3);
    wb[65536 + si] = h; wb[98304 + si] = l;
  } else if (idx < 81920) {
    int j = idx - 65536;
    int n = j >> 7, k = j & 127;
    float wv = (n < 64) ? Ws2[k * 64 + n] : Wn2[k * 64 + (n - 64)];
    unsigned short h, l; split2(wv, h, l);
    int si = j ^ ((n & 7) << 3);
    wb[131072 + si] = h; wb[147456 + si] = l;
  }
}

// ================= fused dual-panel MFMA GEMM (L0/L1) =================
// Block = 64 rows x 256 cols, two sequential 128-col panels sharing one
// register-resident A slice (A fetched ONCE). Panel 0 -> fp32 self (+bias),
// panel 1 -> bf16 z. LDS 64KB reused per panel -> 2 blocks/CU.
__global__ __launch_bounds__(256, 2) void gemm_dual2(const float* __restrict__ hsrc,
                                                     const unsigned short* __restrict__ wth,
                                                     const unsigned short* __restrict__ wtl,
                                                     const float* __restrict__ bias,
                                                     float* __restrict__ out0,
                                                     unsigned short* __restrict__ out1) {
  constexpr int K = 128;
  __shared__ unsigned short bh_s[128 * K];
  __shared__ unsigned short bl_s[128 * K];

  const int tid = threadIdx.x;
  const int w = tid >> 6;
  const int l = tid & 63;
  const int lr = l & 15;
  const int lg = l >> 4;
  const int row0 = blockIdx.x * 64;
  const int arow = min(row0 + w * 16 + lr, N_NODES - 1);

  // ---- A slice: fetched once, reused for both panels ----
  uint4 a[8];
  {
    const uint4* hp = (const uint4*)(hsrc + (size_t)arow * D);
#pragma unroll
    for (int q = 0; q < 2; ++q)
#pragma unroll
      for (int kt = 0; kt < 2; ++kt) {
        a[q * 4 + kt * 2 + 0] = hp[q * 16 + kt * 8 + lg * 2];
        a[q * 4 + kt * 2 + 1] = hp[q * 16 + kt * 8 + lg * 2 + 1];
      }
  }

#pragma unroll
  for (int cb = 0; cb < 2; ++cb) {
    if (cb) __syncthreads();  // WAR: all panel-0 LDS reads complete
    // ---- stage panel cb (pre-swizzled, linear copy) ----
    {
      const uint4* gh = (const uint4*)(wth + (size_t)cb * 128 * K);
      const uint4* gl = (const uint4*)(wtl + (size_t)cb * 128 * K);
      uint4* sh = (uint4*)bh_s;
      uint4* sl = (uint4*)bl_s;
#pragma unroll
      for (int i = 0; i < 8; ++i) {
        sh[tid + i * 256] = gh[tid + i * 256];
        sl[tid + i * 256] = gl[tid + i * 256];
      }
    }
    __syncthreads();

    f32x4 accA[8], accB[8];
#pragma unroll
    for (int i = 0; i < 8; ++i) {
      accA[i] = (f32x4){0.f, 0.f, 0.f, 0.f};
      accB[i] = (f32x4){0.f, 0.f, 0.f, 0.f};
    }

#pragma unroll
    for (int q = 0; q < 2; ++q) {
#pragma unroll
      for (int kt = 0; kt < 2; ++kt) {
        U8 ah, al;
        splitF(a[q * 4 + kt * 2], a[q * 4 + kt * 2 + 1], ah, al);
        const int kb = q * 64 + (((((kt << 2) | lg)) ^ (lr & 7)) << 3);
#pragma unroll
        for (int nf = 0; nf < 8; ++nf) {
          const int si = (nf * 16 + lr) * K + kb;
          bf16x8 bh = *(const bf16x8*)&bh_s[si];
          bf16x8 bl = *(const bf16x8*)&bl_s[si];
          accA[nf] = __builtin_amdgcn_mfma_f32_16x16x32_bf16(ah.v, bh, accA[nf], 0, 0, 0);
          accB[nf] = __builtin_amdgcn_mfma_f32_16x16x32_bf16(al.v, bh, accB[nf], 0, 0, 0);
          accB[nf] = __builtin_amdgcn_mfma_f32_16x16x32_bf16(ah.v, bl, accB[nf], 0, 0, 0);
        }
      }
    }

    // epilogue: panel 0 -> fp32 self (+bias); panel 1 -> bf16 z
#pragma unroll
    for (int nf = 0; nf < 8; ++nf) {
      const int col = nf * 16 + lr;  // within-panel column [0,128)
      const float bv = (cb == 0) ? bias[col] : 0.0f;
#pragma unroll
      for (int i = 0; i < 4; ++i) {
        const int grow = row0 + w * 16 + lg * 4 + i;
        if (grow < N_NODES) {
          float v = accA[nf][i] + accB[nf][i];
          if (cb == 0) {
            out0[(size_t)grow * 128 + col] = v + bv;
          } else {
            out1[(size_t)grow * 128 + col] = bf16_rne(v);
          }
        }
      }
    }
  }
}

// ================= single-panel MFMA GEMM (L2) =================
template <int TC, int ZC>
__global__ __launch_bounds__(256, 2) void gemm_dual(const float* __restrict__ hsrc,
                                                    const unsigned short* __restrict__ wth,
                                                    const unsigned short* __restrict__ wtl,
                                                    const float* __restrict__ bias,
                                                    float* __restrict__ out0,
                                                    unsigned short* __restrict__ out1) {
  constexpr int K = 128;
  __shared__ unsigned short bh_s[128 * K];
  __shared__ unsigned short bl_s[128 * K];

  const int tid = threadIdx.x;
  const int w = tid >> 6;
  const int l = tid & 63;
  const int lr = l & 15;
  const int lg = l >> 4;
  const int cb = blockIdx.y;
  const int colbase = cb * 128;
  const int row0 = blockIdx.x * 64;
  const int arow = min(row0 + w * 16 + lr, N_NODES - 1);

  uint4 a[8];
  {
    const uint4* hp = (const uint4*)(hsrc + (size_t)arow * D);
#pragma unroll
    for (int q = 0; q < 2; ++q)
#pragma unroll
      for (int kt = 0; kt < 2; ++kt) {
        a[q * 4 + kt * 2 + 0] = hp[q * 16 + kt * 8 + lg * 2];
        a[q * 4 + kt * 2 + 1] = hp[q * 16 + kt * 8 + lg * 2 + 1];
      }
  }

  {
    const uint4* gh = (const uint4*)(wth + (size_t)colbase * K);
    const uint4* gl = (const uint4*)(wtl + (size_t)colbase * K);
    uint4* sh = (uint4*)bh_s;
    uint4* sl = (uint4*)bl_s;
#pragma unroll
    for (int i = 0; i < 8; ++i) {
      sh[tid + i * 256] = gh[tid + i * 256];
      sl[tid + i * 256] = gl[tid + i * 256];
    }
  }
  __syncthreads();

  f32x4 accA[8], accB[8];
#pragma unroll
  for (int i = 0; i < 8; ++i) {
    accA[i] = (f32x4){0.f, 0.f, 0.f, 0.f};
    accB[i] = (f32x4){0.f, 0.f, 0.f, 0.f};
  }

#pragma unroll
  for (int q = 0; q < 2; ++q) {
#pragma unroll
    for (int kt = 0; kt < 2; ++kt) {
      U8 ah, al;
      splitF(a[q * 4 + kt * 2], a[q * 4 + kt * 2 + 1], ah, al);
      const int kb = q * 64 + (((((kt << 2) | lg)) ^ (lr & 7)) << 3);
#pragma unroll
      for (int nf = 0; nf < 8; ++nf) {
        const int si = (nf * 16 + lr) * K + kb;
        bf16x8 bh = *(const bf16x8*)&bh_s[si];
        bf16x8 bl = *(const bf16x8*)&bl_s[si];
        accA[nf] = __builtin_amdgcn_mfma_f32_16x16x32_bf16(ah.v, bh, accA[nf], 0, 0, 0);
        accB[nf] = __builtin_amdgcn_mfma_f32_16x16x32_bf16(al.v, bh, accB[nf], 0, 0, 0);
        accB[nf] = __builtin_amdgcn_mfma_f32_16x16x32_bf16(ah.v, bl, accB[nf], 0, 0, 0);
      }
    }
  }

#pragma unroll
  for (int nf = 0; nf < 8; ++nf) {
    const int col = colbase + nf * 16 + lr;
#pragma unroll
    for (int i = 0; i < 4; ++i) {
      const int grow = row0 + w * 16 + lg * 4 + i;
      if (grow < N_NODES) {
        float v = accA[nf][i] + accB[nf][i];
        if (col < ZC) {
          out0[(size_t)grow * ZC + col] = v + bias[col];
        } else {
          out1[(size_t)grow * (TC - ZC) + (col - ZC)] = bf16_rne(v);
        }
      }
    }
  }
}

// ================= gather mean(z bf16) + self + SELU -> h_next =================
__global__ __launch_bounds__(256) void gather_act(const unsigned short* __restrict__ zb,
                                                  const float* __restrict__ selfb,
                                                  const int* __restrict__ rowptr,
                                                  const int* __restrict__ csr,
                                                  float* __restrict__ hnext) {
  const int n = blockIdx.x * 8 + (threadIdx.x >> 5);
  const int sl = threadIdx.x & 31;
  const int start = rowptr[n];
  const int end = (n < N_NODES - 1) ? rowptr[n + 1] : N_EDGES;
  const ushort4* zp = (const ushort4*)zb + sl;  // row stride = 32 ushort4
  float ax = 0.f, ay = 0.f, az = 0.f, aw = 0.f;
#define ACC4(v) { ax += bf16_f(v.x); ay += bf16_f(v.y); az += bf16_f(v.z); aw += bf16_f(v.w); }
  int e = start;
  for (; e + 7 < end; e += 8) {
    int s0 = csr[e],     s1 = csr[e + 1], s2 = csr[e + 2], s3 = csr[e + 3];
    int s4 = csr[e + 4], s5 = csr[e + 5], s6 = csr[e + 6], s7 = csr[e + 7];
    ushort4 v0 = zp[(size_t)s0 * 32];
    ushort4 v1 = zp[(size_t)s1 * 32];
    ushort4 v2 = zp[(size_t)s2 * 32];
    ushort4 v3 = zp[(size_t)s3 * 32];
    ushort4 v4 = zp[(size_t)s4 * 32];
    ushort4 v5 = zp[(size_t)s5 * 32];
    ushort4 v6 = zp[(size_t)s6 * 32];
    ushort4 v7 = zp[(size_t)s7 * 32];
    ACC4(v0) ACC4(v1) ACC4(v2) ACC4(v3) ACC4(v4) ACC4(v5) ACC4(v6) ACC4(v7)
  }
  if (e + 3 < end) {
    int s0 = csr[e], s1 = csr[e + 1], s2 = csr[e + 2], s3 = csr[e + 3];
    ushort4 v0 = zp[(size_t)s0 * 32];
    ushort4 v1 = zp[(size_t)s1 * 32];
    ushort4 v2 = zp[(size_t)s2 * 32];
    ushort4 v3 = zp[(size_t)s3 * 32];
    ACC4(v0) ACC4(v1) ACC4(v2) ACC4(v3)
    e += 4;
  }
  for (; e < end; ++e) {
    ushort4 v0 = zp[(size_t)csr[e] * 32];
    ACC4(v0)
  }
#undef ACC4
  float inv = 1.0f / (float)max(end - start, 1);
  float4 sv = *(const float4*)(selfb + (size_t)n * D + sl * 4);
  float4 o;
  o.x = selu_f(sv.x + ax * inv);
  o.y = selu_f(sv.y + ay * inv);
  o.z = selu_f(sv.z + az * inv);
  o.w = selu_f(sv.w + aw * inv);
  *(float4*)(hnext + (size_t)n * D + sl * 4) = o;
}

// ================= gather mean(z2 bf16) + u + softmax -> out =================
__global__ __launch_bounds__(256) void gather_sm(const unsigned short* __restrict__ z2,
                                                 const float* __restrict__ u,
                                                 const int* __restrict__ rowptr,
                                                 const int* __restrict__ csr,
                                                 float* __restrict__ out) {
  const int n = blockIdx.x * 8 + (threadIdx.x >> 5);
  const int sl = threadIdx.x & 31;
  const int start = rowptr[n];
  const int end = (n < N_NODES - 1) ? rowptr[n + 1] : N_EDGES;
  const ushort2* zp = (const ushort2*)z2 + sl;  // row stride = 32 ushort2
  float ax = 0.f, ay = 0.f;
#define ACC2(v) { ax += bf16_f(v.x); ay += bf16_f(v.y); }
  int e = start;
  for (; e + 7 < end; e += 8) {
    int s0 = csr[e],     s1 = csr[e + 1], s2 = csr[e + 2], s3 = csr[e + 3];
    int s4 = csr[e + 4], s5 = csr[e + 5], s6 = csr[e + 6], s7 = csr[e + 7];
    ushort2 v0 = zp[(size_t)s0 * 32];
    ushort2 v1 = zp[(size_t)s1 * 32];
    ushort2 v2 = zp[(size_t)s2 * 32];
    ushort2 v3 = zp[(size_t)s3 * 32];
    ushort2 v4 = zp[(size_t)s4 * 32];
    ushort2 v5 = zp[(size_t)s5 * 32];
    ushort2 v6 = zp[(size_t)s6 * 32];
    ushort2 v7 = zp[(size_t)s7 * 32];
    ACC2(v0) ACC2(v1) ACC2(v2) ACC2(v3) ACC2(v4) ACC2(v5) ACC2(v6) ACC2(v7)
  }
  if (e + 3 < end) {
    int s0 = csr[e], s1 = csr[e + 1], s2 = csr[e + 2], s3 = csr[e + 3];
    ushort2 v0 = zp[(size_t)s0 * 32];
    ushort2 v1 = zp[(size_t)s1 * 32];
    ushort2 v2 = zp[(size_t)s2 * 32];
    ushort2 v3 = zp[(size_t)s3 * 32];
    ACC2(v0) ACC2(v1) ACC2(v2) ACC2(v3)
    e += 4;
  }
  for (; e < end; ++e) {
    ushort2 v0 = zp[(size_t)csr[e] * 32];
    ACC2(v0)
  }
#undef ACC2
  float inv = 1.0f / (float)max(end - start, 1);
  size_t o = (size_t)n * 64 + sl * 2;
  float vx = u[o] + ax * inv;
  float vy = u[o + 1] + ay * inv;
  float m = fmaxf(vx, vy);
#pragma unroll
  for (int off = 16; off > 0; off >>= 1) m = fmaxf(m, __shfl_xor(m, off, 64));
  float ex = expf(vx - m);
  float ey = expf(vy - m);
  float s = ex + ey;
#pragma unroll
  for (int off = 16; off > 0; off >>= 1) s += __shfl_xor(s, off, 64);
  float r = 1.0f / s;
  out[o] = ex * r;
  out[o + 1] = ey * r;
}

extern "C" void kernel_launch(void* const* d_in, const int* in_sizes, int n_in,
                              void* d_out, int out_size, void* d_ws, size_t ws_size,
                              hipStream_t stream) {
  const float* x   = (const float*)d_in[0];
  const int* src   = (const int*)d_in[1];
  const int* dst   = (const int*)d_in[2];
  const float* Ws0 = (const float*)d_in[3];
  const float* Wn0 = (const float*)d_in[4];
  const float* b0  = (const float*)d_in[5];
  const float* Ws1 = (const float*)d_in[6];
  const float* Wn1 = (const float*)d_in[7];
  const float* b1  = (const float*)d_in[8];
  const float* Ws2 = (const float*)d_in[9];
  const float* Wn2 = (const float*)d_in[10];
  const float* b2  = (const float*)d_in[11];
  float* out = (float*)d_out;

  // ws layout (same 80.2 MB footprint):
  //   rowptr int[50048] | csr int[800000] | h1 25.6MB | h2 25.6MB | Creg 25.6MB
  // Creg: cnt[4*NP4] | cursorP[4*NP4] | bsum (CSR build) -> selfb/u + z2 later.
  char* ws = (char*)d_ws;
  int* rowptr = (int*)ws;
  int* csr    = (int*)(ws + 200192);
  float* h1   = (float*)(ws + 3400192);
  float* h2   = (float*)(ws + 29000192);
  char* Creg  = ws + 54600192;
  float* selfb = (float*)Creg;                              // self / u
  unsigned short* z2 = (unsigned short*)(Creg + 12800000);  // layer-2 z (6.4MB)
  int* cnt     = (int*)Creg;                                // 800768 B
  int* cursorP = (int*)(Creg + 800768);                     // 800768 B
  int* bsum    = (int*)(Creg + 1601536);                    // SCAN1_B ints

  // z for layers 0/1 lives in d_out (12.8 MB exactly; dead before final write)
  unsigned short* zb = (unsigned short*)d_out;

  // split weights staged at h2 base (328 KB)
  unsigned short* wb = (unsigned short*)h2;
  unsigned short* wt0h = wb;
  unsigned short* wt0l = wb + 32768;
  unsigned short* wt1h = wb + 65536;
  unsigned short* wt1l = wb + 98304;
  unsigned short* wt2h = wb + 131072;
  unsigned short* wt2l = wb + 147456;

  // layer-2 weight copy target: h1 base (h1 dead after layer-1 gemm reads it)
  unsigned short* wt2hc = (unsigned short*)h1;
  unsigned short* wt2lc = wt2hc + 16384;

  // CSR build: custom zero + class-partitioned hist/fill + 4-bank sub-counters
  zero_kernel<<<SCAN1_B, 256, 0, stream>>>(cnt, 4 * NP4);
  hist_kernel<<<8 * FILL_CH, 256, 0, stream>>>(dst, cnt);
  scan1_kernel<<<SCAN1_B, 256, 0, stream>>>(cnt, cursorP, bsum);
  scan2_kernel<<<1, 1024, 0, stream>>>(bsum);
  scan3_kernel<<<SCAN1_B, 256, 0, stream>>>(cursorP, rowptr, bsum);
  fill_kernel<<<8 * FILL_CH, 256, 0, stream>>>(src, dst, cursorP, csr);
  wsplit_kernel<<<320, 256, 0, stream>>>(Ws0, Wn0, Ws1, Wn1, Ws2, Wn2, wb);

  // layer 0: self = x@Ws0 + b0 ; z = x@Wn0 (bf16) ; h1 = selu(self + mean(z))
  gemm_dual2<<<NT_GEMM, 256, 0, stream>>>(x, wt0h, wt0l, b0, selfb, zb);
  gather_act<<<6250, 256, 0, stream>>>(zb, selfb, rowptr, csr, h1);

  // layer 1: same with h1 -> h2
  gemm_dual2<<<NT_GEMM, 256, 0, stream>>>(h1, wt1h, wt1l, b1, selfb, zb);
  hipMemcpyAsync(wt2hc, wt2h, 65536, hipMemcpyDeviceToDevice, stream);  // h1 dead now
  gather_act<<<6250, 256, 0, stream>>>(zb, selfb, rowptr, csr, h2);     // clobbers wb

  // layer 2: u = h2@Ws2 + b2 ; z2 = h2@Wn2 (bf16) ; out = softmax(u + mean(z2))
  gemm_dual<128, 64><<<dim3(NT_GEMM, 1), 256, 0, stream>>>(h2, wt2hc, wt2lc, b2, selfb, z2);
  gather_sm<<<6250, 256, 0, stream>>>(z2, selfb, rowptr, csr, out);
}

// Round 16
// 248.582 us; speedup vs baseline: 1.9288x; 1.0107x over previous
//
#include <hip/hip_runtime.h>
#include <hip/hip_bf16.h>

#define N_NODES 50000
#define N_EDGES 800000
#define D 128
#define NPB 50048       // padded per-bank node count
#define NBANK 8
#define SCAN1_B 1564    // (NBANK*NPB)/256
#define NT_GEMM 782     // ceil(N_NODES/64)
#define E_CHUNK 2048
#define FILL_CH 391     // ceil(N_EDGES/E_CHUNK)

typedef __attribute__((ext_vector_type(8))) __bf16 bf16x8;
typedef __attribute__((ext_vector_type(4))) float f32x4;

union U8 {
  bf16x8 v;
  uint4 u;
};

// ---- fp32 -> bf16 helpers ----
__device__ __forceinline__ unsigned short bf16_rne(float x) {
  unsigned u = __builtin_bit_cast(unsigned, x);
  unsigned r = u + 0x7fffu + ((u >> 16) & 1u);
  return (unsigned short)(r >> 16);
}
__device__ __forceinline__ float bf16_f(unsigned short b) {
  unsigned u = ((unsigned)b) << 16;
  return __builtin_bit_cast(float, u);
}
// packed-dword bf16 extraction: lo short -> float, hi short -> float
__device__ __forceinline__ float bflo(unsigned u) {
  return __builtin_bit_cast(float, u << 16);
}
__device__ __forceinline__ float bfhi(unsigned u) {
  return __builtin_bit_cast(float, u & 0xffff0000u);
}
__device__ __forceinline__ void split2(float x, unsigned short& hi, unsigned short& lo) {
  hi = bf16_rne(x);
  lo = bf16_rne(x - bf16_f(hi));
}

__device__ __forceinline__ float selu_f(float x) {
  const float alpha = 1.6732632423543772f;
  const float scale = 1.0507009873554805f;
  return scale * (x > 0.0f ? x : alpha * expm1f(x));
}

// split raw fp32 bits (r0,r1 = 8 dwords) -> bf16 hi/lo fragments (trunc split)
__device__ __forceinline__ void splitF(uint4 r0, uint4 r1, U8& ah, U8& al) {
  unsigned u0 = r0.x, u1 = r0.y, u2 = r0.z, u3 = r0.w;
  unsigned u4 = r1.x, u5 = r1.y, u6 = r1.z, u7 = r1.w;
  ah.u.x = (u0 >> 16) | (u1 & 0xffff0000u);
  ah.u.y = (u2 >> 16) | (u3 & 0xffff0000u);
  ah.u.z = (u4 >> 16) | (u5 & 0xffff0000u);
  ah.u.w = (u6 >> 16) | (u7 & 0xffff0000u);
  unsigned r;
#define LOW(u) __builtin_bit_cast(unsigned, __builtin_bit_cast(float, u) - __builtin_bit_cast(float, u & 0xffff0000u))
  r = LOW(u0); al.u.x = r >> 16;
  r = LOW(u1); al.u.x |= r & 0xffff0000u;
  r = LOW(u2); al.u.y = r >> 16;
  r = LOW(u3); al.u.y |= r & 0xffff0000u;
  r = LOW(u4); al.u.z = r >> 16;
  r = LOW(u5); al.u.z |= r & 0xffff0000u;
  r = LOW(u6); al.u.w = r >> 16;
  r = LOW(u7); al.u.w |= r & 0xffff0000u;
#undef LOW
}

// ================= zero =================
__global__ __launch_bounds__(256) void zero_kernel(int* __restrict__ p, int n) {
  int i = blockIdx.x * 256 + threadIdx.x;
  if (i < n) p[i] = 0;
}

// ================= CSR build =================
// XCD-class partition (class = (dst>>4)&7, block bid: chunk=bid>>3, cls=bid&7)
// + 8-way sub-counters keyed by e&7, layout [p][NPB] (contention spread).
__global__ __launch_bounds__(256) void hist_kernel(const int* __restrict__ dst,
                                                   int* __restrict__ cnt) {
  const int cls = blockIdx.x & 7;
  const int base = (blockIdx.x >> 3) * E_CHUNK + threadIdx.x;
#pragma unroll
  for (int i = 0; i < E_CHUNK / 256; ++i) {
    int e = base + i * 256;
    if (e < N_EDGES) {
      int d = dst[e];
      if (((d >> 4) & 7) == cls) atomicAdd(&cnt[(e & (NBANK - 1)) * NPB + d], 1);
    }
  }
}

// scan1: exclusive scan partials over logical node-major order j=(n<<3)|p,
// reading/writing the transposed [p][NPB] layout.
__global__ __launch_bounds__(256) void scan1_kernel(const int* __restrict__ cnt,
                                                    int* __restrict__ cur,
                                                    int* __restrict__ bsum) {
  __shared__ int s[256];
  const int t = threadIdx.x;
  const int j = blockIdx.x * 256 + t;
  const int n = j >> 3, p = j & 7;
  int v = (n < N_NODES) ? cnt[p * NPB + n] : 0;
  s[t] = v;
  __syncthreads();
#pragma unroll
  for (int off = 1; off < 256; off <<= 1) {
    int u = (t >= off) ? s[t - off] : 0;
    __syncthreads();
    s[t] += u;
    __syncthreads();
  }
  if (n < N_NODES) cur[p * NPB + n] = s[t] - v;  // missing block offset
  if (t == 255) bsum[blockIdx.x] = s[255];
}

// scan3: per-block prefix over bsum computed in-kernel (replaces scan2+scan3);
// add block offsets; emit rowptr[n] at p==0.
__global__ __launch_bounds__(256) void scan3_kernel(int* __restrict__ cur,
                                                    int* __restrict__ rowptr,
                                                    const int* __restrict__ bsum) {
  __shared__ int s[256];
  const int t = threadIdx.x;
  int part = 0;
  for (int j = t; j < blockIdx.x; j += 256) part += bsum[j];
  s[t] = part;
  __syncthreads();
#pragma unroll
  for (int off = 128; off > 0; off >>= 1) {
    if (t < off) s[t] += s[t + off];
    __syncthreads();
  }
  const int prefix = s[0];
  const int j = blockIdx.x * 256 + t;
  const int n = j >> 3, p = j & 7;
  if (n < N_NODES) {
    int v = cur[p * NPB + n] + prefix;
    cur[p * NPB + n] = v;
    if (p == 0) rowptr[n] = v;
  }
}

__global__ __launch_bounds__(256) void fill_kernel(const int* __restrict__ src,
                                                   const int* __restrict__ dst,
                                                   int* __restrict__ cur,
                                                   int* __restrict__ csr_src) {
  const int cls = blockIdx.x & 7;
  const int base = (blockIdx.x >> 3) * E_CHUNK + threadIdx.x;
#pragma unroll
  for (int i = 0; i < E_CHUNK / 256; ++i) {
    int e = base + i * 256;
    if (e < N_EDGES) {
      int d = dst[e];
      if (((d >> 4) & 7) == cls) {
        int pos = atomicAdd(&cur[(e & (NBANK - 1)) * NPB + d], 1);
        csr_src[pos] = src[e];
      }
    }
  }
}

// ================= weight split/transpose precompute =================
// Per-layer B image, K=128, pre-swizzled (si = idx ^ ((n&7)<<3), idx = n*K+k).
__global__ __launch_bounds__(256) void wsplit_kernel(
    const float* __restrict__ Ws0, const float* __restrict__ Wn0,
    const float* __restrict__ Ws1, const float* __restrict__ Wn1,
    const float* __restrict__ Ws2, const float* __restrict__ Wn2,
    unsigned short* __restrict__ wb) {
  int idx = blockIdx.x * 256 + threadIdx.x;
  if (idx < 32768) {
    int n = idx >> 7, k = idx & 127;
    float wv = (n < 128) ? Ws0[k * 128 + n] : Wn0[k * 128 + (n - 128)];
    unsigned short h, l; split2(wv, h, l);
    int si = idx ^ ((n & 7) << 3);
    wb[si] = h; wb[32768 + si] = l;
  } else if (idx < 65536) {
    int j = idx - 32768;
    int n = j >> 7, k = j & 127;
    float wv = (n < 128) ? Ws1[k * 128 + n] : Wn1[k * 128 + (n - 128)];
    unsigned short h, l; split2(wv, h, l);
    int si = j ^ ((n & 7) << 3);
    wb[65536 + si] = h; wb[98304 + si] = l;
  } else if (idx < 81920) {
    int j = idx - 65536;
    int n = j >> 7, k = j & 127;
    float wv = (n < 64) ? Ws2[k * 64 + n] : Wn2[k * 64 + (n - 64)];
    unsigned short h, l; split2(wv, h, l);
    int si = j ^ ((n & 7) << 3);
    wb[131072 + si] = h; wb[147456 + si] = l;
  }
}

// ================= fused dual-panel MFMA GEMM (L0/L1) =================
__global__ __launch_bounds__(256, 2) void gemm_dual2(const float* __restrict__ hsrc,
                                                     const unsigned short* __restrict__ wth,
                                                     const unsigned short* __restrict__ wtl,
                                                     const float* __restrict__ bias,
                                                     float* __restrict__ out0,
                                                     unsigned short* __restrict__ out1) {
  constexpr int K = 128;
  __shared__ unsigned short bh_s[128 * K];
  __shared__ unsigned short bl_s[128 * K];

  const int tid = threadIdx.x;
  const int w = tid >> 6;
  const int l = tid & 63;
  const int lr = l & 15;
  const int lg = l >> 4;
  const int row0 = blockIdx.x * 64;
  const int arow = min(row0 + w * 16 + lr, N_NODES - 1);

  uint4 a[8];
  {
    const uint4* hp = (const uint4*)(hsrc + (size_t)arow * D);
#pragma unroll
    for (int q = 0; q < 2; ++q)
#pragma unroll
      for (int kt = 0; kt < 2; ++kt) {
        a[q * 4 + kt * 2 + 0] = hp[q * 16 + kt * 8 + lg * 2];
        a[q * 4 + kt * 2 + 1] = hp[q * 16 + kt * 8 + lg * 2 + 1];
      }
  }

#pragma unroll
  for (int cb = 0; cb < 2; ++cb) {
    if (cb) __syncthreads();  // WAR: all panel-0 LDS reads complete
    {
      const uint4* gh = (const uint4*)(wth + (size_t)cb * 128 * K);
      const uint4* gl = (const uint4*)(wtl + (size_t)cb * 128 * K);
      uint4* sh = (uint4*)bh_s;
      uint4* sl = (uint4*)bl_s;
#pragma unroll
      for (int i = 0; i < 8; ++i) {
        sh[tid + i * 256] = gh[tid + i * 256];
        sl[tid + i * 256] = gl[tid + i * 256];
      }
    }
    __syncthreads();

    f32x4 accA[8], accB[8];
#pragma unroll
    for (int i = 0; i < 8; ++i) {
      accA[i] = (f32x4){0.f, 0.f, 0.f, 0.f};
      accB[i] = (f32x4){0.f, 0.f, 0.f, 0.f};
    }

#pragma unroll
    for (int q = 0; q < 2; ++q) {
#pragma unroll
      for (int kt = 0; kt < 2; ++kt) {
        U8 ah, al;
        splitF(a[q * 4 + kt * 2], a[q * 4 + kt * 2 + 1], ah, al);
        const int kb = q * 64 + (((((kt << 2) | lg)) ^ (lr & 7)) << 3);
#pragma unroll
        for (int nf = 0; nf < 8; ++nf) {
          const int si = (nf * 16 + lr) * K + kb;
          bf16x8 bh = *(const bf16x8*)&bh_s[si];
          bf16x8 bl = *(const bf16x8*)&bl_s[si];
          accA[nf] = __builtin_amdgcn_mfma_f32_16x16x32_bf16(ah.v, bh, accA[nf], 0, 0, 0);
          accB[nf] = __builtin_amdgcn_mfma_f32_16x16x32_bf16(al.v, bh, accB[nf], 0, 0, 0);
          accB[nf] = __builtin_amdgcn_mfma_f32_16x16x32_bf16(ah.v, bl, accB[nf], 0, 0, 0);
        }
      }
    }

#pragma unroll
    for (int nf = 0; nf < 8; ++nf) {
      const int col = nf * 16 + lr;
      const float bv = (cb == 0) ? bias[col] : 0.0f;
#pragma unroll
      for (int i = 0; i < 4; ++i) {
        const int grow = row0 + w * 16 + lg * 4 + i;
        if (grow < N_NODES) {
          float v = accA[nf][i] + accB[nf][i];
          if (cb == 0) {
            out0[(size_t)grow * 128 + col] = v + bv;
          } else {
            out1[(size_t)grow * 128 + col] = bf16_rne(v);
          }
        }
      }
    }
  }
}

// ================= single-panel MFMA GEMM (L2) =================
template <int TC, int ZC>
__global__ __launch_bounds__(256, 2) void gemm_dual(const float* __restrict__ hsrc,
                                                    const unsigned short* __restrict__ wth,
                                                    const unsigned short* __restrict__ wtl,
                                                    const float* __restrict__ bias,
                                                    float* __restrict__ out0,
                                                    unsigned short* __restrict__ out1) {
  constexpr int K = 128;
  __shared__ unsigned short bh_s[128 * K];
  __shared__ unsigned short bl_s[128 * K];

  const int tid = threadIdx.x;
  const int w = tid >> 6;
  const int l = tid & 63;
  const int lr = l & 15;
  const int lg = l >> 4;
  const int cb = blockIdx.y;
  const int colbase = cb * 128;
  const int row0 = blockIdx.x * 64;
  const int arow = min(row0 + w * 16 + lr, N_NODES - 1);

  uint4 a[8];
  {
    const uint4* hp = (const uint4*)(hsrc + (size_t)arow * D);
#pragma unroll
    for (int q = 0; q < 2; ++q)
#pragma unroll
      for (int kt = 0; kt < 2; ++kt) {
        a[q * 4 + kt * 2 + 0] = hp[q * 16 + kt * 8 + lg * 2];
        a[q * 4 + kt * 2 + 1] = hp[q * 16 + kt * 8 + lg * 2 + 1];
      }
  }

  {
    const uint4* gh = (const uint4*)(wth + (size_t)colbase * K);
    const uint4* gl = (const uint4*)(wtl + (size_t)colbase * K);
    uint4* sh = (uint4*)bh_s;
    uint4* sl = (uint4*)bl_s;
#pragma unroll
    for (int i = 0; i < 8; ++i) {
      sh[tid + i * 256] = gh[tid + i * 256];
      sl[tid + i * 256] = gl[tid + i * 256];
    }
  }
  __syncthreads();

  f32x4 accA[8], accB[8];
#pragma unroll
  for (int i = 0; i < 8; ++i) {
    accA[i] = (f32x4){0.f, 0.f, 0.f, 0.f};
    accB[i] = (f32x4){0.f, 0.f, 0.f, 0.f};
  }

#pragma unroll
  for (int q = 0; q < 2; ++q) {
#pragma unroll
    for (int kt = 0; kt < 2; ++kt) {
      U8 ah, al;
      splitF(a[q * 4 + kt * 2], a[q * 4 + kt * 2 + 1], ah, al);
      const int kb = q * 64 + (((((kt << 2) | lg)) ^ (lr & 7)) << 3);
#pragma unroll
      for (int nf = 0; nf < 8; ++nf) {
        const int si = (nf * 16 + lr) * K + kb;
        bf16x8 bh = *(const bf16x8*)&bh_s[si];
        bf16x8 bl = *(const bf16x8*)&bl_s[si];
        accA[nf] = __builtin_amdgcn_mfma_f32_16x16x32_bf16(ah.v, bh, accA[nf], 0, 0, 0);
        accB[nf] = __builtin_amdgcn_mfma_f32_16x16x32_bf16(al.v, bh, accB[nf], 0, 0, 0);
        accB[nf] = __builtin_amdgcn_mfma_f32_16x16x32_bf16(ah.v, bl, accB[nf], 0, 0, 0);
      }
    }
  }

#pragma unroll
  for (int nf = 0; nf < 8; ++nf) {
    const int col = colbase + nf * 16 + lr;
#pragma unroll
    for (int i = 0; i < 4; ++i) {
      const int grow = row0 + w * 16 + lg * 4 + i;
      if (grow < N_NODES) {
        float v = accA[nf][i] + accB[nf][i];
        if (col < ZC) {
          out0[(size_t)grow * ZC + col] = v + bias[col];
        } else {
          out1[(size_t)grow * (TC - ZC) + (col - ZC)] = bf16_rne(v);
        }
      }
    }
  }
}

// ================= gather mean(z bf16) + self + SELU -> h_next =================
// 16 lanes per node, uint4 (16B = 8 bf16) per lane; 8-edge deep pipeline.
__global__ __launch_bounds__(256) void gather_act(const unsigned short* __restrict__ zb,
                                                  const float* __restrict__ selfb,
                                                  const int* __restrict__ rowptr,
                                                  const int* __restrict__ csr,
                                                  float* __restrict__ hnext) {
  const int n = blockIdx.x * 16 + (threadIdx.x >> 4);
  const int sl = threadIdx.x & 15;
  const int start = rowptr[n];
  const int end = (n < N_NODES - 1) ? rowptr[n + 1] : N_EDGES;
  const uint4* zp = (const uint4*)zb + sl;  // row stride = 16 uint4 (256B)
  float a0 = 0.f, a1 = 0.f, a2 = 0.f, a3 = 0.f;
  float a4 = 0.f, a5 = 0.f, a6 = 0.f, a7 = 0.f;
#define ACCU(v) { a0 += bflo(v.x); a1 += bfhi(v.x); a2 += bflo(v.y); a3 += bfhi(v.y); \
                  a4 += bflo(v.z); a5 += bfhi(v.z); a6 += bflo(v.w); a7 += bfhi(v.w); }
  int e = start;
  for (; e + 7 < end; e += 8) {
    int s0 = csr[e],     s1 = csr[e + 1], s2 = csr[e + 2], s3 = csr[e + 3];
    int s4 = csr[e + 4], s5 = csr[e + 5], s6 = csr[e + 6], s7 = csr[e + 7];
    uint4 v0 = zp[(size_t)s0 * 16];
    uint4 v1 = zp[(size_t)s1 * 16];
    uint4 v2 = zp[(size_t)s2 * 16];
    uint4 v3 = zp[(size_t)s3 * 16];
    uint4 v4 = zp[(size_t)s4 * 16];
    uint4 v5 = zp[(size_t)s5 * 16];
    uint4 v6 = zp[(size_t)s6 * 16];
    uint4 v7 = zp[(size_t)s7 * 16];
    ACCU(v0) ACCU(v1) ACCU(v2) ACCU(v3) ACCU(v4) ACCU(v5) ACCU(v6) ACCU(v7)
  }
  if (e + 3 < end) {
    int s0 = csr[e], s1 = csr[e + 1], s2 = csr[e + 2], s3 = csr[e + 3];
    uint4 v0 = zp[(size_t)s0 * 16];
    uint4 v1 = zp[(size_t)s1 * 16];
    uint4 v2 = zp[(size_t)s2 * 16];
    uint4 v3 = zp[(size_t)s3 * 16];
    ACCU(v0) ACCU(v1) ACCU(v2) ACCU(v3)
    e += 4;
  }
  for (; e < end; ++e) {
    uint4 v0 = zp[(size_t)csr[e] * 16];
    ACCU(v0)
  }
#undef ACCU
  float inv = 1.0f / (float)max(end - start, 1);
  const float* sp = selfb + (size_t)n * D + sl * 8;
  float4 sv0 = *(const float4*)sp;
  float4 sv1 = *(const float4*)(sp + 4);
  float4 o0, o1;
  o0.x = selu_f(sv0.x + a0 * inv);
  o0.y = selu_f(sv0.y + a1 * inv);
  o0.z = selu_f(sv0.z + a2 * inv);
  o0.w = selu_f(sv0.w + a3 * inv);
  o1.x = selu_f(sv1.x + a4 * inv);
  o1.y = selu_f(sv1.y + a5 * inv);
  o1.z = selu_f(sv1.z + a6 * inv);
  o1.w = selu_f(sv1.w + a7 * inv);
  float* op = hnext + (size_t)n * D + sl * 8;
  *(float4*)op = o0;
  *(float4*)(op + 4) = o1;
}

// ================= gather mean(z2 bf16) + u + softmax -> out =================
// 16 lanes per node, uint2 (8B = 4 bf16) per lane; width-16 shuffle softmax.
__global__ __launch_bounds__(256) void gather_sm(const unsigned short* __restrict__ z2,
                                                 const float* __restrict__ u,
                                                 const int* __restrict__ rowptr,
                                                 const int* __restrict__ csr,
                                                 float* __restrict__ out) {
  const int n = blockIdx.x * 16 + (threadIdx.x >> 4);
  const int sl = threadIdx.x & 15;
  const int start = rowptr[n];
  const int end = (n < N_NODES - 1) ? rowptr[n + 1] : N_EDGES;
  const uint2* zp = (const uint2*)z2 + sl;  // row stride = 16 uint2 (128B)
  float a0 = 0.f, a1 = 0.f, a2 = 0.f, a3 = 0.f;
#define ACCU(v) { a0 += bflo(v.x); a1 += bfhi(v.x); a2 += bflo(v.y); a3 += bfhi(v.y); }
  int e = start;
  for (; e + 7 < end; e += 8) {
    int s0 = csr[e],     s1 = csr[e + 1], s2 = csr[e + 2], s3 = csr[e + 3];
    int s4 = csr[e + 4], s5 = csr[e + 5], s6 = csr[e + 6], s7 = csr[e + 7];
    uint2 v0 = zp[(size_t)s0 * 16];
    uint2 v1 = zp[(size_t)s1 * 16];
    uint2 v2 = zp[(size_t)s2 * 16];
    uint2 v3 = zp[(size_t)s3 * 16];
    uint2 v4 = zp[(size_t)s4 * 16];
    uint2 v5 = zp[(size_t)s5 * 16];
    uint2 v6 = zp[(size_t)s6 * 16];
    uint2 v7 = zp[(size_t)s7 * 16];
    ACCU(v0) ACCU(v1) ACCU(v2) ACCU(v3) ACCU(v4) ACCU(v5) ACCU(v6) ACCU(v7)
  }
  if (e + 3 < end) {
    int s0 = csr[e], s1 = csr[e + 1], s2 = csr[e + 2], s3 = csr[e + 3];
    uint2 v0 = zp[(size_t)s0 * 16];
    uint2 v1 = zp[(size_t)s1 * 16];
    uint2 v2 = zp[(size_t)s2 * 16];
    uint2 v3 = zp[(size_t)s3 * 16];
    ACCU(v0) ACCU(v1) ACCU(v2) ACCU(v3)
    e += 4;
  }
  for (; e < end; ++e) {
    uint2 v0 = zp[(size_t)csr[e] * 16];
    ACCU(v0)
  }
#undef ACCU
  float inv = 1.0f / (float)max(end - start, 1);
  size_t o = (size_t)n * 64 + sl * 4;
  float4 uv = *(const float4*)(u + o);
  float v0 = uv.x + a0 * inv;
  float v1 = uv.y + a1 * inv;
  float v2 = uv.z + a2 * inv;
  float v3 = uv.w + a3 * inv;
  float m = fmaxf(fmaxf(v0, v1), fmaxf(v2, v3));
#pragma unroll
  for (int off = 8; off > 0; off >>= 1) m = fmaxf(m, __shfl_xor(m, off, 16));
  float e0 = expf(v0 - m);
  float e1 = expf(v1 - m);
  float e2 = expf(v2 - m);
  float e3 = expf(v3 - m);
  float s = (e0 + e1) + (e2 + e3);
#pragma unroll
  for (int off = 8; off > 0; off >>= 1) s += __shfl_xor(s, off, 16);
  float r = 1.0f / s;
  float4 ov;
  ov.x = e0 * r; ov.y = e1 * r; ov.z = e2 * r; ov.w = e3 * r;
  *(float4*)(out + o) = ov;
}

extern "C" void kernel_launch(void* const* d_in, const int* in_sizes, int n_in,
                              void* d_out, int out_size, void* d_ws, size_t ws_size,
                              hipStream_t stream) {
  const float* x   = (const float*)d_in[0];
  const int* src   = (const int*)d_in[1];
  const int* dst   = (const int*)d_in[2];
  const float* Ws0 = (const float*)d_in[3];
  const float* Wn0 = (const float*)d_in[4];
  const float* b0  = (const float*)d_in[5];
  const float* Ws1 = (const float*)d_in[6];
  const float* Wn1 = (const float*)d_in[7];
  const float* b1  = (const float*)d_in[8];
  const float* Ws2 = (const float*)d_in[9];
  const float* Wn2 = (const float*)d_in[10];
  const float* b2  = (const float*)d_in[11];
  float* out = (float*)d_out;

  // ws layout (same 80.2 MB footprint):
  //   rowptr int[50048] | csr int[800000] | h1 25.6MB | h2 25.6MB | Creg 25.6MB
  // Creg: cnt[8*NPB] | cursorP[8*NPB] | bsum (CSR build) -> selfb/u + z2 later.
  char* ws = (char*)d_ws;
  int* rowptr = (int*)ws;
  int* csr    = (int*)(ws + 200192);
  float* h1   = (float*)(ws + 3400192);
  float* h2   = (float*)(ws + 29000192);
  char* Creg  = ws + 54600192;
  float* selfb = (float*)Creg;                              // self / u
  unsigned short* z2 = (unsigned short*)(Creg + 12800000);  // layer-2 z (6.4MB)
  int* cnt     = (int*)Creg;                                // 1601536 B
  int* cursorP = (int*)(Creg + 1601536);                    // 1601536 B
  int* bsum    = (int*)(Creg + 3203072);                    // SCAN1_B ints

  // z for layers 0/1 lives in d_out (12.8 MB exactly; dead before final write)
  unsigned short* zb = (unsigned short*)d_out;

  // split weights staged at h2 base (328 KB)
  unsigned short* wb = (unsigned short*)h2;
  unsigned short* wt0h = wb;
  unsigned short* wt0l = wb + 32768;
  unsigned short* wt1h = wb + 65536;
  unsigned short* wt1l = wb + 98304;
  unsigned short* wt2h = wb + 131072;
  unsigned short* wt2l = wb + 147456;

  // layer-2 weight copy target: h1 base (h1 dead after layer-1 gemm reads it)
  unsigned short* wt2hc = (unsigned short*)h1;
  unsigned short* wt2lc = wt2hc + 16384;

  // CSR build: zero + class-partitioned hist/fill + 8-bank sub-counters + scan
  zero_kernel<<<SCAN1_B, 256, 0, stream>>>(cnt, NBANK * NPB);
  hist_kernel<<<8 * FILL_CH, 256, 0, stream>>>(dst, cnt);
  scan1_kernel<<<SCAN1_B, 256, 0, stream>>>(cnt, cursorP, bsum);
  scan3_kernel<<<SCAN1_B, 256, 0, stream>>>(cursorP, rowptr, bsum);
  fill_kernel<<<8 * FILL_CH, 256, 0, stream>>>(src, dst, cursorP, csr);
  wsplit_kernel<<<320, 256, 0, stream>>>(Ws0, Wn0, Ws1, Wn1, Ws2, Wn2, wb);

  // layer 0: self = x@Ws0 + b0 ; z = x@Wn0 (bf16) ; h1 = selu(self + mean(z))
  gemm_dual2<<<NT_GEMM, 256, 0, stream>>>(x, wt0h, wt0l, b0, selfb, zb);
  gather_act<<<3125, 256, 0, stream>>>(zb, selfb, rowptr, csr, h1);

  // layer 1: same with h1 -> h2
  gemm_dual2<<<NT_GEMM, 256, 0, stream>>>(h1, wt1h, wt1l, b1, selfb, zb);
  hipMemcpyAsync(wt2hc, wt2h, 65536, hipMemcpyDeviceToDevice, stream);  // h1 dead now
  gather_act<<<3125, 256, 0, stream>>>(zb, selfb, rowptr, csr, h2);     // clobbers wb

  // layer 2: u = h2@Ws2 + b2 ; z2 = h2@Wn2 (bf16) ; out = softmax(u + mean(z2))
  gemm_dual<128, 64><<<dim3(NT_GEMM, 1), 256, 0, stream>>>(h2, wt2hc, wt2lc, b2, selfb, z2);
  gather_sm<<<3125, 256, 0, stream>>>(z2, selfb, rowptr, csr, out);
}